// Round 2
// baseline (862.331 us; speedup 1.0000x reference)
//
#include <hip/hip_runtime.h>
#include <hip/hip_bf16.h>
#include <math.h>

// ---------------- problem constants ----------------
constexpr int NN = 50000;   // nodes
constexpr int EE = 800000;  // edges

// ---------------- workspace layout (float offsets) ----------------
// f32 weights (written by wnorm)
constexpr int OFF_WT_NODE  = 0;        // [128][512] k-major: col groups 0:asrc+asub 1:adst-asub 2:pool 3:pool2
constexpr int OFF_WT_AMUL  = 65536;    // [128][128] k-major
constexpr int OFF_WT_FINAL = 81920;    // [384][128] k-major; k: 0-127 neigh, 128-255 neigh2, 256-383 self
constexpr int OFF_WT_MLP   = 131072;   // 2 x [128][128] k-major
constexpr int OFF_WAOUT    = 163840;   // [128]
constexpr int OFF_BE       = 163968;   // [128]
constexpr int OFF_BFIN     = 164096;   // [128]
constexpr int OFF_BAOUT    = 164224;   // [1] (pad 16)
// bf16 transposed weight tables ([o][k])
constexpr int OFF_WNODEBF  = 164240;               // 512*128 ushort = 32768 fl
constexpr int OFF_WFINBF   = OFF_WNODEBF + 32768;  // 128*384 ushort = 24576 fl
constexpr int OFF_WMLPBF   = OFF_WFINBF + 24576;   // 2*128*128 ushort = 16384 fl
constexpr int OFF_WAMULBF  = OFF_WMLPBF + 16384;   // 128*128 ushort = 8192 fl
// big arrays
constexpr int OFF_FEATBF   = OFF_WAMULBF + 8192;   // [N][128] bf16
constexpr int OFF_SBF      = OFF_FEATBF + NN*64;   // region reused: edge fused weight table
constexpr int OFF_WEDGEBF  = OFF_SBF;              // [128][384] bf16 = [Wmul | Wsrc+Wsub | Wdst-Wsub]
constexpr int OFF_HBF      = OFF_SBF + NN*128;     // [N][256] bf16 (h | h2)
constexpr int OFF_SEV      = OFF_HBF + NN*128;     // [E] f32, dst-sorted e
constexpr int OFF_NEIGHBF  = OFF_SEV + EE;         // [N][256] bf16 (neigh | neigh2)
constexpr int OFF_STARTS   = OFF_NEIGHBF + NN*128; // [N+1] int (+pad)
constexpr int OFF_HIST     = OFF_STARTS + NN + 8;  // [N] int
constexpr int OFF_CURSOR   = OFF_HIST + NN;        // [N] int
constexpr int OFF_SSRCD    = OFF_CURSOR + NN;      // [E] int2 (src,dst sorted by dst)

typedef __attribute__((ext_vector_type(8))) short bf16x8;
typedef __attribute__((ext_vector_type(4))) float f32x4;

// ---------------- device helpers ----------------
// fast GELU (tanh form via sigmoid), log2e folded into polynomial, rcp instead of div.
// gelu(x) ~= x * sigmoid(1.5957691216 x + 0.07135481283 x^3); exp(-u) = exp2(w)
__device__ __forceinline__ float gelu_f(float x) {
    float x2 = x * x;
    float w = x * fmaf(-0.1029448f, x2, -2.3022082f);
    return x * __builtin_amdgcn_rcpf(1.0f + __builtin_amdgcn_exp2f(w));
}
__device__ __forceinline__ float leaky_f(float x) {
    return x > 0.0f ? x : 0.2f * x;
}
__device__ __forceinline__ unsigned short f2bf(float x) {
    unsigned u = __float_as_uint(x);
    return (unsigned short)((u + 0x7fffu + ((u >> 16) & 1u)) >> 16);
}
__device__ __forceinline__ float bf2f(unsigned short b) {
    return __uint_as_float(((unsigned)b) << 16);
}
// packed 2x f32 -> bf16x2 (lo in bits 0-15) via HIP's HW-backed scalar convert
__device__ __forceinline__ unsigned pk_bf16(float lo, float hi) {
    __hip_bfloat16 l = __float2bfloat16(lo);
    __hip_bfloat16 h = __float2bfloat16(hi);
    unsigned short lu = *reinterpret_cast<unsigned short*>(&l);
    unsigned short hu = *reinterpret_cast<unsigned short*>(&h);
    return (unsigned)lu | ((unsigned)hu << 16);
}
__device__ __forceinline__ unsigned mulpack(unsigned a, unsigned b) {
    float a0 = __uint_as_float(a << 16), a1 = __uint_as_float(a & 0xffff0000u);
    float b0 = __uint_as_float(b << 16), b1 = __uint_as_float(b & 0xffff0000u);
    return pk_bf16(a0 * b0, a1 * b1);
}
__device__ __forceinline__ float block_sum128(float v, float* sbuf) {
    #pragma unroll
    for (int o = 32; o > 0; o >>= 1) v += __shfl_down(v, o, 64);
    int lane = threadIdx.x & 63, w = threadIdx.x >> 6;
    if (lane == 0) sbuf[w] = v;
    __syncthreads();
    float r = sbuf[0] + sbuf[1];
    __syncthreads();
    return r;
}

// ---------------- weight normalization ----------------
struct WnormArgs {
    const float *asrc_v, *asrc_g, *asrc_b;
    const float *adst_v, *adst_g, *adst_b;
    const float *asub_v, *asub_g, *asub_b;
    const float *amul_v, *amul_g, *amul_b;
    const float *aout_v, *aout_g, *aout_b;
    const float *pool_v, *pool_g, *pool_b;
    const float *pool2_v, *pool2_g, *pool2_b;
    const float *self_v, *self_g, *self_b;
    const float *neigh_v, *neigh_g, *neigh_b;
    const float *neigh2_v, *neigh2_g, *neigh2_b;
    const float *mlp_v, *mlp_g, *mlp_b;
    float* ws;
};

__global__ __launch_bounds__(128) void wnorm_kernel(WnormArgs a) {
    __shared__ float sbuf[2];
    int bid = blockIdx.x, i = threadIdx.x;
    float* ws = a.ws;
    if (bid < 1280) {
        int o = bid & 127, grp = bid >> 7;
        const float *v1 = nullptr, *g1 = nullptr, *v2 = nullptr, *g2 = nullptr;
        float sgn2 = 1.0f; float* dst = nullptr; int stride = 0;
        switch (grp) {
            case 0: v1=a.asrc_v; g1=a.asrc_g; v2=a.asub_v; g2=a.asub_g; sgn2= 1.f; dst=ws+OFF_WT_NODE+o;        stride=512; break;
            case 1: v1=a.adst_v; g1=a.adst_g; v2=a.asub_v; g2=a.asub_g; sgn2=-1.f; dst=ws+OFF_WT_NODE+128+o;    stride=512; break;
            case 2: v1=a.pool_v;  g1=a.pool_g;  dst=ws+OFF_WT_NODE+256+o;          stride=512; break;
            case 3: v1=a.pool2_v; g1=a.pool2_g; dst=ws+OFF_WT_NODE+384+o;          stride=512; break;
            case 4: v1=a.amul_v;  g1=a.amul_g;  dst=ws+OFF_WT_AMUL+o;              stride=128; break;
            case 5: v1=a.neigh_v; g1=a.neigh_g; dst=ws+OFF_WT_FINAL+o;             stride=128; break;
            case 6: v1=a.neigh2_v;g1=a.neigh2_g;dst=ws+OFF_WT_FINAL+128*128+o;     stride=128; break;
            case 7: v1=a.self_v;  g1=a.self_g;  dst=ws+OFF_WT_FINAL+256*128+o;     stride=128; break;
            case 8: v1=a.mlp_v;        g1=a.mlp_g;     dst=ws+OFF_WT_MLP+o;        stride=128; break;
            case 9: v1=a.mlp_v+16384;  g1=a.mlp_g+128; dst=ws+OFF_WT_MLP+16384+o;  stride=128; break;
        }
        float x1 = v1[o*128 + i];
        float n1 = sqrtf(block_sum128(x1*x1, sbuf));
        float w = g1[o] * x1 / n1;
        if (v2) {
            float x2 = v2[o*128 + i];
            float n2 = sqrtf(block_sum128(x2*x2, sbuf));
            w += sgn2 * g2[o] * x2 / n2;
        }
        dst[i * stride] = w;
    } else {
        float v = a.aout_v[i];
        float n = sqrtf(block_sum128(v*v, sbuf));
        ws[OFF_WAOUT + i] = a.aout_g[0] * v / n;
        ws[OFF_BE + i]    = a.asrc_b[i] + a.adst_b[i] + a.asub_b[i] + a.amul_b[i];
        ws[OFF_BFIN + i]  = a.self_b[i] + a.neigh_b[i] + a.neigh2_b[i];
        if (i == 0) ws[OFF_BAOUT] = a.aout_b[0];
    }
}

// ---------------- bf16 conversions ----------------
__global__ __launch_bounds__(256) void convert_feat_kernel(const float* __restrict__ feat,
                                                           unsigned short* __restrict__ featbf) {
    int i = (blockIdx.x * 256 + threadIdx.x) * 8;
    float4 v0 = ((const float4*)feat)[i >> 2];
    float4 v1 = ((const float4*)feat)[(i >> 2) + 1];
    uint4 p;
    p.x = pk_bf16(v0.x, v0.y);
    p.y = pk_bf16(v0.z, v0.w);
    p.z = pk_bf16(v1.x, v1.y);
    p.w = pk_bf16(v1.z, v1.w);
    *(uint4*)&featbf[i] = p;
}

// all weight tables -> transposed bf16 [o][k]; 832 blocks x 256
__global__ __launch_bounds__(256) void convert_weights_kernel(float* __restrict__ ws) {
    int idx = blockIdx.x * 256 + threadIdx.x;
    unsigned short* wnodebf = (unsigned short*)(ws + OFF_WNODEBF);
    unsigned short* wfinbf  = (unsigned short*)(ws + OFF_WFINBF);
    unsigned short* wmlpbf  = (unsigned short*)(ws + OFF_WMLPBF);
    unsigned short* wamulbf = (unsigned short*)(ws + OFF_WAMULBF);
    unsigned short* wedgebf = (unsigned short*)(ws + OFF_WEDGEBF);
    if (idx < 65536) {                 // node: [k 128][n 512] -> [n][k]
        int k = idx >> 9, n = idx & 511;
        wnodebf[n * 128 + k] = f2bf(ws[OFF_WT_NODE + k * 512 + n]);
    } else if (idx < 114688) {         // final: [k 384][o 128] -> [o][k]
        int i = idx - 65536, k = i >> 7, o = i & 127;
        wfinbf[o * 384 + k] = f2bf(ws[OFF_WT_FINAL + k * 128 + o]);
    } else if (idx < 147456) {         // mlp: 2 x [k 128][o 128] -> [o][k]
        int i = idx - 114688, l = i >> 14, j = i & 16383, k = j >> 7, o = j & 127;
        wmlpbf[l * 16384 + o * 128 + k] = f2bf(ws[OFF_WT_MLP + l * 16384 + k * 128 + o]);
    } else if (idx < 163840) {         // amul: [k 128][o 128] -> [o][k]
        int i = idx - 147456, k = i >> 7, o = i & 127;
        wamulbf[o * 128 + k] = f2bf(ws[OFF_WT_AMUL + k * 128 + o]);
    } else {                           // fused edge table: [o 128][k 384] = [Wmul | W1 | W2]
        int i = idx - 163840, k = i >> 7, o = i & 127;
        float v = (k < 128) ? ws[OFF_WT_AMUL + k * 128 + o]
                : (k < 256) ? ws[OFF_WT_NODE + (k - 128) * 512 + o]
                            : ws[OFF_WT_NODE + (k - 256) * 512 + 128 + o];
        wedgebf[o * 384 + k] = f2bf(v);
    }
}

// ---------------- CSR-by-dst construction ----------------
__global__ __launch_bounds__(256) void hist_zero_kernel(float* __restrict__ ws) {
    int i = blockIdx.x * 256 + threadIdx.x;
    if (i < NN) ((int*)(ws + OFF_HIST))[i] = 0;
}

__global__ __launch_bounds__(256) void hist_kernel(const int* __restrict__ dst, float* __restrict__ ws) {
    int e = blockIdx.x * 256 + threadIdx.x;
    if (e < EE) atomicAdd(&((int*)(ws + OFF_HIST))[dst[e]], 1);
}

__global__ __launch_bounds__(1024) void scan_kernel(float* __restrict__ ws) {
    __shared__ int sp[1024];
    const int* hist = (const int*)(ws + OFF_HIST);
    int* starts = (int*)(ws + OFF_STARTS);
    int* cursor = (int*)(ws + OFF_CURSOR);
    int t = threadIdx.x;
    const int C = 49;
    int base = t * C;
    int local = 0;
    for (int j = 0; j < C; ++j) { int idx = base + j; if (idx < NN) local += hist[idx]; }
    sp[t] = local;
    __syncthreads();
    for (int o = 1; o < 1024; o <<= 1) {
        int v = (t >= o) ? sp[t - o] : 0;
        __syncthreads();
        sp[t] += v;
        __syncthreads();
    }
    int run = sp[t] - local;
    for (int j = 0; j < C; ++j) {
        int idx = base + j;
        if (idx < NN) { starts[idx] = run; cursor[idx] = run; run += hist[idx]; }
    }
    if (t == 0) starts[NN] = EE;
}

__global__ __launch_bounds__(256) void scatteridx_kernel(const int* __restrict__ src,
                                                         const int* __restrict__ dst,
                                                         float* __restrict__ ws) {
    int e = blockIdx.x * 256 + threadIdx.x;
    if (e >= EE) return;
    int d = dst[e];
    int pos = atomicAdd(&((int*)(ws + OFF_CURSOR))[d], 1);
    ((int2*)(ws + OFF_SSRCD))[pos] = make_int2(src[e], d);
}

// ---------------- segmented reduction -> neighbf bf16 [N][256], 2-deep pipelined ----------------
__global__ __launch_bounds__(256) void segreduce_kernel(float* __restrict__ ws) {
    int n = blockIdx.x * 4 + (threadIdx.x >> 6);
    int lane = threadIdx.x & 63;
    const int* starts = (const int*)(ws + OFF_STARTS);
    const int2* ssrcd = (const int2*)(ws + OFF_SSRCD);
    const float* sev = ws + OFF_SEV;
    const unsigned short* hbf = (const unsigned short*)(ws + OFF_HBF);
    unsigned short* neighbf = (unsigned short*)(ws + OFF_NEIGHBF);
    int s0 = starts[n], s1 = starts[n + 1];
    float2 mx = make_float2(-INFINITY, -INFINITY);
    float2 sm = make_float2(0.f, 0.f);
    int i = s0;
    for (; i + 2 <= s1; i += 2) {
        int sA = ssrcd[i].x, sB = ssrcd[i + 1].x;
        float evA = sev[i], evB = sev[i + 1];
        unsigned hvA  = *(const unsigned*)&hbf[sA * 256 + lane * 2];
        unsigned h2vA = *(const unsigned*)&hbf[sA * 256 + 128 + lane * 2];
        unsigned hvB  = *(const unsigned*)&hbf[sB * 256 + lane * 2];
        unsigned h2vB = *(const unsigned*)&hbf[sB * 256 + 128 + lane * 2];
        mx.x = fmaxf(mx.x, evA * bf2f((unsigned short)(hvA & 0xffffu)));
        mx.y = fmaxf(mx.y, evA * bf2f((unsigned short)(hvA >> 16)));
        sm.x += evA * bf2f((unsigned short)(h2vA & 0xffffu));
        sm.y += evA * bf2f((unsigned short)(h2vA >> 16));
        mx.x = fmaxf(mx.x, evB * bf2f((unsigned short)(hvB & 0xffffu)));
        mx.y = fmaxf(mx.y, evB * bf2f((unsigned short)(hvB >> 16)));
        sm.x += evB * bf2f((unsigned short)(h2vB & 0xffffu));
        sm.y += evB * bf2f((unsigned short)(h2vB >> 16));
    }
    if (i < s1) {
        int s = ssrcd[i].x;
        float ev = sev[i];
        unsigned hv  = *(const unsigned*)&hbf[s * 256 + lane * 2];
        unsigned h2v = *(const unsigned*)&hbf[s * 256 + 128 + lane * 2];
        mx.x = fmaxf(mx.x, ev * bf2f((unsigned short)(hv & 0xffffu)));
        mx.y = fmaxf(mx.y, ev * bf2f((unsigned short)(hv >> 16)));
        sm.x += ev * bf2f((unsigned short)(h2v & 0xffffu));
        sm.y += ev * bf2f((unsigned short)(h2v >> 16));
    }
    int cnt = s1 - s0;
    if (cnt == 0) { mx.x = 0.f; mx.y = 0.f; }
    float ic = 1.0f / (float)max(cnt, 1);
    *(unsigned*)&neighbf[n * 256 + lane * 2] = pk_bf16(mx.x, mx.y);
    *(unsigned*)&neighbf[n * 256 + 128 + lane * 2] = pk_bf16(sm.x * ic, sm.y * ic);
}

// ---------------- node GEMM (MFMA): h / h2 only (S-table is fused into edge GEMM) ----------------
__global__ __launch_bounds__(256) void gemm_node_mfma(const unsigned short* __restrict__ featbf,
                                                      const float* __restrict__ pool_b,
                                                      const float* __restrict__ pool2_b,
                                                      unsigned short* __restrict__ hbf,
                                                      const unsigned short* __restrict__ wnodebf) {
    __shared__ unsigned short As[64 * 136];
    int tid = threadIdx.x;
    int row0 = blockIdx.x * 64, gy = blockIdx.y;
    #pragma unroll
    for (int it = 0; it < 4; ++it) {
        int idx = tid + it * 256;
        int r = idx >> 4, u = idx & 15;
        int rr = min(row0 + r, NN - 1);
        *(uint4*)&As[r * 136 + u * 8] = *(const uint4*)&featbf[rr * 128 + u * 8];
    }
    __syncthreads();
    int lane = tid & 63, w = tid >> 6;
    int quad = lane >> 4, l15 = lane & 15;
    const unsigned short* B = wnodebf + (gy + 2) * 128 * 128;
    const float* bias = gy == 0 ? pool_b : pool2_b;
    f32x4 acc[8] = {};
    #pragma unroll 1
    for (int ks = 0; ks < 4; ++ks) {
        bf16x8 a = *(const bf16x8*)&As[(w * 16 + l15) * 136 + ks * 32 + quad * 8];
        #pragma unroll
        for (int t = 0; t < 8; ++t) {
            bf16x8 b = *(const bf16x8*)&B[(t * 16 + l15) * 128 + ks * 32 + quad * 8];
            acc[t] = __builtin_amdgcn_mfma_f32_16x16x32_bf16(a, b, acc[t], 0, 0, 0);
        }
    }
    #pragma unroll
    for (int reg = 0; reg < 4; ++reg) {
        int row = row0 + w * 16 + quad * 4 + reg;
        if (row >= NN) continue;
        #pragma unroll
        for (int t = 0; t < 8; ++t) {
            int col = t * 16 + l15;
            hbf[row * 256 + gy * 128 + col] = f2bf(gelu_f(acc[t][reg] + bias[col]));
        }
    }
}

// ---------------- edge GEMM: fused K=384 [fs*fd | fs | fd] @ [Wmul|W1|W2]^T, LDS-free,
// barrier-free, direct gather-to-fragment, 128 edges/block (32/wave), epilogue -> sev ----
__global__ __launch_bounds__(256, 3) void gemm_edge(const unsigned short* __restrict__ featbf,
                                                    const unsigned short* __restrict__ wedgebf,
                                                    float* __restrict__ ws) {
    int tid = threadIdx.x;
    int lane = tid & 63, w = tid >> 6;
    int quad = lane >> 4, l15 = lane & 15;
    int e0 = blockIdx.x * 128;
    const int2* ssrcd = (const int2*)(ws + OFF_SSRCD);
    int r0 = w * 32 + l15;                       // A-fragment row, row-group 0
    int2 i0 = ssrcd[e0 + r0];
    int2 i1 = ssrcd[e0 + r0 + 16];               // row-group 1
    const unsigned short* f0s = &featbf[i0.x * 128];
    const unsigned short* f0d = &featbf[i0.y * 128];
    const unsigned short* f1s = &featbf[i1.x * 128];
    const unsigned short* f1d = &featbf[i1.y * 128];
    int ko = quad * 8;
    uint4 c0s = *(const uint4*)&f0s[ko];
    uint4 c0d = *(const uint4*)&f0d[ko];
    uint4 c1s = *(const uint4*)&f1s[ko];
    uint4 c1d = *(const uint4*)&f1d[ko];
    f32x4 acc0[8] = {}, acc1[8] = {};
    #pragma unroll
    for (int kb = 0; kb < 4; ++kb) {
        uint4 n0s = c0s, n0d = c0d, n1s = c1s, n1d = c1d;
        if (kb < 3) {                            // prefetch next K-chunk of feat gathers
            int ko2 = ko + (kb + 1) * 32;
            n0s = *(const uint4*)&f0s[ko2];
            n0d = *(const uint4*)&f0d[ko2];
            n1s = *(const uint4*)&f1s[ko2];
            n1d = *(const uint4*)&f1d[ko2];
        }
        uint4 m0, m1;                            // elementwise fs*fd products (bf16)
        m0.x = mulpack(c0s.x, c0d.x); m0.y = mulpack(c0s.y, c0d.y);
        m0.z = mulpack(c0s.z, c0d.z); m0.w = mulpack(c0s.w, c0d.w);
        m1.x = mulpack(c1s.x, c1d.x); m1.y = mulpack(c1s.y, c1d.y);
        m1.z = mulpack(c1s.z, c1d.z); m1.w = mulpack(c1s.w, c1d.w);
        bf16x8 am0 = *(const bf16x8*)&m0,  am1 = *(const bf16x8*)&m1;
        bf16x8 as0 = *(const bf16x8*)&c0s, ad0 = *(const bf16x8*)&c0d;
        bf16x8 as1 = *(const bf16x8*)&c1s, ad1 = *(const bf16x8*)&c1d;
        #pragma unroll
        for (int t = 0; t < 8; ++t) {
            const unsigned short* bp = &wedgebf[(t * 16 + l15) * 384 + kb * 32 + quad * 8];
            bf16x8 bm = *(const bf16x8*)&bp[0];      // Wmul k-slice
            bf16x8 b1 = *(const bf16x8*)&bp[128];    // W1 (asrc+asub) k-slice
            bf16x8 b2 = *(const bf16x8*)&bp[256];    // W2 (adst-asub) k-slice
            acc0[t] = __builtin_amdgcn_mfma_f32_16x16x32_bf16(am0, bm, acc0[t], 0, 0, 0);
            acc1[t] = __builtin_amdgcn_mfma_f32_16x16x32_bf16(am1, bm, acc1[t], 0, 0, 0);
            acc0[t] = __builtin_amdgcn_mfma_f32_16x16x32_bf16(as0, b1, acc0[t], 0, 0, 0);
            acc1[t] = __builtin_amdgcn_mfma_f32_16x16x32_bf16(as1, b1, acc1[t], 0, 0, 0);
            acc0[t] = __builtin_amdgcn_mfma_f32_16x16x32_bf16(ad0, b2, acc0[t], 0, 0, 0);
            acc1[t] = __builtin_amdgcn_mfma_f32_16x16x32_bf16(ad1, b2, acc1[t], 0, 0, 0);
        }
        c0s = n0s; c0d = n0d; c1s = n1s; c1d = n1d;
    }
    // epilogue: e = leaky(sum_col gelu(acc + be) * waout + b_aout)
    const float* waout = ws + OFF_WAOUT;
    const float* be = ws + OFF_BE;
    float b_aout = ws[OFF_BAOUT];
    float* e_out = ws + OFF_SEV;
    float wv[8], bv[8];
    #pragma unroll
    for (int t = 0; t < 8; ++t) { wv[t] = waout[t * 16 + l15]; bv[t] = be[t * 16 + l15]; }
    #pragma unroll
    for (int g = 0; g < 2; ++g) {
        #pragma unroll
        for (int reg = 0; reg < 4; ++reg) {
            int r = w * 32 + g * 16 + quad * 4 + reg;
            float partial = 0.0f;
            #pragma unroll
            for (int t = 0; t < 8; ++t) {
                float v = (g ? acc1[t][reg] : acc0[t][reg]) + bv[t];
                partial += gelu_f(v) * wv[t];
            }
            partial += __shfl_xor(partial, 1, 16);
            partial += __shfl_xor(partial, 2, 16);
            partial += __shfl_xor(partial, 4, 16);
            partial += __shfl_xor(partial, 8, 16);
            if (l15 == 0) e_out[e0 + r] = leaky_f(partial + b_aout);
        }
    }
}

// ---------------- final GEMM (MFMA, K=384, single-stage LDS) -> out f32 ----------------
__global__ __launch_bounds__(256) void gemm_final_mfma(const unsigned short* __restrict__ neighbf,
                                                       const unsigned short* __restrict__ featbf,
                                                       const unsigned short* __restrict__ wfinbf,
                                                       float* __restrict__ out,
                                                       const float* __restrict__ ws) {
    __shared__ unsigned short As[64 * 392];   // 64 rows x 384 cols bf16 (+8 pad)
    __shared__ float bfin_s[128];
    int tid = threadIdx.x;
    int row0 = blockIdx.x * 64;
    if (tid < 128) bfin_s[tid] = ws[OFF_BFIN + tid];
    #pragma unroll
    for (int rg = 0; rg < 3; ++rg) {
        #pragma unroll
        for (int it = 0; it < 4; ++it) {
            int idx = tid + it * 256;
            int r = idx >> 4, u = idx & 15;
            int rr = min(row0 + r, NN - 1);
            const unsigned short* sp = (rg == 0) ? &neighbf[rr * 256 + u * 8]
                                     : (rg == 1) ? &neighbf[rr * 256 + 128 + u * 8]
                                                 : &featbf[rr * 128 + u * 8];
            *(uint4*)&As[r * 392 + rg * 128 + u * 8] = *(const uint4*)sp;
        }
    }
    __syncthreads();
    int lane = tid & 63, w = tid >> 6;
    int quad = lane >> 4, l15 = lane & 15;
    f32x4 acc[8] = {};
    #pragma unroll 1
    for (int ks = 0; ks < 12; ++ks) {
        bf16x8 a = *(const bf16x8*)&As[(w * 16 + l15) * 392 + ks * 32 + quad * 8];
        #pragma unroll
        for (int t = 0; t < 8; ++t) {
            bf16x8 b = *(const bf16x8*)&wfinbf[(t * 16 + l15) * 384 + ks * 32 + quad * 8];
            acc[t] = __builtin_amdgcn_mfma_f32_16x16x32_bf16(a, b, acc[t], 0, 0, 0);
        }
    }
    #pragma unroll
    for (int reg = 0; reg < 4; ++reg) {
        int row = row0 + w * 16 + quad * 4 + reg;
        if (row >= NN) continue;
        #pragma unroll
        for (int t = 0; t < 8; ++t) {
            int col = t * 16 + l15;
            out[row * 128 + col] = acc[t][reg] + bfin_s[col];
        }
    }
}

// ---------------- MLP layer (MFMA, in-place on out; block reads only its own rows) ----------------
__global__ __launch_bounds__(256) void gemm_mlp_mfma(float* __restrict__ out,
                                                     const unsigned short* __restrict__ wmlp,
                                                     const float* __restrict__ bias) {
    __shared__ unsigned short As[64 * 136];
    int tid = threadIdx.x;
    int row0 = blockIdx.x * 64;
    #pragma unroll
    for (int it = 0; it < 8; ++it) {
        int idx = tid + it * 256;            // 64 rows x 32 float4-units
        int r = idx >> 5, u = idx & 31;
        int rr = min(row0 + r, NN - 1);      // clamp stays within this block's rows
        float4 v = ((const float4*)out)[rr * 32 + u];
        unsigned p0 = pk_bf16(gelu_f(v.x), gelu_f(v.y));
        unsigned p1 = pk_bf16(gelu_f(v.z), gelu_f(v.w));
        *(unsigned*)&As[r * 136 + u * 4]     = p0;
        *(unsigned*)&As[r * 136 + u * 4 + 2] = p1;
    }
    __syncthreads();
    int lane = tid & 63, w = tid >> 6;
    int quad = lane >> 4, l15 = lane & 15;
    f32x4 acc[8] = {};
    #pragma unroll 1
    for (int ks = 0; ks < 4; ++ks) {
        bf16x8 a = *(const bf16x8*)&As[(w * 16 + l15) * 136 + ks * 32 + quad * 8];
        #pragma unroll
        for (int t = 0; t < 8; ++t) {
            bf16x8 b = *(const bf16x8*)&wmlp[(t * 16 + l15) * 128 + ks * 32 + quad * 8];
            acc[t] = __builtin_amdgcn_mfma_f32_16x16x32_bf16(a, b, acc[t], 0, 0, 0);
        }
    }
    #pragma unroll
    for (int reg = 0; reg < 4; ++reg) {
        int row = row0 + w * 16 + quad * 4 + reg;
        if (row >= NN) continue;
        #pragma unroll
        for (int t = 0; t < 8; ++t) {
            int col = t * 16 + l15;
            out[row * 128 + col] += acc[t][reg] + bias[col];
        }
    }
}

// ---------------- host launch ----------------
extern "C" void kernel_launch(void* const* d_in, const int* in_sizes, int n_in,
                              void* d_out, int out_size, void* d_ws, size_t ws_size,
                              hipStream_t stream) {
    const float* feat = (const float*)d_in[0];
    WnormArgs wa;
    wa.asrc_v = (const float*)d_in[1];  wa.asrc_g = (const float*)d_in[2];  wa.asrc_b = (const float*)d_in[3];
    wa.adst_v = (const float*)d_in[4];  wa.adst_g = (const float*)d_in[5];  wa.adst_b = (const float*)d_in[6];
    wa.asub_v = (const float*)d_in[7];  wa.asub_g = (const float*)d_in[8];  wa.asub_b = (const float*)d_in[9];
    wa.amul_v = (const float*)d_in[10]; wa.amul_g = (const float*)d_in[11]; wa.amul_b = (const float*)d_in[12];
    wa.aout_v = (const float*)d_in[13]; wa.aout_g = (const float*)d_in[14]; wa.aout_b = (const float*)d_in[15];
    wa.pool_v = (const float*)d_in[16]; wa.pool_g = (const float*)d_in[17]; wa.pool_b = (const float*)d_in[18];
    wa.pool2_v= (const float*)d_in[19]; wa.pool2_g= (const float*)d_in[20]; wa.pool2_b= (const float*)d_in[21];
    wa.self_v = (const float*)d_in[22]; wa.self_g = (const float*)d_in[23]; wa.self_b = (const float*)d_in[24];
    wa.neigh_v= (const float*)d_in[25]; wa.neigh_g= (const float*)d_in[26]; wa.neigh_b= (const float*)d_in[27];
    wa.neigh2_v=(const float*)d_in[28]; wa.neigh2_g=(const float*)d_in[29]; wa.neigh2_b=(const float*)d_in[30];
    wa.mlp_v  = (const float*)d_in[31]; wa.mlp_g  = (const float*)d_in[32]; wa.mlp_b  = (const float*)d_in[33];
    const int* src = (const int*)d_in[34];
    const int* dst = (const int*)d_in[35];
    float* out = (float*)d_out;
    float* ws = (float*)d_ws;
    wa.ws = ws;
    unsigned short* featbf  = (unsigned short*)(ws + OFF_FEATBF);
    unsigned short* hbf     = (unsigned short*)(ws + OFF_HBF);
    unsigned short* neighbf = (unsigned short*)(ws + OFF_NEIGHBF);
    unsigned short* wnodebf = (unsigned short*)(ws + OFF_WNODEBF);
    unsigned short* wfinbf  = (unsigned short*)(ws + OFF_WFINBF);
    unsigned short* wmlpbf  = (unsigned short*)(ws + OFF_WMLPBF);
    unsigned short* wedgebf = (unsigned short*)(ws + OFF_WEDGEBF);

    // 1) normalized weights + fused bias vectors
    wnorm_kernel<<<dim3(1281), dim3(128), 0, stream>>>(wa);
    // 2) bf16 conversions (incl. fused edge weight table [128][384])
    convert_feat_kernel<<<dim3(NN * 128 / (256 * 8)), dim3(256), 0, stream>>>(feat, featbf);
    convert_weights_kernel<<<dim3(832), dim3(256), 0, stream>>>(ws);
    // 3) CSR-by-dst
    hist_zero_kernel<<<dim3((NN + 255) / 256), dim3(256), 0, stream>>>(ws);
    hist_kernel<<<dim3((EE + 255) / 256), dim3(256), 0, stream>>>(dst, ws);
    scan_kernel<<<dim3(1), dim3(1024), 0, stream>>>(ws);
    scatteridx_kernel<<<dim3((EE + 255) / 256), dim3(256), 0, stream>>>(src, dst, ws);
    // 4) node-level GEMM (MFMA): h/h2 only (S fused into edge GEMM)
    gemm_node_mfma<<<dim3(782, 2), dim3(256), 0, stream>>>(featbf, wa.pool_b, wa.pool2_b, hbf, wnodebf);
    // 5) edge GEMM (fused K=384, LDS/barrier-free) -> sev
    gemm_edge<<<dim3(EE / 128), dim3(256), 0, stream>>>(featbf, wedgebf, ws);
    // 6) segmented reduce -> neighbf (max zeroed | mean)
    segreduce_kernel<<<dim3(NN / 4), dim3(256), 0, stream>>>(ws);
    // 7) final GEMM (MFMA) -> out f32
    gemm_final_mfma<<<dim3(782), dim3(256), 0, stream>>>(neighbf, featbf, wfinbf, out, ws);
    // 8) two residual MLP layers (MFMA, in-place, block-self-contained rows)
    gemm_mlp_mfma<<<dim3(782), dim3(256), 0, stream>>>(out, wmlpbf, wa.mlp_b);
    gemm_mlp_mfma<<<dim3(782), dim3(256), 0, stream>>>(out, wmlpbf + 16384, wa.mlp_b + 128);
}

// Round 3
// 809.906 us; speedup vs baseline: 1.0647x; 1.0647x over previous
//
#include <hip/hip_runtime.h>
#include <hip/hip_bf16.h>
#include <math.h>

// ---------------- problem constants ----------------
constexpr int NN = 50000;   // nodes
constexpr int EE = 800000;  // edges

// ---------------- workspace layout (float offsets) ----------------
// f32 weights (written by wnorm)
constexpr int OFF_WT_NODE  = 0;        // [128][512] k-major: col groups 0:asrc+asub 1:adst-asub 2:pool 3:pool2
constexpr int OFF_WT_AMUL  = 65536;    // [128][128] k-major
constexpr int OFF_WT_FINAL = 81920;    // [384][128] k-major; k: 0-127 neigh, 128-255 neigh2, 256-383 self
constexpr int OFF_WT_MLP   = 131072;   // 2 x [128][128] k-major
constexpr int OFF_WAOUT    = 163840;   // [128]
constexpr int OFF_BE       = 163968;   // [128]
constexpr int OFF_BFIN     = 164096;   // [128]
constexpr int OFF_BAOUT    = 164224;   // [1] (pad 16)
// bf16 transposed weight tables ([o][k])
constexpr int OFF_WNODEBF  = 164240;               // 512*128 ushort = 32768 fl
constexpr int OFF_WFINBF   = OFF_WNODEBF + 32768;  // 128*384 ushort = 24576 fl
constexpr int OFF_WMLPBF   = OFF_WFINBF + 24576;   // 2*128*128 ushort = 16384 fl
constexpr int OFF_WAMULBF  = OFF_WMLPBF + 16384;   // 128*128 ushort = 8192 fl
// big arrays
constexpr int OFF_FEATBF   = OFF_WAMULBF + 8192;   // [N][128] bf16
constexpr int OFF_SBF      = OFF_FEATBF + NN*64;   // region reused: edge fused weight table
constexpr int OFF_WEDGEBF  = OFF_SBF;              // packed fragments: [(t*3+slice)*4+kb][lane 64][8] bf16
constexpr int OFF_HBF      = OFF_SBF + NN*128;     // [N][256] bf16 (h | h2)
constexpr int OFF_SEV      = OFF_HBF + NN*128;     // [E] f32, dst-sorted e
constexpr int OFF_NEIGHBF  = OFF_SEV + EE;         // [N][256] bf16 (neigh | neigh2)
constexpr int OFF_STARTS   = OFF_NEIGHBF + NN*128; // [N+1] int (+pad)
constexpr int OFF_HIST     = OFF_STARTS + NN + 8;  // [N] int
constexpr int OFF_CURSOR   = OFF_HIST + NN;        // [N] int
constexpr int OFF_SSRCD    = OFF_CURSOR + NN;      // [E] int2 (src,dst sorted by dst)

typedef __attribute__((ext_vector_type(8))) short bf16x8;
typedef __attribute__((ext_vector_type(4))) float f32x4;

// ---------------- device helpers ----------------
// fast GELU (tanh form via sigmoid), log2e folded into polynomial, rcp instead of div.
__device__ __forceinline__ float gelu_f(float x) {
    float x2 = x * x;
    float w = x * fmaf(-0.1029448f, x2, -2.3022082f);
    return x * __builtin_amdgcn_rcpf(1.0f + __builtin_amdgcn_exp2f(w));
}
__device__ __forceinline__ float leaky_f(float x) {
    return x > 0.0f ? x : 0.2f * x;
}
__device__ __forceinline__ unsigned short f2bf(float x) {
    unsigned u = __float_as_uint(x);
    return (unsigned short)((u + 0x7fffu + ((u >> 16) & 1u)) >> 16);
}
__device__ __forceinline__ float bf2f(unsigned short b) {
    return __uint_as_float(((unsigned)b) << 16);
}
__device__ __forceinline__ unsigned pk_bf16(float lo, float hi) {
    __hip_bfloat16 l = __float2bfloat16(lo);
    __hip_bfloat16 h = __float2bfloat16(hi);
    unsigned short lu = *reinterpret_cast<unsigned short*>(&l);
    unsigned short hu = *reinterpret_cast<unsigned short*>(&h);
    return (unsigned)lu | ((unsigned)hu << 16);
}
__device__ __forceinline__ unsigned mulpack(unsigned a, unsigned b) {
    float a0 = __uint_as_float(a << 16), a1 = __uint_as_float(a & 0xffff0000u);
    float b0 = __uint_as_float(b << 16), b1 = __uint_as_float(b & 0xffff0000u);
    return pk_bf16(a0 * b0, a1 * b1);
}
__device__ __forceinline__ float block_sum128(float v, float* sbuf) {
    #pragma unroll
    for (int o = 32; o > 0; o >>= 1) v += __shfl_down(v, o, 64);
    int lane = threadIdx.x & 63, w = threadIdx.x >> 6;
    if (lane == 0) sbuf[w] = v;
    __syncthreads();
    float r = sbuf[0] + sbuf[1];
    __syncthreads();
    return r;
}

// ---------------- weight normalization ----------------
struct WnormArgs {
    const float *asrc_v, *asrc_g, *asrc_b;
    const float *adst_v, *adst_g, *adst_b;
    const float *asub_v, *asub_g, *asub_b;
    const float *amul_v, *amul_g, *amul_b;
    const float *aout_v, *aout_g, *aout_b;
    const float *pool_v, *pool_g, *pool_b;
    const float *pool2_v, *pool2_g, *pool2_b;
    const float *self_v, *self_g, *self_b;
    const float *neigh_v, *neigh_g, *neigh_b;
    const float *neigh2_v, *neigh2_g, *neigh2_b;
    const float *mlp_v, *mlp_g, *mlp_b;
    float* ws;
};

__global__ __launch_bounds__(128) void wnorm_kernel(WnormArgs a) {
    __shared__ float sbuf[2];
    int bid = blockIdx.x, i = threadIdx.x;
    float* ws = a.ws;
    if (bid < 1280) {
        int o = bid & 127, grp = bid >> 7;
        const float *v1 = nullptr, *g1 = nullptr, *v2 = nullptr, *g2 = nullptr;
        float sgn2 = 1.0f; float* dst = nullptr; int stride = 0;
        switch (grp) {
            case 0: v1=a.asrc_v; g1=a.asrc_g; v2=a.asub_v; g2=a.asub_g; sgn2= 1.f; dst=ws+OFF_WT_NODE+o;        stride=512; break;
            case 1: v1=a.adst_v; g1=a.adst_g; v2=a.asub_v; g2=a.asub_g; sgn2=-1.f; dst=ws+OFF_WT_NODE+128+o;    stride=512; break;
            case 2: v1=a.pool_v;  g1=a.pool_g;  dst=ws+OFF_WT_NODE+256+o;          stride=512; break;
            case 3: v1=a.pool2_v; g1=a.pool2_g; dst=ws+OFF_WT_NODE+384+o;          stride=512; break;
            case 4: v1=a.amul_v;  g1=a.amul_g;  dst=ws+OFF_WT_AMUL+o;              stride=128; break;
            case 5: v1=a.neigh_v; g1=a.neigh_g; dst=ws+OFF_WT_FINAL+o;             stride=128; break;
            case 6: v1=a.neigh2_v;g1=a.neigh2_g;dst=ws+OFF_WT_FINAL+128*128+o;     stride=128; break;
            case 7: v1=a.self_v;  g1=a.self_g;  dst=ws+OFF_WT_FINAL+256*128+o;     stride=128; break;
            case 8: v1=a.mlp_v;        g1=a.mlp_g;     dst=ws+OFF_WT_MLP+o;        stride=128; break;
            case 9: v1=a.mlp_v+16384;  g1=a.mlp_g+128; dst=ws+OFF_WT_MLP+16384+o;  stride=128; break;
        }
        float x1 = v1[o*128 + i];
        float n1 = sqrtf(block_sum128(x1*x1, sbuf));
        float w = g1[o] * x1 / n1;
        if (v2) {
            float x2 = v2[o*128 + i];
            float n2 = sqrtf(block_sum128(x2*x2, sbuf));
            w += sgn2 * g2[o] * x2 / n2;
        }
        dst[i * stride] = w;
    } else {
        float v = a.aout_v[i];
        float n = sqrtf(block_sum128(v*v, sbuf));
        ws[OFF_WAOUT + i] = a.aout_g[0] * v / n;
        ws[OFF_BE + i]    = a.asrc_b[i] + a.adst_b[i] + a.asub_b[i] + a.amul_b[i];
        ws[OFF_BFIN + i]  = a.self_b[i] + a.neigh_b[i] + a.neigh2_b[i];
        if (i == 0) ws[OFF_BAOUT] = a.aout_b[0];
    }
}

// ---------------- bf16 conversions ----------------
__global__ __launch_bounds__(256) void convert_feat_kernel(const float* __restrict__ feat,
                                                           unsigned short* __restrict__ featbf) {
    int i = (blockIdx.x * 256 + threadIdx.x) * 8;
    float4 v0 = ((const float4*)feat)[i >> 2];
    float4 v1 = ((const float4*)feat)[(i >> 2) + 1];
    uint4 p;
    p.x = pk_bf16(v0.x, v0.y);
    p.y = pk_bf16(v0.z, v0.w);
    p.z = pk_bf16(v1.x, v1.y);
    p.w = pk_bf16(v1.z, v1.w);
    *(uint4*)&featbf[i] = p;
}

// all weight tables -> bf16; 832 blocks x 256
__global__ __launch_bounds__(256) void convert_weights_kernel(float* __restrict__ ws) {
    int idx = blockIdx.x * 256 + threadIdx.x;
    unsigned short* wnodebf = (unsigned short*)(ws + OFF_WNODEBF);
    unsigned short* wfinbf  = (unsigned short*)(ws + OFF_WFINBF);
    unsigned short* wmlpbf  = (unsigned short*)(ws + OFF_WMLPBF);
    unsigned short* wamulbf = (unsigned short*)(ws + OFF_WAMULBF);
    unsigned short* wedgebf = (unsigned short*)(ws + OFF_WEDGEBF);
    if (idx < 65536) {                 // node: [k 128][n 512] -> [n][k]
        int k = idx >> 9, n = idx & 511;
        wnodebf[n * 128 + k] = f2bf(ws[OFF_WT_NODE + k * 512 + n]);
    } else if (idx < 114688) {         // final: [k 384][o 128] -> [o][k]
        int i = idx - 65536, k = i >> 7, o = i & 127;
        wfinbf[o * 384 + k] = f2bf(ws[OFF_WT_FINAL + k * 128 + o]);
    } else if (idx < 147456) {         // mlp: 2 x [k 128][o 128] -> [o][k]
        int i = idx - 114688, l = i >> 14, j = i & 16383, k = j >> 7, o = j & 127;
        wmlpbf[l * 16384 + o * 128 + k] = f2bf(ws[OFF_WT_MLP + l * 16384 + k * 128 + o]);
    } else if (idx < 163840) {         // amul: [k 128][o 128] -> [o][k]
        int i = idx - 147456, k = i >> 7, o = i & 127;
        wamulbf[o * 128 + k] = f2bf(ws[OFF_WT_AMUL + k * 128 + o]);
    } else {
        // packed fused edge table: fragment id f = (t*3+slice)*4+kb; layout [f][lane 64][elem 8]
        // fragment (t,slice,kb,lane): B row o = t*16 + (lane&15), k = slice*128 + kb*32 + (lane>>4)*8 + elem
        // slice 0 = Wmul, slice 1 = Wsrc+Wsub, slice 2 = Wdst-Wsub
        int i = idx - 163840;              // [0, 49152)
        int elem = i & 7, f = i >> 3;
        int lane = f & 63, kb = (f >> 6) & 3, ts = f >> 8;   // ts in [0,24)
        int t = ts / 3, slice = ts - t * 3;
        int o = t * 16 + (lane & 15);
        int kk = kb * 32 + (lane >> 4) * 8 + elem;
        float v = (slice == 0) ? ws[OFF_WT_AMUL + kk * 128 + o]
                : (slice == 1) ? ws[OFF_WT_NODE + kk * 512 + o]
                               : ws[OFF_WT_NODE + kk * 512 + 128 + o];
        wedgebf[i] = f2bf(v);
    }
}

// ---------------- CSR-by-dst construction ----------------
__global__ __launch_bounds__(256) void hist_zero_kernel(float* __restrict__ ws) {
    int i = blockIdx.x * 256 + threadIdx.x;
    if (i < NN) ((int*)(ws + OFF_HIST))[i] = 0;
}

__global__ __launch_bounds__(256) void hist_kernel(const int* __restrict__ dst, float* __restrict__ ws) {
    int e = blockIdx.x * 256 + threadIdx.x;
    if (e < EE) atomicAdd(&((int*)(ws + OFF_HIST))[dst[e]], 1);
}

__global__ __launch_bounds__(1024) void scan_kernel(float* __restrict__ ws) {
    __shared__ int sp[1024];
    const int* hist = (const int*)(ws + OFF_HIST);
    int* starts = (int*)(ws + OFF_STARTS);
    int* cursor = (int*)(ws + OFF_CURSOR);
    int t = threadIdx.x;
    const int C = 49;
    int base = t * C;
    int local = 0;
    for (int j = 0; j < C; ++j) { int idx = base + j; if (idx < NN) local += hist[idx]; }
    sp[t] = local;
    __syncthreads();
    for (int o = 1; o < 1024; o <<= 1) {
        int v = (t >= o) ? sp[t - o] : 0;
        __syncthreads();
        sp[t] += v;
        __syncthreads();
    }
    int run = sp[t] - local;
    for (int j = 0; j < C; ++j) {
        int idx = base + j;
        if (idx < NN) { starts[idx] = run; cursor[idx] = run; run += hist[idx]; }
    }
    if (t == 0) starts[NN] = EE;
}

__global__ __launch_bounds__(256) void scatteridx_kernel(const int* __restrict__ src,
                                                         const int* __restrict__ dst,
                                                         float* __restrict__ ws) {
    int e = blockIdx.x * 256 + threadIdx.x;
    if (e >= EE) return;
    int d = dst[e];
    int pos = atomicAdd(&((int*)(ws + OFF_CURSOR))[d], 1);
    ((int2*)(ws + OFF_SSRCD))[pos] = make_int2(src[e], d);
}

// ---------------- segmented reduction -> neighbf bf16 [N][256] ----------------
__global__ __launch_bounds__(256) void segreduce_kernel(float* __restrict__ ws) {
    int n = blockIdx.x * 4 + (threadIdx.x >> 6);
    int lane = threadIdx.x & 63;
    const int* starts = (const int*)(ws + OFF_STARTS);
    const int2* ssrcd = (const int2*)(ws + OFF_SSRCD);
    const float* sev = ws + OFF_SEV;
    const unsigned short* hbf = (const unsigned short*)(ws + OFF_HBF);
    unsigned short* neighbf = (unsigned short*)(ws + OFF_NEIGHBF);
    int s0 = starts[n], s1 = starts[n + 1];
    float2 mx = make_float2(-INFINITY, -INFINITY);
    float2 sm = make_float2(0.f, 0.f);
    int i = s0;
    for (; i + 2 <= s1; i += 2) {
        int sA = ssrcd[i].x, sB = ssrcd[i + 1].x;
        float evA = sev[i], evB = sev[i + 1];
        unsigned hvA  = *(const unsigned*)&hbf[sA * 256 + lane * 2];
        unsigned h2vA = *(const unsigned*)&hbf[sA * 256 + 128 + lane * 2];
        unsigned hvB  = *(const unsigned*)&hbf[sB * 256 + lane * 2];
        unsigned h2vB = *(const unsigned*)&hbf[sB * 256 + 128 + lane * 2];
        mx.x = fmaxf(mx.x, evA * bf2f((unsigned short)(hvA & 0xffffu)));
        mx.y = fmaxf(mx.y, evA * bf2f((unsigned short)(hvA >> 16)));
        sm.x += evA * bf2f((unsigned short)(h2vA & 0xffffu));
        sm.y += evA * bf2f((unsigned short)(h2vA >> 16));
        mx.x = fmaxf(mx.x, evB * bf2f((unsigned short)(hvB & 0xffffu)));
        mx.y = fmaxf(mx.y, evB * bf2f((unsigned short)(hvB >> 16)));
        sm.x += evB * bf2f((unsigned short)(h2vB & 0xffffu));
        sm.y += evB * bf2f((unsigned short)(h2vB >> 16));
    }
    if (i < s1) {
        int s = ssrcd[i].x;
        float ev = sev[i];
        unsigned hv  = *(const unsigned*)&hbf[s * 256 + lane * 2];
        unsigned h2v = *(const unsigned*)&hbf[s * 256 + 128 + lane * 2];
        mx.x = fmaxf(mx.x, ev * bf2f((unsigned short)(hv & 0xffffu)));
        mx.y = fmaxf(mx.y, ev * bf2f((unsigned short)(hv >> 16)));
        sm.x += ev * bf2f((unsigned short)(h2v & 0xffffu));
        sm.y += ev * bf2f((unsigned short)(h2v >> 16));
    }
    int cnt = s1 - s0;
    if (cnt == 0) { mx.x = 0.f; mx.y = 0.f; }
    float ic = 1.0f / (float)max(cnt, 1);
    *(unsigned*)&neighbf[n * 256 + lane * 2] = pk_bf16(mx.x, mx.y);
    *(unsigned*)&neighbf[n * 256 + 128 + lane * 2] = pk_bf16(sm.x * ic, sm.y * ic);
}

// ---------------- node GEMM (MFMA): h / h2 only ----------------
__global__ __launch_bounds__(256) void gemm_node_mfma(const unsigned short* __restrict__ featbf,
                                                      const float* __restrict__ pool_b,
                                                      const float* __restrict__ pool2_b,
                                                      unsigned short* __restrict__ hbf,
                                                      const unsigned short* __restrict__ wnodebf) {
    __shared__ unsigned short As[64 * 136];
    int tid = threadIdx.x;
    int row0 = blockIdx.x * 64, gy = blockIdx.y;
    #pragma unroll
    for (int it = 0; it < 4; ++it) {
        int idx = tid + it * 256;
        int r = idx >> 4, u = idx & 15;
        int rr = min(row0 + r, NN - 1);
        *(uint4*)&As[r * 136 + u * 8] = *(const uint4*)&featbf[rr * 128 + u * 8];
    }
    __syncthreads();
    int lane = tid & 63, w = tid >> 6;
    int quad = lane >> 4, l15 = lane & 15;
    const unsigned short* B = wnodebf + (gy + 2) * 128 * 128;
    const float* bias = gy == 0 ? pool_b : pool2_b;
    f32x4 acc[8] = {};
    #pragma unroll 1
    for (int ks = 0; ks < 4; ++ks) {
        bf16x8 a = *(const bf16x8*)&As[(w * 16 + l15) * 136 + ks * 32 + quad * 8];
        #pragma unroll
        for (int t = 0; t < 8; ++t) {
            bf16x8 b = *(const bf16x8*)&B[(t * 16 + l15) * 128 + ks * 32 + quad * 8];
            acc[t] = __builtin_amdgcn_mfma_f32_16x16x32_bf16(a, b, acc[t], 0, 0, 0);
        }
    }
    #pragma unroll
    for (int reg = 0; reg < 4; ++reg) {
        int row = row0 + w * 16 + quad * 4 + reg;
        if (row >= NN) continue;
        #pragma unroll
        for (int t = 0; t < 8; ++t) {
            int col = t * 16 + l15;
            hbf[row * 256 + gy * 128 + col] = f2bf(gelu_f(acc[t][reg] + bias[col]));
        }
    }
}

// ---------------- edge GEMM: fused K=384 [fs*fd | fs | fd] @ packed B, LDS-free, barrier-free,
// 64 edges/wave (4 row-groups, 4x B-fragment reuse), 256 edges/block, coalesced B loads ----
__global__ __launch_bounds__(256, 2) void gemm_edge(const unsigned short* __restrict__ featbf,
                                                    const unsigned short* __restrict__ wedgebf,
                                                    float* __restrict__ ws) {
    int tid = threadIdx.x;
    int lane = tid & 63, w = tid >> 6;
    int quad = lane >> 4, l15 = lane & 15;
    int e0 = blockIdx.x * 256;
    const int2* ssrcd = (const int2*)(ws + OFF_SSRCD);
    int base = e0 + w * 64 + l15;                // wave handles edges [e0+w*64, +64)
    int2 i0 = ssrcd[base];
    int2 i1 = ssrcd[base + 16];
    int2 i2 = ssrcd[base + 32];
    int2 i3 = ssrcd[base + 48];
    const unsigned short* p0s = &featbf[i0.x * 128];
    const unsigned short* p0d = &featbf[i0.y * 128];
    const unsigned short* p1s = &featbf[i1.x * 128];
    const unsigned short* p1d = &featbf[i1.y * 128];
    const unsigned short* p2s = &featbf[i2.x * 128];
    const unsigned short* p2d = &featbf[i2.y * 128];
    const unsigned short* p3s = &featbf[i3.x * 128];
    const unsigned short* p3d = &featbf[i3.y * 128];
    int ko = quad * 8;
    f32x4 acc0[8] = {}, acc1[8] = {}, acc2[8] = {}, acc3[8] = {};
    #pragma unroll 1
    for (int kb = 0; kb < 4; ++kb) {
        int k = ko + kb * 32;
        uint4 c0s = *(const uint4*)&p0s[k];
        uint4 c0d = *(const uint4*)&p0d[k];
        uint4 c1s = *(const uint4*)&p1s[k];
        uint4 c1d = *(const uint4*)&p1d[k];
        uint4 c2s = *(const uint4*)&p2s[k];
        uint4 c2d = *(const uint4*)&p2d[k];
        uint4 c3s = *(const uint4*)&p3s[k];
        uint4 c3d = *(const uint4*)&p3d[k];
        uint4 m0, m1, m2, m3;                    // elementwise fs*fd (bf16)
        m0.x = mulpack(c0s.x, c0d.x); m0.y = mulpack(c0s.y, c0d.y);
        m0.z = mulpack(c0s.z, c0d.z); m0.w = mulpack(c0s.w, c0d.w);
        m1.x = mulpack(c1s.x, c1d.x); m1.y = mulpack(c1s.y, c1d.y);
        m1.z = mulpack(c1s.z, c1d.z); m1.w = mulpack(c1s.w, c1d.w);
        m2.x = mulpack(c2s.x, c2d.x); m2.y = mulpack(c2s.y, c2d.y);
        m2.z = mulpack(c2s.z, c2d.z); m2.w = mulpack(c2s.w, c2d.w);
        m3.x = mulpack(c3s.x, c3d.x); m3.y = mulpack(c3s.y, c3d.y);
        m3.z = mulpack(c3s.z, c3d.z); m3.w = mulpack(c3s.w, c3d.w);
        bf16x8 am0 = *(const bf16x8*)&m0,  am1 = *(const bf16x8*)&m1;
        bf16x8 am2 = *(const bf16x8*)&m2,  am3 = *(const bf16x8*)&m3;
        bf16x8 as0 = *(const bf16x8*)&c0s, ad0 = *(const bf16x8*)&c0d;
        bf16x8 as1 = *(const bf16x8*)&c1s, ad1 = *(const bf16x8*)&c1d;
        bf16x8 as2 = *(const bf16x8*)&c2s, ad2 = *(const bf16x8*)&c2d;
        bf16x8 as3 = *(const bf16x8*)&c3s, ad3 = *(const bf16x8*)&c3d;
        // packed B: fragment id f = (t*3+slice)*4+kb, frag at wedgebf[(f*64+lane)*8]
        const unsigned short* bbase = &wedgebf[(kb * 64 + lane) * 8];
        #pragma unroll
        for (int t = 0; t < 8; ++t) {
            bf16x8 bm = *(const bf16x8*)&bbase[(t * 3 + 0) * 2048];
            bf16x8 b1 = *(const bf16x8*)&bbase[(t * 3 + 1) * 2048];
            bf16x8 b2 = *(const bf16x8*)&bbase[(t * 3 + 2) * 2048];
            acc0[t] = __builtin_amdgcn_mfma_f32_16x16x32_bf16(am0, bm, acc0[t], 0, 0, 0);
            acc1[t] = __builtin_amdgcn_mfma_f32_16x16x32_bf16(am1, bm, acc1[t], 0, 0, 0);
            acc2[t] = __builtin_amdgcn_mfma_f32_16x16x32_bf16(am2, bm, acc2[t], 0, 0, 0);
            acc3[t] = __builtin_amdgcn_mfma_f32_16x16x32_bf16(am3, bm, acc3[t], 0, 0, 0);
            acc0[t] = __builtin_amdgcn_mfma_f32_16x16x32_bf16(as0, b1, acc0[t], 0, 0, 0);
            acc1[t] = __builtin_amdgcn_mfma_f32_16x16x32_bf16(as1, b1, acc1[t], 0, 0, 0);
            acc2[t] = __builtin_amdgcn_mfma_f32_16x16x32_bf16(as2, b1, acc2[t], 0, 0, 0);
            acc3[t] = __builtin_amdgcn_mfma_f32_16x16x32_bf16(as3, b1, acc3[t], 0, 0, 0);
            acc0[t] = __builtin_amdgcn_mfma_f32_16x16x32_bf16(ad0, b2, acc0[t], 0, 0, 0);
            acc1[t] = __builtin_amdgcn_mfma_f32_16x16x32_bf16(ad1, b2, acc1[t], 0, 0, 0);
            acc2[t] = __builtin_amdgcn_mfma_f32_16x16x32_bf16(ad2, b2, acc2[t], 0, 0, 0);
            acc3[t] = __builtin_amdgcn_mfma_f32_16x16x32_bf16(ad3, b2, acc3[t], 0, 0, 0);
        }
    }
    // epilogue: e = leaky(sum_col gelu(acc + be) * waout + b_aout)
    const float* waout = ws + OFF_WAOUT;
    const float* be = ws + OFF_BE;
    float b_aout = ws[OFF_BAOUT];
    float* e_out = ws + OFF_SEV;
    float wv[8], bv[8];
    #pragma unroll
    for (int t = 0; t < 8; ++t) { wv[t] = waout[t * 16 + l15]; bv[t] = be[t * 16 + l15]; }
    #pragma unroll
    for (int g = 0; g < 4; ++g) {
        #pragma unroll
        for (int reg = 0; reg < 4; ++reg) {
            int r = w * 64 + g * 16 + quad * 4 + reg;
            float partial = 0.0f;
            #pragma unroll
            for (int t = 0; t < 8; ++t) {
                float v = (g == 0 ? acc0[t][reg] : g == 1 ? acc1[t][reg]
                         : g == 2 ? acc2[t][reg] : acc3[t][reg]) + bv[t];
                partial += gelu_f(v) * wv[t];
            }
            partial += __shfl_xor(partial, 1, 16);
            partial += __shfl_xor(partial, 2, 16);
            partial += __shfl_xor(partial, 4, 16);
            partial += __shfl_xor(partial, 8, 16);
            if (l15 == 0) e_out[e0 + r] = leaky_f(partial + b_aout);
        }
    }
}

// ---------------- final GEMM (MFMA, K=384, single-stage LDS) -> out f32 ----------------
__global__ __launch_bounds__(256) void gemm_final_mfma(const unsigned short* __restrict__ neighbf,
                                                       const unsigned short* __restrict__ featbf,
                                                       const unsigned short* __restrict__ wfinbf,
                                                       float* __restrict__ out,
                                                       const float* __restrict__ ws) {
    __shared__ unsigned short As[64 * 392];   // 64 rows x 384 cols bf16 (+8 pad)
    __shared__ float bfin_s[128];
    int tid = threadIdx.x;
    int row0 = blockIdx.x * 64;
    if (tid < 128) bfin_s[tid] = ws[OFF_BFIN + tid];
    #pragma unroll
    for (int rg = 0; rg < 3; ++rg) {
        #pragma unroll
        for (int it = 0; it < 4; ++it) {
            int idx = tid + it * 256;
            int r = idx >> 4, u = idx & 15;
            int rr = min(row0 + r, NN - 1);
            const unsigned short* sp = (rg == 0) ? &neighbf[rr * 256 + u * 8]
                                     : (rg == 1) ? &neighbf[rr * 256 + 128 + u * 8]
                                                 : &featbf[rr * 128 + u * 8];
            *(uint4*)&As[r * 392 + rg * 128 + u * 8] = *(const uint4*)sp;
        }
    }
    __syncthreads();
    int lane = tid & 63, w = tid >> 6;
    int quad = lane >> 4, l15 = lane & 15;
    f32x4 acc[8] = {};
    #pragma unroll 1
    for (int ks = 0; ks < 12; ++ks) {
        bf16x8 a = *(const bf16x8*)&As[(w * 16 + l15) * 392 + ks * 32 + quad * 8];
        #pragma unroll
        for (int t = 0; t < 8; ++t) {
            bf16x8 b = *(const bf16x8*)&wfinbf[(t * 16 + l15) * 384 + ks * 32 + quad * 8];
            acc[t] = __builtin_amdgcn_mfma_f32_16x16x32_bf16(a, b, acc[t], 0, 0, 0);
        }
    }
    #pragma unroll
    for (int reg = 0; reg < 4; ++reg) {
        int row = row0 + w * 16 + quad * 4 + reg;
        if (row >= NN) continue;
        #pragma unroll
        for (int t = 0; t < 8; ++t) {
            int col = t * 16 + l15;
            out[row * 128 + col] = acc[t][reg] + bfin_s[col];
        }
    }
}

// ---------------- MLP layer (MFMA, in-place on out; block reads only its own rows) ----------------
__global__ __launch_bounds__(256) void gemm_mlp_mfma(float* __restrict__ out,
                                                     const unsigned short* __restrict__ wmlp,
                                                     const float* __restrict__ bias) {
    __shared__ unsigned short As[64 * 136];
    int tid = threadIdx.x;
    int row0 = blockIdx.x * 64;
    #pragma unroll
    for (int it = 0; it < 8; ++it) {
        int idx = tid + it * 256;            // 64 rows x 32 float4-units
        int r = idx >> 5, u = idx & 31;
        int rr = min(row0 + r, NN - 1);      // clamp stays within this block's rows
        float4 v = ((const float4*)out)[rr * 32 + u];
        unsigned p0 = pk_bf16(gelu_f(v.x), gelu_f(v.y));
        unsigned p1 = pk_bf16(gelu_f(v.z), gelu_f(v.w));
        *(unsigned*)&As[r * 136 + u * 4]     = p0;
        *(unsigned*)&As[r * 136 + u * 4 + 2] = p1;
    }
    __syncthreads();
    int lane = tid & 63, w = tid >> 6;
    int quad = lane >> 4, l15 = lane & 15;
    f32x4 acc[8] = {};
    #pragma unroll 1
    for (int ks = 0; ks < 4; ++ks) {
        bf16x8 a = *(const bf16x8*)&As[(w * 16 + l15) * 136 + ks * 32 + quad * 8];
        #pragma unroll
        for (int t = 0; t < 8; ++t) {
            bf16x8 b = *(const bf16x8*)&wmlp[(t * 16 + l15) * 128 + ks * 32 + quad * 8];
            acc[t] = __builtin_amdgcn_mfma_f32_16x16x32_bf16(a, b, acc[t], 0, 0, 0);
        }
    }
    #pragma unroll
    for (int reg = 0; reg < 4; ++reg) {
        int row = row0 + w * 16 + quad * 4 + reg;
        if (row >= NN) continue;
        #pragma unroll
        for (int t = 0; t < 8; ++t) {
            int col = t * 16 + l15;
            out[row * 128 + col] += acc[t][reg] + bias[col];
        }
    }
}

// ---------------- host launch ----------------
extern "C" void kernel_launch(void* const* d_in, const int* in_sizes, int n_in,
                              void* d_out, int out_size, void* d_ws, size_t ws_size,
                              hipStream_t stream) {
    const float* feat = (const float*)d_in[0];
    WnormArgs wa;
    wa.asrc_v = (const float*)d_in[1];  wa.asrc_g = (const float*)d_in[2];  wa.asrc_b = (const float*)d_in[3];
    wa.adst_v = (const float*)d_in[4];  wa.adst_g = (const float*)d_in[5];  wa.adst_b = (const float*)d_in[6];
    wa.asub_v = (const float*)d_in[7];  wa.asub_g = (const float*)d_in[8];  wa.asub_b = (const float*)d_in[9];
    wa.amul_v = (const float*)d_in[10]; wa.amul_g = (const float*)d_in[11]; wa.amul_b = (const float*)d_in[12];
    wa.aout_v = (const float*)d_in[13]; wa.aout_g = (const float*)d_in[14]; wa.aout_b = (const float*)d_in[15];
    wa.pool_v = (const float*)d_in[16]; wa.pool_g = (const float*)d_in[17]; wa.pool_b = (const float*)d_in[18];
    wa.pool2_v= (const float*)d_in[19]; wa.pool2_g= (const float*)d_in[20]; wa.pool2_b= (const float*)d_in[21];
    wa.self_v = (const float*)d_in[22]; wa.self_g = (const float*)d_in[23]; wa.self_b = (const float*)d_in[24];
    wa.neigh_v= (const float*)d_in[25]; wa.neigh_g= (const float*)d_in[26]; wa.neigh_b= (const float*)d_in[27];
    wa.neigh2_v=(const float*)d_in[28]; wa.neigh2_g=(const float*)d_in[29]; wa.neigh2_b=(const float*)d_in[30];
    wa.mlp_v  = (const float*)d_in[31]; wa.mlp_g  = (const float*)d_in[32]; wa.mlp_b  = (const float*)d_in[33];
    const int* src = (const int*)d_in[34];
    const int* dst = (const int*)d_in[35];
    float* out = (float*)d_out;
    float* ws = (float*)d_ws;
    wa.ws = ws;
    unsigned short* featbf  = (unsigned short*)(ws + OFF_FEATBF);
    unsigned short* hbf     = (unsigned short*)(ws + OFF_HBF);
    unsigned short* neighbf = (unsigned short*)(ws + OFF_NEIGHBF);
    unsigned short* wnodebf = (unsigned short*)(ws + OFF_WNODEBF);
    unsigned short* wfinbf  = (unsigned short*)(ws + OFF_WFINBF);
    unsigned short* wmlpbf  = (unsigned short*)(ws + OFF_WMLPBF);
    unsigned short* wedgebf = (unsigned short*)(ws + OFF_WEDGEBF);

    // 1) normalized weights + fused bias vectors
    wnorm_kernel<<<dim3(1281), dim3(128), 0, stream>>>(wa);
    // 2) bf16 conversions (incl. packed fused edge weight table)
    convert_feat_kernel<<<dim3(NN * 128 / (256 * 8)), dim3(256), 0, stream>>>(feat, featbf);
    convert_weights_kernel<<<dim3(832), dim3(256), 0, stream>>>(ws);
    // 3) CSR-by-dst
    hist_zero_kernel<<<dim3((NN + 255) / 256), dim3(256), 0, stream>>>(ws);
    hist_kernel<<<dim3((EE + 255) / 256), dim3(256), 0, stream>>>(dst, ws);
    scan_kernel<<<dim3(1), dim3(1024), 0, stream>>>(ws);
    scatteridx_kernel<<<dim3((EE + 255) / 256), dim3(256), 0, stream>>>(src, dst, ws);
    // 4) node-level GEMM (MFMA): h/h2 only (S fused into edge GEMM)
    gemm_node_mfma<<<dim3(782, 2), dim3(256), 0, stream>>>(featbf, wa.pool_b, wa.pool2_b, hbf, wnodebf);
    // 5) edge GEMM (fused K=384, 64 edges/wave, packed coalesced B) -> sev
    gemm_edge<<<dim3(EE / 256), dim3(256), 0, stream>>>(featbf, wedgebf, ws);
    // 6) segmented reduce -> neighbf (max zeroed | mean)
    segreduce_kernel<<<dim3(NN / 4), dim3(256), 0, stream>>>(ws);
    // 7) final GEMM (MFMA) -> out f32
    gemm_final_mfma<<<dim3(782), dim3(256), 0, stream>>>(neighbf, featbf, wfinbf, out, ws);
    // 8) two residual MLP layers (MFMA, in-place, block-self-contained rows)
    gemm_mlp_mfma<<<dim3(782), dim3(256), 0, stream>>>(out, wmlpbf, wa.mlp_b);
    gemm_mlp_mfma<<<dim3(782), dim3(256), 0, stream>>>(out, wmlpbf + 16384, wa.mlp_b + 128);
}

// Round 4
// 741.978 us; speedup vs baseline: 1.1622x; 1.0915x over previous
//
#include <hip/hip_runtime.h>
#include <hip/hip_bf16.h>
#include <math.h>

// ---------------- problem constants ----------------
constexpr int NN = 50000;   // nodes
constexpr int EE = 800000;  // edges

// ---------------- workspace layout (float offsets) ----------------
// f32 weights (written by wnorm)
constexpr int OFF_WT_NODE  = 0;        // [128][512] k-major: col groups 0:asrc+asub 1:adst-asub 2:pool 3:pool2
constexpr int OFF_WT_AMUL  = 65536;    // [128][128] k-major
constexpr int OFF_WT_FINAL = 81920;    // [384][128] k-major; k: 0-127 neigh, 128-255 neigh2, 256-383 self
constexpr int OFF_WT_MLP   = 131072;   // 2 x [128][128] k-major
constexpr int OFF_WAOUT    = 163840;   // [128]
constexpr int OFF_BE       = 163968;   // [128]
constexpr int OFF_BFIN     = 164096;   // [128]
constexpr int OFF_BAOUT    = 164224;   // [1] (pad 16)
// bf16 transposed weight tables ([o][k])
constexpr int OFF_WNODEBF  = 164240;               // 512*128 ushort = 32768 fl
constexpr int OFF_WFINBF   = OFF_WNODEBF + 32768;  // 128*384 ushort = 24576 fl
constexpr int OFF_WMLPBF   = OFF_WFINBF + 24576;   // 2*128*128 ushort = 16384 fl
constexpr int OFF_WAMULBF  = OFF_WMLPBF + 16384;   // 128*128 ushort = 8192 fl
// big arrays
constexpr int OFF_FEATBF   = OFF_WAMULBF + 8192;   // [N][128] bf16
constexpr int OFF_SBF      = OFF_FEATBF + NN*64;   // region reused: edge fused weight table
constexpr int OFF_WEDGEBF  = OFF_SBF;              // packed fragments: [(t*3+slice)*4+kb][lane 64][8] bf16
constexpr int OFF_HBF      = OFF_SBF + NN*128;     // [N][256] bf16 (h | h2)
constexpr int OFF_SEV      = OFF_HBF + NN*128;     // [E] f32, dst-sorted e
constexpr int OFF_NEIGHBF  = OFF_SEV + EE;         // [N][256] bf16 (neigh | neigh2)
constexpr int OFF_STARTS   = OFF_NEIGHBF + NN*128; // [N+1] int (+pad)
constexpr int OFF_HIST     = OFF_STARTS + NN + 8;  // [N] int
constexpr int OFF_CURSOR   = OFF_HIST + NN;        // [N] int
constexpr int OFF_SSRCD    = OFF_CURSOR + NN;      // [E] int2 (src,dst sorted by dst)

typedef __attribute__((ext_vector_type(8))) short bf16x8;
typedef __attribute__((ext_vector_type(4))) float f32x4;

// ---------------- device helpers ----------------
// fast GELU (tanh form via sigmoid), log2e folded into polynomial, rcp instead of div.
__device__ __forceinline__ float gelu_f(float x) {
    float x2 = x * x;
    float w = x * fmaf(-0.1029448f, x2, -2.3022082f);
    return x * __builtin_amdgcn_rcpf(1.0f + __builtin_amdgcn_exp2f(w));
}
__device__ __forceinline__ float leaky_f(float x) {
    return x > 0.0f ? x : 0.2f * x;
}
__device__ __forceinline__ unsigned short f2bf(float x) {
    unsigned u = __float_as_uint(x);
    return (unsigned short)((u + 0x7fffu + ((u >> 16) & 1u)) >> 16);
}
__device__ __forceinline__ float bf2f(unsigned short b) {
    return __uint_as_float(((unsigned)b) << 16);
}
__device__ __forceinline__ unsigned pk_bf16(float lo, float hi) {
    __hip_bfloat16 l = __float2bfloat16(lo);
    __hip_bfloat16 h = __float2bfloat16(hi);
    unsigned short lu = *reinterpret_cast<unsigned short*>(&l);
    unsigned short hu = *reinterpret_cast<unsigned short*>(&h);
    return (unsigned)lu | ((unsigned)hu << 16);
}
__device__ __forceinline__ unsigned mulpack(unsigned a, unsigned b) {
    float a0 = __uint_as_float(a << 16), a1 = __uint_as_float(a & 0xffff0000u);
    float b0 = __uint_as_float(b << 16), b1 = __uint_as_float(b & 0xffff0000u);
    return pk_bf16(a0 * b0, a1 * b1);
}
__device__ __forceinline__ float block_sum128(float v, float* sbuf) {
    #pragma unroll
    for (int o = 32; o > 0; o >>= 1) v += __shfl_down(v, o, 64);
    int lane = threadIdx.x & 63, w = threadIdx.x >> 6;
    if (lane == 0) sbuf[w] = v;
    __syncthreads();
    float r = sbuf[0] + sbuf[1];
    __syncthreads();
    return r;
}

// ---------------- weight normalization ----------------
struct WnormArgs {
    const float *asrc_v, *asrc_g, *asrc_b;
    const float *adst_v, *adst_g, *adst_b;
    const float *asub_v, *asub_g, *asub_b;
    const float *amul_v, *amul_g, *amul_b;
    const float *aout_v, *aout_g, *aout_b;
    const float *pool_v, *pool_g, *pool_b;
    const float *pool2_v, *pool2_g, *pool2_b;
    const float *self_v, *self_g, *self_b;
    const float *neigh_v, *neigh_g, *neigh_b;
    const float *neigh2_v, *neigh2_g, *neigh2_b;
    const float *mlp_v, *mlp_g, *mlp_b;
    float* ws;
};

__global__ __launch_bounds__(128) void wnorm_kernel(WnormArgs a) {
    __shared__ float sbuf[2];
    int bid = blockIdx.x, i = threadIdx.x;
    float* ws = a.ws;
    if (bid < 1280) {
        int o = bid & 127, grp = bid >> 7;
        const float *v1 = nullptr, *g1 = nullptr, *v2 = nullptr, *g2 = nullptr;
        float sgn2 = 1.0f; float* dst = nullptr; int stride = 0;
        switch (grp) {
            case 0: v1=a.asrc_v; g1=a.asrc_g; v2=a.asub_v; g2=a.asub_g; sgn2= 1.f; dst=ws+OFF_WT_NODE+o;        stride=512; break;
            case 1: v1=a.adst_v; g1=a.adst_g; v2=a.asub_v; g2=a.asub_g; sgn2=-1.f; dst=ws+OFF_WT_NODE+128+o;    stride=512; break;
            case 2: v1=a.pool_v;  g1=a.pool_g;  dst=ws+OFF_WT_NODE+256+o;          stride=512; break;
            case 3: v1=a.pool2_v; g1=a.pool2_g; dst=ws+OFF_WT_NODE+384+o;          stride=512; break;
            case 4: v1=a.amul_v;  g1=a.amul_g;  dst=ws+OFF_WT_AMUL+o;              stride=128; break;
            case 5: v1=a.neigh_v; g1=a.neigh_g; dst=ws+OFF_WT_FINAL+o;             stride=128; break;
            case 6: v1=a.neigh2_v;g1=a.neigh2_g;dst=ws+OFF_WT_FINAL+128*128+o;     stride=128; break;
            case 7: v1=a.self_v;  g1=a.self_g;  dst=ws+OFF_WT_FINAL+256*128+o;     stride=128; break;
            case 8: v1=a.mlp_v;        g1=a.mlp_g;     dst=ws+OFF_WT_MLP+o;        stride=128; break;
            case 9: v1=a.mlp_v+16384;  g1=a.mlp_g+128; dst=ws+OFF_WT_MLP+16384+o;  stride=128; break;
        }
        float x1 = v1[o*128 + i];
        float n1 = sqrtf(block_sum128(x1*x1, sbuf));
        float w = g1[o] * x1 / n1;
        if (v2) {
            float x2 = v2[o*128 + i];
            float n2 = sqrtf(block_sum128(x2*x2, sbuf));
            w += sgn2 * g2[o] * x2 / n2;
        }
        dst[i * stride] = w;
    } else {
        float v = a.aout_v[i];
        float n = sqrtf(block_sum128(v*v, sbuf));
        ws[OFF_WAOUT + i] = a.aout_g[0] * v / n;
        ws[OFF_BE + i]    = a.asrc_b[i] + a.adst_b[i] + a.asub_b[i] + a.amul_b[i];
        ws[OFF_BFIN + i]  = a.self_b[i] + a.neigh_b[i] + a.neigh2_b[i];
        if (i == 0) ws[OFF_BAOUT] = a.aout_b[0];
    }
}

// ---------------- bf16 conversions ----------------
__global__ __launch_bounds__(256) void convert_feat_kernel(const float* __restrict__ feat,
                                                           unsigned short* __restrict__ featbf) {
    int i = (blockIdx.x * 256 + threadIdx.x) * 8;
    float4 v0 = ((const float4*)feat)[i >> 2];
    float4 v1 = ((const float4*)feat)[(i >> 2) + 1];
    uint4 p;
    p.x = pk_bf16(v0.x, v0.y);
    p.y = pk_bf16(v0.z, v0.w);
    p.z = pk_bf16(v1.x, v1.y);
    p.w = pk_bf16(v1.z, v1.w);
    *(uint4*)&featbf[i] = p;
}

// all weight tables -> bf16; 832 blocks x 256
__global__ __launch_bounds__(256) void convert_weights_kernel(float* __restrict__ ws) {
    int idx = blockIdx.x * 256 + threadIdx.x;
    unsigned short* wnodebf = (unsigned short*)(ws + OFF_WNODEBF);
    unsigned short* wfinbf  = (unsigned short*)(ws + OFF_WFINBF);
    unsigned short* wmlpbf  = (unsigned short*)(ws + OFF_WMLPBF);
    unsigned short* wamulbf = (unsigned short*)(ws + OFF_WAMULBF);
    unsigned short* wedgebf = (unsigned short*)(ws + OFF_WEDGEBF);
    if (idx < 65536) {                 // node: [k 128][n 512] -> [n][k]
        int k = idx >> 9, n = idx & 511;
        wnodebf[n * 128 + k] = f2bf(ws[OFF_WT_NODE + k * 512 + n]);
    } else if (idx < 114688) {         // final: [k 384][o 128] -> [o][k]
        int i = idx - 65536, k = i >> 7, o = i & 127;
        wfinbf[o * 384 + k] = f2bf(ws[OFF_WT_FINAL + k * 128 + o]);
    } else if (idx < 147456) {         // mlp: 2 x [k 128][o 128] -> [o][k]
        int i = idx - 114688, l = i >> 14, j = i & 16383, k = j >> 7, o = j & 127;
        wmlpbf[l * 16384 + o * 128 + k] = f2bf(ws[OFF_WT_MLP + l * 16384 + k * 128 + o]);
    } else if (idx < 163840) {         // amul: [k 128][o 128] -> [o][k]
        int i = idx - 147456, k = i >> 7, o = i & 127;
        wamulbf[o * 128 + k] = f2bf(ws[OFF_WT_AMUL + k * 128 + o]);
    } else {
        // packed fused edge table: fragment id f = (t*3+slice)*4+kb; layout [f][lane 64][elem 8]
        // fragment (t,slice,kb,lane): B row o = t*16 + (lane&15), k = slice*128 + kb*32 + (lane>>4)*8 + elem
        // slice 0 = Wmul, slice 1 = Wsrc+Wsub, slice 2 = Wdst-Wsub
        int i = idx - 163840;              // [0, 49152)
        int elem = i & 7, f = i >> 3;
        int lane = f & 63, kb = (f >> 6) & 3, ts = f >> 8;   // ts in [0,24)
        int t = ts / 3, slice = ts - t * 3;
        int o = t * 16 + (lane & 15);
        int kk = kb * 32 + (lane >> 4) * 8 + elem;
        float v = (slice == 0) ? ws[OFF_WT_AMUL + kk * 128 + o]
                : (slice == 1) ? ws[OFF_WT_NODE + kk * 512 + o]
                               : ws[OFF_WT_NODE + kk * 512 + 128 + o];
        wedgebf[i] = f2bf(v);
    }
}

// ---------------- CSR-by-dst construction ----------------
__global__ __launch_bounds__(256) void hist_zero_kernel(float* __restrict__ ws) {
    int i = blockIdx.x * 256 + threadIdx.x;
    if (i < NN) ((int*)(ws + OFF_HIST))[i] = 0;
}

__global__ __launch_bounds__(256) void hist_kernel(const int* __restrict__ dst, float* __restrict__ ws) {
    int e = blockIdx.x * 256 + threadIdx.x;
    if (e < EE) atomicAdd(&((int*)(ws + OFF_HIST))[dst[e]], 1);
}

__global__ __launch_bounds__(1024) void scan_kernel(float* __restrict__ ws) {
    __shared__ int sp[1024];
    const int* hist = (const int*)(ws + OFF_HIST);
    int* starts = (int*)(ws + OFF_STARTS);
    int* cursor = (int*)(ws + OFF_CURSOR);
    int t = threadIdx.x;
    const int C = 49;
    int base = t * C;
    int local = 0;
    for (int j = 0; j < C; ++j) { int idx = base + j; if (idx < NN) local += hist[idx]; }
    sp[t] = local;
    __syncthreads();
    for (int o = 1; o < 1024; o <<= 1) {
        int v = (t >= o) ? sp[t - o] : 0;
        __syncthreads();
        sp[t] += v;
        __syncthreads();
    }
    int run = sp[t] - local;
    for (int j = 0; j < C; ++j) {
        int idx = base + j;
        if (idx < NN) { starts[idx] = run; cursor[idx] = run; run += hist[idx]; }
    }
    if (t == 0) starts[NN] = EE;
}

__global__ __launch_bounds__(256) void scatteridx_kernel(const int* __restrict__ src,
                                                         const int* __restrict__ dst,
                                                         float* __restrict__ ws) {
    int e = blockIdx.x * 256 + threadIdx.x;
    if (e >= EE) return;
    int d = dst[e];
    int pos = atomicAdd(&((int*)(ws + OFF_CURSOR))[d], 1);
    ((int2*)(ws + OFF_SSRCD))[pos] = make_int2(src[e], d);
}

// ---------------- segmented reduction -> neighbf bf16 [N][256] ----------------
__global__ __launch_bounds__(256) void segreduce_kernel(float* __restrict__ ws) {
    int n = blockIdx.x * 4 + (threadIdx.x >> 6);
    int lane = threadIdx.x & 63;
    const int* starts = (const int*)(ws + OFF_STARTS);
    const int2* ssrcd = (const int2*)(ws + OFF_SSRCD);
    const float* sev = ws + OFF_SEV;
    const unsigned short* hbf = (const unsigned short*)(ws + OFF_HBF);
    unsigned short* neighbf = (unsigned short*)(ws + OFF_NEIGHBF);
    int s0 = starts[n], s1 = starts[n + 1];
    float2 mx = make_float2(-INFINITY, -INFINITY);
    float2 sm = make_float2(0.f, 0.f);
    int i = s0;
    for (; i + 2 <= s1; i += 2) {
        int sA = ssrcd[i].x, sB = ssrcd[i + 1].x;
        float evA = sev[i], evB = sev[i + 1];
        unsigned hvA  = *(const unsigned*)&hbf[sA * 256 + lane * 2];
        unsigned h2vA = *(const unsigned*)&hbf[sA * 256 + 128 + lane * 2];
        unsigned hvB  = *(const unsigned*)&hbf[sB * 256 + lane * 2];
        unsigned h2vB = *(const unsigned*)&hbf[sB * 256 + 128 + lane * 2];
        mx.x = fmaxf(mx.x, evA * bf2f((unsigned short)(hvA & 0xffffu)));
        mx.y = fmaxf(mx.y, evA * bf2f((unsigned short)(hvA >> 16)));
        sm.x += evA * bf2f((unsigned short)(h2vA & 0xffffu));
        sm.y += evA * bf2f((unsigned short)(h2vA >> 16));
        mx.x = fmaxf(mx.x, evB * bf2f((unsigned short)(hvB & 0xffffu)));
        mx.y = fmaxf(mx.y, evB * bf2f((unsigned short)(hvB >> 16)));
        sm.x += evB * bf2f((unsigned short)(h2vB & 0xffffu));
        sm.y += evB * bf2f((unsigned short)(h2vB >> 16));
    }
    if (i < s1) {
        int s = ssrcd[i].x;
        float ev = sev[i];
        unsigned hv  = *(const unsigned*)&hbf[s * 256 + lane * 2];
        unsigned h2v = *(const unsigned*)&hbf[s * 256 + 128 + lane * 2];
        mx.x = fmaxf(mx.x, ev * bf2f((unsigned short)(hv & 0xffffu)));
        mx.y = fmaxf(mx.y, ev * bf2f((unsigned short)(hv >> 16)));
        sm.x += ev * bf2f((unsigned short)(h2v & 0xffffu));
        sm.y += ev * bf2f((unsigned short)(h2v >> 16));
    }
    int cnt = s1 - s0;
    if (cnt == 0) { mx.x = 0.f; mx.y = 0.f; }
    float ic = 1.0f / (float)max(cnt, 1);
    *(unsigned*)&neighbf[n * 256 + lane * 2] = pk_bf16(mx.x, mx.y);
    *(unsigned*)&neighbf[n * 256 + 128 + lane * 2] = pk_bf16(sm.x * ic, sm.y * ic);
}

// ---------------- node GEMM (MFMA): h / h2 only ----------------
__global__ __launch_bounds__(256) void gemm_node_mfma(const unsigned short* __restrict__ featbf,
                                                      const float* __restrict__ pool_b,
                                                      const float* __restrict__ pool2_b,
                                                      unsigned short* __restrict__ hbf,
                                                      const unsigned short* __restrict__ wnodebf) {
    __shared__ unsigned short As[64 * 136];
    int tid = threadIdx.x;
    int row0 = blockIdx.x * 64, gy = blockIdx.y;
    #pragma unroll
    for (int it = 0; it < 4; ++it) {
        int idx = tid + it * 256;
        int r = idx >> 4, u = idx & 15;
        int rr = min(row0 + r, NN - 1);
        *(uint4*)&As[r * 136 + u * 8] = *(const uint4*)&featbf[rr * 128 + u * 8];
    }
    __syncthreads();
    int lane = tid & 63, w = tid >> 6;
    int quad = lane >> 4, l15 = lane & 15;
    const unsigned short* B = wnodebf + (gy + 2) * 128 * 128;
    const float* bias = gy == 0 ? pool_b : pool2_b;
    f32x4 acc[8] = {};
    #pragma unroll 1
    for (int ks = 0; ks < 4; ++ks) {
        bf16x8 a = *(const bf16x8*)&As[(w * 16 + l15) * 136 + ks * 32 + quad * 8];
        #pragma unroll
        for (int t = 0; t < 8; ++t) {
            bf16x8 b = *(const bf16x8*)&B[(t * 16 + l15) * 128 + ks * 32 + quad * 8];
            acc[t] = __builtin_amdgcn_mfma_f32_16x16x32_bf16(a, b, acc[t], 0, 0, 0);
        }
    }
    #pragma unroll
    for (int reg = 0; reg < 4; ++reg) {
        int row = row0 + w * 16 + quad * 4 + reg;
        if (row >= NN) continue;
        #pragma unroll
        for (int t = 0; t < 8; ++t) {
            int col = t * 16 + l15;
            hbf[row * 256 + gy * 128 + col] = f2bf(gelu_f(acc[t][reg] + bias[col]));
        }
    }
}

// ---------------- edge GEMM: fused K=384 [fs*fd | fs | fd] @ packed B, LDS-free, barrier-free,
// 32 edges/wave (2 row-groups), 128 edges/block, A-prefetch depth 1, coalesced B, 3 waves/SIMD ----
__global__ __launch_bounds__(256, 3) void gemm_edge(const unsigned short* __restrict__ featbf,
                                                    const unsigned short* __restrict__ wedgebf,
                                                    float* __restrict__ ws) {
    int tid = threadIdx.x;
    int lane = tid & 63, w = tid >> 6;
    int quad = lane >> 4, l15 = lane & 15;
    int e0 = blockIdx.x * 128;
    const int2* ssrcd = (const int2*)(ws + OFF_SSRCD);
    int base = e0 + w * 32 + l15;                // wave handles edges [e0+w*32, +32)
    int2 i0 = ssrcd[base];
    int2 i1 = ssrcd[base + 16];
    const unsigned short* p0s = &featbf[i0.x * 128];
    const unsigned short* p0d = &featbf[i0.y * 128];
    const unsigned short* p1s = &featbf[i1.x * 128];
    const unsigned short* p1d = &featbf[i1.y * 128];
    int ko = quad * 8;
    uint4 c0s = *(const uint4*)&p0s[ko];
    uint4 c0d = *(const uint4*)&p0d[ko];
    uint4 c1s = *(const uint4*)&p1s[ko];
    uint4 c1d = *(const uint4*)&p1d[ko];
    f32x4 acc0[8] = {}, acc1[8] = {};
    #pragma unroll
    for (int kb = 0; kb < 4; ++kb) {
        uint4 n0s = c0s, n0d = c0d, n1s = c1s, n1d = c1d;
        if (kb < 3) {                            // prefetch next K-chunk of feat gathers
            int k2 = ko + (kb + 1) * 32;
            n0s = *(const uint4*)&p0s[k2];
            n0d = *(const uint4*)&p0d[k2];
            n1s = *(const uint4*)&p1s[k2];
            n1d = *(const uint4*)&p1d[k2];
        }
        uint4 m0, m1;                            // elementwise fs*fd (bf16)
        m0.x = mulpack(c0s.x, c0d.x); m0.y = mulpack(c0s.y, c0d.y);
        m0.z = mulpack(c0s.z, c0d.z); m0.w = mulpack(c0s.w, c0d.w);
        m1.x = mulpack(c1s.x, c1d.x); m1.y = mulpack(c1s.y, c1d.y);
        m1.z = mulpack(c1s.z, c1d.z); m1.w = mulpack(c1s.w, c1d.w);
        bf16x8 am0 = *(const bf16x8*)&m0,  am1 = *(const bf16x8*)&m1;
        bf16x8 as0 = *(const bf16x8*)&c0s, ad0 = *(const bf16x8*)&c0d;
        bf16x8 as1 = *(const bf16x8*)&c1s, ad1 = *(const bf16x8*)&c1d;
        // packed B: fragment id f = (t*3+slice)*4+kb, frag at wedgebf[(f*64+lane)*8]
        const unsigned short* bbase = &wedgebf[(kb * 64 + lane) * 8];
        #pragma unroll
        for (int t = 0; t < 8; ++t) {
            bf16x8 bm = *(const bf16x8*)&bbase[(t * 3 + 0) * 2048];
            bf16x8 b1 = *(const bf16x8*)&bbase[(t * 3 + 1) * 2048];
            bf16x8 b2 = *(const bf16x8*)&bbase[(t * 3 + 2) * 2048];
            acc0[t] = __builtin_amdgcn_mfma_f32_16x16x32_bf16(am0, bm, acc0[t], 0, 0, 0);
            acc1[t] = __builtin_amdgcn_mfma_f32_16x16x32_bf16(am1, bm, acc1[t], 0, 0, 0);
            acc0[t] = __builtin_amdgcn_mfma_f32_16x16x32_bf16(as0, b1, acc0[t], 0, 0, 0);
            acc1[t] = __builtin_amdgcn_mfma_f32_16x16x32_bf16(as1, b1, acc1[t], 0, 0, 0);
            acc0[t] = __builtin_amdgcn_mfma_f32_16x16x32_bf16(ad0, b2, acc0[t], 0, 0, 0);
            acc1[t] = __builtin_amdgcn_mfma_f32_16x16x32_bf16(ad1, b2, acc1[t], 0, 0, 0);
        }
        c0s = n0s; c0d = n0d; c1s = n1s; c1d = n1d;
    }
    // epilogue: e = leaky(sum_col gelu(acc + be) * waout + b_aout)
    const float* waout = ws + OFF_WAOUT;
    const float* be = ws + OFF_BE;
    float b_aout = ws[OFF_BAOUT];
    float* e_out = ws + OFF_SEV;
    float wv[8], bv[8];
    #pragma unroll
    for (int t = 0; t < 8; ++t) { wv[t] = waout[t * 16 + l15]; bv[t] = be[t * 16 + l15]; }
    #pragma unroll
    for (int g = 0; g < 2; ++g) {
        #pragma unroll
        for (int reg = 0; reg < 4; ++reg) {
            int r = w * 32 + g * 16 + quad * 4 + reg;
            float partial = 0.0f;
            #pragma unroll
            for (int t = 0; t < 8; ++t) {
                float v = (g ? acc1[t][reg] : acc0[t][reg]) + bv[t];
                partial += gelu_f(v) * wv[t];
            }
            partial += __shfl_xor(partial, 1, 16);
            partial += __shfl_xor(partial, 2, 16);
            partial += __shfl_xor(partial, 4, 16);
            partial += __shfl_xor(partial, 8, 16);
            if (l15 == 0) e_out[e0 + r] = leaky_f(partial + b_aout);
        }
    }
}

// ---------------- final GEMM (MFMA, K=384, single-stage LDS) -> out f32 ----------------
__global__ __launch_bounds__(256) void gemm_final_mfma(const unsigned short* __restrict__ neighbf,
                                                       const unsigned short* __restrict__ featbf,
                                                       const unsigned short* __restrict__ wfinbf,
                                                       float* __restrict__ out,
                                                       const float* __restrict__ ws) {
    __shared__ unsigned short As[64 * 392];   // 64 rows x 384 cols bf16 (+8 pad)
    __shared__ float bfin_s[128];
    int tid = threadIdx.x;
    int row0 = blockIdx.x * 64;
    if (tid < 128) bfin_s[tid] = ws[OFF_BFIN + tid];
    #pragma unroll
    for (int rg = 0; rg < 3; ++rg) {
        #pragma unroll
        for (int it = 0; it < 4; ++it) {
            int idx = tid + it * 256;
            int r = idx >> 4, u = idx & 15;
            int rr = min(row0 + r, NN - 1);
            const unsigned short* sp = (rg == 0) ? &neighbf[rr * 256 + u * 8]
                                     : (rg == 1) ? &neighbf[rr * 256 + 128 + u * 8]
                                                 : &featbf[rr * 128 + u * 8];
            *(uint4*)&As[r * 392 + rg * 128 + u * 8] = *(const uint4*)sp;
        }
    }
    __syncthreads();
    int lane = tid & 63, w = tid >> 6;
    int quad = lane >> 4, l15 = lane & 15;
    f32x4 acc[8] = {};
    #pragma unroll 1
    for (int ks = 0; ks < 12; ++ks) {
        bf16x8 a = *(const bf16x8*)&As[(w * 16 + l15) * 392 + ks * 32 + quad * 8];
        #pragma unroll
        for (int t = 0; t < 8; ++t) {
            bf16x8 b = *(const bf16x8*)&wfinbf[(t * 16 + l15) * 384 + ks * 32 + quad * 8];
            acc[t] = __builtin_amdgcn_mfma_f32_16x16x32_bf16(a, b, acc[t], 0, 0, 0);
        }
    }
    #pragma unroll
    for (int reg = 0; reg < 4; ++reg) {
        int row = row0 + w * 16 + quad * 4 + reg;
        if (row >= NN) continue;
        #pragma unroll
        for (int t = 0; t < 8; ++t) {
            int col = t * 16 + l15;
            out[row * 128 + col] = acc[t][reg] + bfin_s[col];
        }
    }
}

// ---------------- MLP layer (MFMA, in-place on out; block reads only its own rows) ----------------
__global__ __launch_bounds__(256) void gemm_mlp_mfma(float* __restrict__ out,
                                                     const unsigned short* __restrict__ wmlp,
                                                     const float* __restrict__ bias) {
    __shared__ unsigned short As[64 * 136];
    int tid = threadIdx.x;
    int row0 = blockIdx.x * 64;
    #pragma unroll
    for (int it = 0; it < 8; ++it) {
        int idx = tid + it * 256;            // 64 rows x 32 float4-units
        int r = idx >> 5, u = idx & 31;
        int rr = min(row0 + r, NN - 1);      // clamp stays within this block's rows
        float4 v = ((const float4*)out)[rr * 32 + u];
        unsigned p0 = pk_bf16(gelu_f(v.x), gelu_f(v.y));
        unsigned p1 = pk_bf16(gelu_f(v.z), gelu_f(v.w));
        *(unsigned*)&As[r * 136 + u * 4]     = p0;
        *(unsigned*)&As[r * 136 + u * 4 + 2] = p1;
    }
    __syncthreads();
    int lane = tid & 63, w = tid >> 6;
    int quad = lane >> 4, l15 = lane & 15;
    f32x4 acc[8] = {};
    #pragma unroll 1
    for (int ks = 0; ks < 4; ++ks) {
        bf16x8 a = *(const bf16x8*)&As[(w * 16 + l15) * 136 + ks * 32 + quad * 8];
        #pragma unroll
        for (int t = 0; t < 8; ++t) {
            bf16x8 b = *(const bf16x8*)&wmlp[(t * 16 + l15) * 128 + ks * 32 + quad * 8];
            acc[t] = __builtin_amdgcn_mfma_f32_16x16x32_bf16(a, b, acc[t], 0, 0, 0);
        }
    }
    #pragma unroll
    for (int reg = 0; reg < 4; ++reg) {
        int row = row0 + w * 16 + quad * 4 + reg;
        if (row >= NN) continue;
        #pragma unroll
        for (int t = 0; t < 8; ++t) {
            int col = t * 16 + l15;
            out[row * 128 + col] += acc[t][reg] + bias[col];
        }
    }
}

// ---------------- host launch ----------------
extern "C" void kernel_launch(void* const* d_in, const int* in_sizes, int n_in,
                              void* d_out, int out_size, void* d_ws, size_t ws_size,
                              hipStream_t stream) {
    const float* feat = (const float*)d_in[0];
    WnormArgs wa;
    wa.asrc_v = (const float*)d_in[1];  wa.asrc_g = (const float*)d_in[2];  wa.asrc_b = (const float*)d_in[3];
    wa.adst_v = (const float*)d_in[4];  wa.adst_g = (const float*)d_in[5];  wa.adst_b = (const float*)d_in[6];
    wa.asub_v = (const float*)d_in[7];  wa.asub_g = (const float*)d_in[8];  wa.asub_b = (const float*)d_in[9];
    wa.amul_v = (const float*)d_in[10]; wa.amul_g = (const float*)d_in[11]; wa.amul_b = (const float*)d_in[12];
    wa.aout_v = (const float*)d_in[13]; wa.aout_g = (const float*)d_in[14]; wa.aout_b = (const float*)d_in[15];
    wa.pool_v = (const float*)d_in[16]; wa.pool_g = (const float*)d_in[17]; wa.pool_b = (const float*)d_in[18];
    wa.pool2_v= (const float*)d_in[19]; wa.pool2_g= (const float*)d_in[20]; wa.pool2_b= (const float*)d_in[21];
    wa.self_v = (const float*)d_in[22]; wa.self_g = (const float*)d_in[23]; wa.self_b = (const float*)d_in[24];
    wa.neigh_v= (const float*)d_in[25]; wa.neigh_g= (const float*)d_in[26]; wa.neigh_b= (const float*)d_in[27];
    wa.neigh2_v=(const float*)d_in[28]; wa.neigh2_g=(const float*)d_in[29]; wa.neigh2_b=(const float*)d_in[30];
    wa.mlp_v  = (const float*)d_in[31]; wa.mlp_g  = (const float*)d_in[32]; wa.mlp_b  = (const float*)d_in[33];
    const int* src = (const int*)d_in[34];
    const int* dst = (const int*)d_in[35];
    float* out = (float*)d_out;
    float* ws = (float*)d_ws;
    wa.ws = ws;
    unsigned short* featbf  = (unsigned short*)(ws + OFF_FEATBF);
    unsigned short* hbf     = (unsigned short*)(ws + OFF_HBF);
    unsigned short* neighbf = (unsigned short*)(ws + OFF_NEIGHBF);
    unsigned short* wnodebf = (unsigned short*)(ws + OFF_WNODEBF);
    unsigned short* wfinbf  = (unsigned short*)(ws + OFF_WFINBF);
    unsigned short* wmlpbf  = (unsigned short*)(ws + OFF_WMLPBF);
    unsigned short* wedgebf = (unsigned short*)(ws + OFF_WEDGEBF);

    // 1) normalized weights + fused bias vectors
    wnorm_kernel<<<dim3(1281), dim3(128), 0, stream>>>(wa);
    // 2) bf16 conversions (incl. packed fused edge weight table)
    convert_feat_kernel<<<dim3(NN * 128 / (256 * 8)), dim3(256), 0, stream>>>(feat, featbf);
    convert_weights_kernel<<<dim3(832), dim3(256), 0, stream>>>(ws);
    // 3) CSR-by-dst
    hist_zero_kernel<<<dim3((NN + 255) / 256), dim3(256), 0, stream>>>(ws);
    hist_kernel<<<dim3((EE + 255) / 256), dim3(256), 0, stream>>>(dst, ws);
    scan_kernel<<<dim3(1), dim3(1024), 0, stream>>>(ws);
    scatteridx_kernel<<<dim3((EE + 255) / 256), dim3(256), 0, stream>>>(src, dst, ws);
    // 4) node-level GEMM (MFMA): h/h2 only (S fused into edge GEMM)
    gemm_node_mfma<<<dim3(782, 2), dim3(256), 0, stream>>>(featbf, wa.pool_b, wa.pool2_b, hbf, wnodebf);
    // 5) edge GEMM (fused K=384, 32 edges/wave, prefetch, packed coalesced B) -> sev
    gemm_edge<<<dim3(EE / 128), dim3(256), 0, stream>>>(featbf, wedgebf, ws);
    // 6) segmented reduce -> neighbf (max zeroed | mean)
    segreduce_kernel<<<dim3(NN / 4), dim3(256), 0, stream>>>(ws);
    // 7) final GEMM (MFMA) -> out f32
    gemm_final_mfma<<<dim3(782), dim3(256), 0, stream>>>(neighbf, featbf, wfinbf, out, ws);
    // 8) two residual MLP layers (MFMA, in-place, block-self-contained rows)
    gemm_mlp_mfma<<<dim3(782), dim3(256), 0, stream>>>(out, wmlpbf, wa.mlp_b);
    gemm_mlp_mfma<<<dim3(782), dim3(256), 0, stream>>>(out, wmlpbf + 16384, wa.mlp_b + 128);
}

// Round 5
// 660.573 us; speedup vs baseline: 1.3054x; 1.1232x over previous
//
#include <hip/hip_runtime.h>
#include <hip/hip_bf16.h>
#include <math.h>

// ---------------- problem constants ----------------
constexpr int NN = 50000;   // nodes
constexpr int EE = 800000;  // edges

// ---------------- workspace layout (float offsets) ----------------
// f32 weights (written by wnorm)
constexpr int OFF_WT_NODE  = 0;        // [128][512] k-major: col groups 0:asrc+asub 1:adst-asub 2:pool 3:pool2
constexpr int OFF_WT_AMUL  = 65536;    // [128][128] k-major
constexpr int OFF_WT_FINAL = 81920;    // [384][128] k-major; k: 0-127 neigh, 128-255 neigh2, 256-383 self
constexpr int OFF_WT_MLP   = 131072;   // 2 x [128][128] k-major
constexpr int OFF_WAOUT    = 163840;   // [128]
constexpr int OFF_BE       = 163968;   // [128]
constexpr int OFF_BFIN     = 164096;   // [128]
constexpr int OFF_BAOUT    = 164224;   // [1] (pad 16)
// bf16 transposed weight tables ([o][k])
constexpr int OFF_WNODEBF  = 164240;               // 512*128 ushort = 32768 fl
constexpr int OFF_WFINBF   = OFF_WNODEBF + 32768;  // 128*384 ushort = 24576 fl
constexpr int OFF_WMLPBF   = OFF_WFINBF + 24576;   // 2*128*128 ushort = 16384 fl
constexpr int OFF_WAMULBF  = OFF_WMLPBF + 16384;   // 128*128 ushort = 8192 fl
// big arrays
constexpr int OFF_FEATBF   = OFF_WAMULBF + 8192;   // [N][128] bf16
constexpr int OFF_SBF      = OFF_FEATBF + NN*64;   // region reused: edge fused weight table
constexpr int OFF_WEDGEBF  = OFF_SBF;              // packed fragments: [(t*3+slice)*4+kb][lane 64][8] bf16
constexpr int OFF_HBF      = OFF_SBF + NN*128;     // [N][256] bf16 (h | h2)
constexpr int OFF_SEV      = OFF_HBF + NN*128;     // [E] f32, dst-sorted e
constexpr int OFF_NEIGHBF  = OFF_SEV + EE;         // [N][256] bf16 (neigh | neigh2)
constexpr int OFF_STARTS   = OFF_NEIGHBF + NN*128; // [N+1] int (+pad)
constexpr int OFF_HIST     = OFF_STARTS + NN + 8;  // [N] int
constexpr int OFF_CURSOR   = OFF_HIST + NN;        // [N] int
constexpr int OFF_SSRCD    = OFF_CURSOR + NN;      // [E] int2 (src,dst sorted by dst)

typedef __attribute__((ext_vector_type(8))) short bf16x8;
typedef __attribute__((ext_vector_type(4))) float f32x4;

// ---------------- device helpers ----------------
// fast GELU (tanh form via sigmoid), log2e folded into polynomial, rcp instead of div.
__device__ __forceinline__ float gelu_f(float x) {
    float x2 = x * x;
    float w = x * fmaf(-0.1029448f, x2, -2.3022082f);
    return x * __builtin_amdgcn_rcpf(1.0f + __builtin_amdgcn_exp2f(w));
}
__device__ __forceinline__ float leaky_f(float x) {
    return x > 0.0f ? x : 0.2f * x;
}
__device__ __forceinline__ unsigned short f2bf(float x) {
    unsigned u = __float_as_uint(x);
    return (unsigned short)((u + 0x7fffu + ((u >> 16) & 1u)) >> 16);
}
__device__ __forceinline__ float bf2f(unsigned short b) {
    return __uint_as_float(((unsigned)b) << 16);
}
__device__ __forceinline__ unsigned pk_bf16(float lo, float hi) {
    __hip_bfloat16 l = __float2bfloat16(lo);
    __hip_bfloat16 h = __float2bfloat16(hi);
    unsigned short lu = *reinterpret_cast<unsigned short*>(&l);
    unsigned short hu = *reinterpret_cast<unsigned short*>(&h);
    return (unsigned)lu | ((unsigned)hu << 16);
}
__device__ __forceinline__ unsigned mulpack(unsigned a, unsigned b) {
    float a0 = __uint_as_float(a << 16), a1 = __uint_as_float(a & 0xffff0000u);
    float b0 = __uint_as_float(b << 16), b1 = __uint_as_float(b & 0xffff0000u);
    return pk_bf16(a0 * b0, a1 * b1);
}
__device__ __forceinline__ float block_sum128(float v, float* sbuf) {
    #pragma unroll
    for (int o = 32; o > 0; o >>= 1) v += __shfl_down(v, o, 64);
    int lane = threadIdx.x & 63, w = threadIdx.x >> 6;
    if (lane == 0) sbuf[w] = v;
    __syncthreads();
    float r = sbuf[0] + sbuf[1];
    __syncthreads();
    return r;
}

// ---------------- weight normalization ----------------
struct WnormArgs {
    const float *asrc_v, *asrc_g, *asrc_b;
    const float *adst_v, *adst_g, *adst_b;
    const float *asub_v, *asub_g, *asub_b;
    const float *amul_v, *amul_g, *amul_b;
    const float *aout_v, *aout_g, *aout_b;
    const float *pool_v, *pool_g, *pool_b;
    const float *pool2_v, *pool2_g, *pool2_b;
    const float *self_v, *self_g, *self_b;
    const float *neigh_v, *neigh_g, *neigh_b;
    const float *neigh2_v, *neigh2_g, *neigh2_b;
    const float *mlp_v, *mlp_g, *mlp_b;
    float* ws;
};

__global__ __launch_bounds__(128) void wnorm_kernel(WnormArgs a) {
    __shared__ float sbuf[2];
    int bid = blockIdx.x, i = threadIdx.x;
    float* ws = a.ws;
    if (bid < 1280) {
        int o = bid & 127, grp = bid >> 7;
        const float *v1 = nullptr, *g1 = nullptr, *v2 = nullptr, *g2 = nullptr;
        float sgn2 = 1.0f; float* dst = nullptr; int stride = 0;
        switch (grp) {
            case 0: v1=a.asrc_v; g1=a.asrc_g; v2=a.asub_v; g2=a.asub_g; sgn2= 1.f; dst=ws+OFF_WT_NODE+o;        stride=512; break;
            case 1: v1=a.adst_v; g1=a.adst_g; v2=a.asub_v; g2=a.asub_g; sgn2=-1.f; dst=ws+OFF_WT_NODE+128+o;    stride=512; break;
            case 2: v1=a.pool_v;  g1=a.pool_g;  dst=ws+OFF_WT_NODE+256+o;          stride=512; break;
            case 3: v1=a.pool2_v; g1=a.pool2_g; dst=ws+OFF_WT_NODE+384+o;          stride=512; break;
            case 4: v1=a.amul_v;  g1=a.amul_g;  dst=ws+OFF_WT_AMUL+o;              stride=128; break;
            case 5: v1=a.neigh_v; g1=a.neigh_g; dst=ws+OFF_WT_FINAL+o;             stride=128; break;
            case 6: v1=a.neigh2_v;g1=a.neigh2_g;dst=ws+OFF_WT_FINAL+128*128+o;     stride=128; break;
            case 7: v1=a.self_v;  g1=a.self_g;  dst=ws+OFF_WT_FINAL+256*128+o;     stride=128; break;
            case 8: v1=a.mlp_v;        g1=a.mlp_g;     dst=ws+OFF_WT_MLP+o;        stride=128; break;
            case 9: v1=a.mlp_v+16384;  g1=a.mlp_g+128; dst=ws+OFF_WT_MLP+16384+o;  stride=128; break;
        }
        float x1 = v1[o*128 + i];
        float n1 = sqrtf(block_sum128(x1*x1, sbuf));
        float w = g1[o] * x1 / n1;
        if (v2) {
            float x2 = v2[o*128 + i];
            float n2 = sqrtf(block_sum128(x2*x2, sbuf));
            w += sgn2 * g2[o] * x2 / n2;
        }
        dst[i * stride] = w;
    } else {
        float v = a.aout_v[i];
        float n = sqrtf(block_sum128(v*v, sbuf));
        ws[OFF_WAOUT + i] = a.aout_g[0] * v / n;
        ws[OFF_BE + i]    = a.asrc_b[i] + a.adst_b[i] + a.asub_b[i] + a.amul_b[i];
        ws[OFF_BFIN + i]  = a.self_b[i] + a.neigh_b[i] + a.neigh2_b[i];
        if (i == 0) ws[OFF_BAOUT] = a.aout_b[0];
    }
}

// ---------------- bf16 conversions ----------------
__global__ __launch_bounds__(256) void convert_feat_kernel(const float* __restrict__ feat,
                                                           unsigned short* __restrict__ featbf) {
    int i = (blockIdx.x * 256 + threadIdx.x) * 8;
    float4 v0 = ((const float4*)feat)[i >> 2];
    float4 v1 = ((const float4*)feat)[(i >> 2) + 1];
    uint4 p;
    p.x = pk_bf16(v0.x, v0.y);
    p.y = pk_bf16(v0.z, v0.w);
    p.z = pk_bf16(v1.x, v1.y);
    p.w = pk_bf16(v1.z, v1.w);
    *(uint4*)&featbf[i] = p;
}

// all weight tables -> bf16; 832 blocks x 256
__global__ __launch_bounds__(256) void convert_weights_kernel(float* __restrict__ ws) {
    int idx = blockIdx.x * 256 + threadIdx.x;
    unsigned short* wnodebf = (unsigned short*)(ws + OFF_WNODEBF);
    unsigned short* wfinbf  = (unsigned short*)(ws + OFF_WFINBF);
    unsigned short* wmlpbf  = (unsigned short*)(ws + OFF_WMLPBF);
    unsigned short* wamulbf = (unsigned short*)(ws + OFF_WAMULBF);
    unsigned short* wedgebf = (unsigned short*)(ws + OFF_WEDGEBF);
    if (idx < 65536) {                 // node: [k 128][n 512] -> [n][k]
        int k = idx >> 9, n = idx & 511;
        wnodebf[n * 128 + k] = f2bf(ws[OFF_WT_NODE + k * 512 + n]);
    } else if (idx < 114688) {         // final: [k 384][o 128] -> [o][k]
        int i = idx - 65536, k = i >> 7, o = i & 127;
        wfinbf[o * 384 + k] = f2bf(ws[OFF_WT_FINAL + k * 128 + o]);
    } else if (idx < 147456) {         // mlp: 2 x [k 128][o 128] -> [o][k]
        int i = idx - 114688, l = i >> 14, j = i & 16383, k = j >> 7, o = j & 127;
        wmlpbf[l * 16384 + o * 128 + k] = f2bf(ws[OFF_WT_MLP + l * 16384 + k * 128 + o]);
    } else if (idx < 163840) {         // amul: [k 128][o 128] -> [o][k]
        int i = idx - 147456, k = i >> 7, o = i & 127;
        wamulbf[o * 128 + k] = f2bf(ws[OFF_WT_AMUL + k * 128 + o]);
    } else {
        // packed fused edge table: fragment id f = (t*3+slice)*4+kb; layout [f][lane 64][elem 8]
        // fragment (t,slice,kb,lane): B row o = t*16 + (lane&15), k = slice*128 + kb*32 + (lane>>4)*8 + elem
        // slice 0 = Wmul, slice 1 = Wsrc+Wsub, slice 2 = Wdst-Wsub
        int i = idx - 163840;              // [0, 49152)
        int elem = i & 7, f = i >> 3;
        int lane = f & 63, kb = (f >> 6) & 3, ts = f >> 8;   // ts in [0,24)
        int t = ts / 3, slice = ts - t * 3;
        int o = t * 16 + (lane & 15);
        int kk = kb * 32 + (lane >> 4) * 8 + elem;
        float v = (slice == 0) ? ws[OFF_WT_AMUL + kk * 128 + o]
                : (slice == 1) ? ws[OFF_WT_NODE + kk * 512 + o]
                               : ws[OFF_WT_NODE + kk * 512 + 128 + o];
        wedgebf[i] = f2bf(v);
    }
}

// ---------------- CSR-by-dst construction ----------------
__global__ __launch_bounds__(256) void hist_zero_kernel(float* __restrict__ ws) {
    int i = blockIdx.x * 256 + threadIdx.x;
    if (i < NN) ((int*)(ws + OFF_HIST))[i] = 0;
}

__global__ __launch_bounds__(256) void hist_kernel(const int* __restrict__ dst, float* __restrict__ ws) {
    int e = blockIdx.x * 256 + threadIdx.x;
    if (e < EE) atomicAdd(&((int*)(ws + OFF_HIST))[dst[e]], 1);
}

__global__ __launch_bounds__(1024) void scan_kernel(float* __restrict__ ws) {
    __shared__ int sp[1024];
    const int* hist = (const int*)(ws + OFF_HIST);
    int* starts = (int*)(ws + OFF_STARTS);
    int* cursor = (int*)(ws + OFF_CURSOR);
    int t = threadIdx.x;
    const int C = 49;
    int base = t * C;
    int local = 0;
    for (int j = 0; j < C; ++j) { int idx = base + j; if (idx < NN) local += hist[idx]; }
    sp[t] = local;
    __syncthreads();
    for (int o = 1; o < 1024; o <<= 1) {
        int v = (t >= o) ? sp[t - o] : 0;
        __syncthreads();
        sp[t] += v;
        __syncthreads();
    }
    int run = sp[t] - local;
    for (int j = 0; j < C; ++j) {
        int idx = base + j;
        if (idx < NN) { starts[idx] = run; cursor[idx] = run; run += hist[idx]; }
    }
    if (t == 0) starts[NN] = EE;
}

__global__ __launch_bounds__(256) void scatteridx_kernel(const int* __restrict__ src,
                                                         const int* __restrict__ dst,
                                                         float* __restrict__ ws) {
    int e = blockIdx.x * 256 + threadIdx.x;
    if (e >= EE) return;
    int d = dst[e];
    int pos = atomicAdd(&((int*)(ws + OFF_CURSOR))[d], 1);
    ((int2*)(ws + OFF_SSRCD))[pos] = make_int2(src[e], d);
}

// ---------------- segmented reduction -> neighbf bf16 [N][256] ----------------
__global__ __launch_bounds__(256) void segreduce_kernel(float* __restrict__ ws) {
    int n = blockIdx.x * 4 + (threadIdx.x >> 6);
    int lane = threadIdx.x & 63;
    const int* starts = (const int*)(ws + OFF_STARTS);
    const int2* ssrcd = (const int2*)(ws + OFF_SSRCD);
    const float* sev = ws + OFF_SEV;
    const unsigned short* hbf = (const unsigned short*)(ws + OFF_HBF);
    unsigned short* neighbf = (unsigned short*)(ws + OFF_NEIGHBF);
    int s0 = starts[n], s1 = starts[n + 1];
    float2 mx = make_float2(-INFINITY, -INFINITY);
    float2 sm = make_float2(0.f, 0.f);
    int i = s0;
    for (; i + 2 <= s1; i += 2) {
        int sA = ssrcd[i].x, sB = ssrcd[i + 1].x;
        float evA = sev[i], evB = sev[i + 1];
        unsigned hvA  = *(const unsigned*)&hbf[sA * 256 + lane * 2];
        unsigned h2vA = *(const unsigned*)&hbf[sA * 256 + 128 + lane * 2];
        unsigned hvB  = *(const unsigned*)&hbf[sB * 256 + lane * 2];
        unsigned h2vB = *(const unsigned*)&hbf[sB * 256 + 128 + lane * 2];
        mx.x = fmaxf(mx.x, evA * bf2f((unsigned short)(hvA & 0xffffu)));
        mx.y = fmaxf(mx.y, evA * bf2f((unsigned short)(hvA >> 16)));
        sm.x += evA * bf2f((unsigned short)(h2vA & 0xffffu));
        sm.y += evA * bf2f((unsigned short)(h2vA >> 16));
        mx.x = fmaxf(mx.x, evB * bf2f((unsigned short)(hvB & 0xffffu)));
        mx.y = fmaxf(mx.y, evB * bf2f((unsigned short)(hvB >> 16)));
        sm.x += evB * bf2f((unsigned short)(h2vB & 0xffffu));
        sm.y += evB * bf2f((unsigned short)(h2vB >> 16));
    }
    if (i < s1) {
        int s = ssrcd[i].x;
        float ev = sev[i];
        unsigned hv  = *(const unsigned*)&hbf[s * 256 + lane * 2];
        unsigned h2v = *(const unsigned*)&hbf[s * 256 + 128 + lane * 2];
        mx.x = fmaxf(mx.x, ev * bf2f((unsigned short)(hv & 0xffffu)));
        mx.y = fmaxf(mx.y, ev * bf2f((unsigned short)(hv >> 16)));
        sm.x += ev * bf2f((unsigned short)(h2v & 0xffffu));
        sm.y += ev * bf2f((unsigned short)(h2v >> 16));
    }
    int cnt = s1 - s0;
    if (cnt == 0) { mx.x = 0.f; mx.y = 0.f; }
    float ic = 1.0f / (float)max(cnt, 1);
    *(unsigned*)&neighbf[n * 256 + lane * 2] = pk_bf16(mx.x, mx.y);
    *(unsigned*)&neighbf[n * 256 + 128 + lane * 2] = pk_bf16(sm.x * ic, sm.y * ic);
}

// ---------------- node GEMM (MFMA): h / h2 only ----------------
__global__ __launch_bounds__(256) void gemm_node_mfma(const unsigned short* __restrict__ featbf,
                                                      const float* __restrict__ pool_b,
                                                      const float* __restrict__ pool2_b,
                                                      unsigned short* __restrict__ hbf,
                                                      const unsigned short* __restrict__ wnodebf) {
    __shared__ unsigned short As[64 * 136];
    int tid = threadIdx.x;
    int row0 = blockIdx.x * 64, gy = blockIdx.y;
    #pragma unroll
    for (int it = 0; it < 4; ++it) {
        int idx = tid + it * 256;
        int r = idx >> 4, u = idx & 15;
        int rr = min(row0 + r, NN - 1);
        *(uint4*)&As[r * 136 + u * 8] = *(const uint4*)&featbf[rr * 128 + u * 8];
    }
    __syncthreads();
    int lane = tid & 63, w = tid >> 6;
    int quad = lane >> 4, l15 = lane & 15;
    const unsigned short* B = wnodebf + (gy + 2) * 128 * 128;
    const float* bias = gy == 0 ? pool_b : pool2_b;
    f32x4 acc[8] = {};
    #pragma unroll 1
    for (int ks = 0; ks < 4; ++ks) {
        bf16x8 a = *(const bf16x8*)&As[(w * 16 + l15) * 136 + ks * 32 + quad * 8];
        #pragma unroll
        for (int t = 0; t < 8; ++t) {
            bf16x8 b = *(const bf16x8*)&B[(t * 16 + l15) * 128 + ks * 32 + quad * 8];
            acc[t] = __builtin_amdgcn_mfma_f32_16x16x32_bf16(a, b, acc[t], 0, 0, 0);
        }
    }
    #pragma unroll
    for (int reg = 0; reg < 4; ++reg) {
        int row = row0 + w * 16 + quad * 4 + reg;
        if (row >= NN) continue;
        #pragma unroll
        for (int t = 0; t < 8; ++t) {
            int col = t * 16 + l15;
            hbf[row * 256 + gy * 128 + col] = f2bf(gelu_f(acc[t][reg] + bias[col]));
        }
    }
}

// ---------------- edge GEMM: fused K=384 [fs*fd | fs | fd] @ B, B LDS-staged (double-buffered,
// T14 issue-early/write-late), A-gather prefetch depth 2, 32 edges/wave, 128/block ----------
__global__ __launch_bounds__(256, 3) void gemm_edge(const unsigned short* __restrict__ featbf,
                                                    const unsigned short* __restrict__ wedgebf,
                                                    float* __restrict__ ws) {
    __shared__ unsigned short Bs[2][24 * 512];   // 2 x 24 KB (24 fragments x 64 lanes x 8 bf16)
    int tid = threadIdx.x;
    int lane = tid & 63, w = tid >> 6;
    int quad = lane >> 4, l15 = lane & 15;
    int e0 = blockIdx.x * 128;
    const int2* ssrcd = (const int2*)(ws + OFF_SSRCD);
    int base = e0 + w * 32 + l15;                // wave handles edges [e0+w*32, +32)
    int2 i0 = ssrcd[base];
    int2 i1 = ssrcd[base + 16];
    const unsigned short* p0s = &featbf[i0.x * 128];
    const unsigned short* p0d = &featbf[i0.y * 128];
    const unsigned short* p1s = &featbf[i1.x * 128];
    const unsigned short* p1d = &featbf[i1.y * 128];
    int ko = quad * 8;

    // ---- prologue: A chunks kb0,kb1; B stage kb0 ----
    uint4 ca[2][4];                              // A double-buffer [kb&1][stream]
    ca[0][0] = *(const uint4*)&p0s[ko];
    ca[0][1] = *(const uint4*)&p0d[ko];
    ca[0][2] = *(const uint4*)&p1s[ko];
    ca[0][3] = *(const uint4*)&p1d[ko];
    ca[1][0] = *(const uint4*)&p0s[ko + 32];
    ca[1][1] = *(const uint4*)&p0d[ko + 32];
    ca[1][2] = *(const uint4*)&p1s[ko + 32];
    ca[1][3] = *(const uint4*)&p1d[ko + 32];
    uint4 sb[6];                                 // B staging regs: wave w owns frags ts = w*6..w*6+5
    #pragma unroll
    for (int i = 0; i < 6; ++i) {
        int ts = w * 6 + i;
        sb[i] = *(const uint4*)&wedgebf[(ts * 4 + 0) * 512 + lane * 8];
    }
    #pragma unroll
    for (int i = 0; i < 6; ++i) {
        int ts = w * 6 + i;
        *(uint4*)&Bs[0][ts * 512 + lane * 8] = sb[i];
    }
    __syncthreads();

    f32x4 acc0[8] = {}, acc1[8] = {};
    #pragma unroll
    for (int kb = 0; kb < 4; ++kb) {
        // consume current A chunk into bf16 fragments (before overwrite by prefetch)
        uint4 c0s = ca[kb & 1][0], c0d = ca[kb & 1][1];
        uint4 c1s = ca[kb & 1][2], c1d = ca[kb & 1][3];
        uint4 m0, m1;                            // elementwise fs*fd (bf16)
        m0.x = mulpack(c0s.x, c0d.x); m0.y = mulpack(c0s.y, c0d.y);
        m0.z = mulpack(c0s.z, c0d.z); m0.w = mulpack(c0s.w, c0d.w);
        m1.x = mulpack(c1s.x, c1d.x); m1.y = mulpack(c1s.y, c1d.y);
        m1.z = mulpack(c1s.z, c1d.z); m1.w = mulpack(c1s.w, c1d.w);
        bf16x8 am0 = *(const bf16x8*)&m0,  am1 = *(const bf16x8*)&m1;
        bf16x8 as0 = *(const bf16x8*)&c0s, ad0 = *(const bf16x8*)&c0d;
        bf16x8 as1 = *(const bf16x8*)&c1s, ad1 = *(const bf16x8*)&c1d;
        // issue A prefetch for kb+2 into the freed slot
        if (kb < 2) {
            int k2 = ko + (kb + 2) * 32;
            ca[kb & 1][0] = *(const uint4*)&p0s[k2];
            ca[kb & 1][1] = *(const uint4*)&p0d[k2];
            ca[kb & 1][2] = *(const uint4*)&p1s[k2];
            ca[kb & 1][3] = *(const uint4*)&p1d[k2];
        }
        // issue B global loads for kb+1 (write to LDS after MFMA phase — T14 split)
        if (kb < 3) {
            #pragma unroll
            for (int i = 0; i < 6; ++i) {
                int ts = w * 6 + i;
                sb[i] = *(const uint4*)&wedgebf[(ts * 4 + kb + 1) * 512 + lane * 8];
            }
        }
        // MFMA phase: B from LDS (ds_read_b128, conflict-free)
        const unsigned short* bb = &Bs[kb & 1][lane * 8];
        #pragma unroll
        for (int t = 0; t < 8; ++t) {
            bf16x8 bm = *(const bf16x8*)&bb[(t * 3 + 0) * 512];
            bf16x8 b1 = *(const bf16x8*)&bb[(t * 3 + 1) * 512];
            bf16x8 b2 = *(const bf16x8*)&bb[(t * 3 + 2) * 512];
            acc0[t] = __builtin_amdgcn_mfma_f32_16x16x32_bf16(am0, bm, acc0[t], 0, 0, 0);
            acc1[t] = __builtin_amdgcn_mfma_f32_16x16x32_bf16(am1, bm, acc1[t], 0, 0, 0);
            acc0[t] = __builtin_amdgcn_mfma_f32_16x16x32_bf16(as0, b1, acc0[t], 0, 0, 0);
            acc1[t] = __builtin_amdgcn_mfma_f32_16x16x32_bf16(as1, b1, acc1[t], 0, 0, 0);
            acc0[t] = __builtin_amdgcn_mfma_f32_16x16x32_bf16(ad0, b2, acc0[t], 0, 0, 0);
            acc1[t] = __builtin_amdgcn_mfma_f32_16x16x32_bf16(ad1, b2, acc1[t], 0, 0, 0);
        }
        // write-late: staged B -> LDS buf for kb+1, then barrier
        if (kb < 3) {
            #pragma unroll
            for (int i = 0; i < 6; ++i) {
                int ts = w * 6 + i;
                *(uint4*)&Bs[(kb + 1) & 1][ts * 512 + lane * 8] = sb[i];
            }
            __syncthreads();
        }
    }

    // epilogue: e = leaky(sum_col gelu(acc + be) * waout + b_aout)
    const float* waout = ws + OFF_WAOUT;
    const float* be = ws + OFF_BE;
    float b_aout = ws[OFF_BAOUT];
    float* e_out = ws + OFF_SEV;
    float wv[8], bv[8];
    #pragma unroll
    for (int t = 0; t < 8; ++t) { wv[t] = waout[t * 16 + l15]; bv[t] = be[t * 16 + l15]; }
    #pragma unroll
    for (int g = 0; g < 2; ++g) {
        #pragma unroll
        for (int reg = 0; reg < 4; ++reg) {
            int r = w * 32 + g * 16 + quad * 4 + reg;
            float partial = 0.0f;
            #pragma unroll
            for (int t = 0; t < 8; ++t) {
                float v = (g ? acc1[t][reg] : acc0[t][reg]) + bv[t];
                partial += gelu_f(v) * wv[t];
            }
            partial += __shfl_xor(partial, 1, 16);
            partial += __shfl_xor(partial, 2, 16);
            partial += __shfl_xor(partial, 4, 16);
            partial += __shfl_xor(partial, 8, 16);
            if (l15 == 0) e_out[e0 + r] = leaky_f(partial + b_aout);
        }
    }
}

// ---------------- final GEMM (MFMA, K=384, single-stage LDS) -> out f32 ----------------
__global__ __launch_bounds__(256) void gemm_final_mfma(const unsigned short* __restrict__ neighbf,
                                                       const unsigned short* __restrict__ featbf,
                                                       const unsigned short* __restrict__ wfinbf,
                                                       float* __restrict__ out,
                                                       const float* __restrict__ ws) {
    __shared__ unsigned short As[64 * 392];   // 64 rows x 384 cols bf16 (+8 pad)
    __shared__ float bfin_s[128];
    int tid = threadIdx.x;
    int row0 = blockIdx.x * 64;
    if (tid < 128) bfin_s[tid] = ws[OFF_BFIN + tid];
    #pragma unroll
    for (int rg = 0; rg < 3; ++rg) {
        #pragma unroll
        for (int it = 0; it < 4; ++it) {
            int idx = tid + it * 256;
            int r = idx >> 4, u = idx & 15;
            int rr = min(row0 + r, NN - 1);
            const unsigned short* sp = (rg == 0) ? &neighbf[rr * 256 + u * 8]
                                     : (rg == 1) ? &neighbf[rr * 256 + 128 + u * 8]
                                                 : &featbf[rr * 128 + u * 8];
            *(uint4*)&As[r * 392 + rg * 128 + u * 8] = *(const uint4*)sp;
        }
    }
    __syncthreads();
    int lane = tid & 63, w = tid >> 6;
    int quad = lane >> 4, l15 = lane & 15;
    f32x4 acc[8] = {};
    #pragma unroll 1
    for (int ks = 0; ks < 12; ++ks) {
        bf16x8 a = *(const bf16x8*)&As[(w * 16 + l15) * 392 + ks * 32 + quad * 8];
        #pragma unroll
        for (int t = 0; t < 8; ++t) {
            bf16x8 b = *(const bf16x8*)&wfinbf[(t * 16 + l15) * 384 + ks * 32 + quad * 8];
            acc[t] = __builtin_amdgcn_mfma_f32_16x16x32_bf16(a, b, acc[t], 0, 0, 0);
        }
    }
    #pragma unroll
    for (int reg = 0; reg < 4; ++reg) {
        int row = row0 + w * 16 + quad * 4 + reg;
        if (row >= NN) continue;
        #pragma unroll
        for (int t = 0; t < 8; ++t) {
            int col = t * 16 + l15;
            out[row * 128 + col] = acc[t][reg] + bfin_s[col];
        }
    }
}

// ---------------- MLP layer (MFMA, in-place on out; block reads only its own rows) ----------------
__global__ __launch_bounds__(256) void gemm_mlp_mfma(float* __restrict__ out,
                                                     const unsigned short* __restrict__ wmlp,
                                                     const float* __restrict__ bias) {
    __shared__ unsigned short As[64 * 136];
    int tid = threadIdx.x;
    int row0 = blockIdx.x * 64;
    #pragma unroll
    for (int it = 0; it < 8; ++it) {
        int idx = tid + it * 256;            // 64 rows x 32 float4-units
        int r = idx >> 5, u = idx & 31;
        int rr = min(row0 + r, NN - 1);      // clamp stays within this block's rows
        float4 v = ((const float4*)out)[rr * 32 + u];
        unsigned p0 = pk_bf16(gelu_f(v.x), gelu_f(v.y));
        unsigned p1 = pk_bf16(gelu_f(v.z), gelu_f(v.w));
        *(unsigned*)&As[r * 136 + u * 4]     = p0;
        *(unsigned*)&As[r * 136 + u * 4 + 2] = p1;
    }
    __syncthreads();
    int lane = tid & 63, w = tid >> 6;
    int quad = lane >> 4, l15 = lane & 15;
    f32x4 acc[8] = {};
    #pragma unroll 1
    for (int ks = 0; ks < 4; ++ks) {
        bf16x8 a = *(const bf16x8*)&As[(w * 16 + l15) * 136 + ks * 32 + quad * 8];
        #pragma unroll
        for (int t = 0; t < 8; ++t) {
            bf16x8 b = *(const bf16x8*)&wmlp[(t * 16 + l15) * 128 + ks * 32 + quad * 8];
            acc[t] = __builtin_amdgcn_mfma_f32_16x16x32_bf16(a, b, acc[t], 0, 0, 0);
        }
    }
    #pragma unroll
    for (int reg = 0; reg < 4; ++reg) {
        int row = row0 + w * 16 + quad * 4 + reg;
        if (row >= NN) continue;
        #pragma unroll
        for (int t = 0; t < 8; ++t) {
            int col = t * 16 + l15;
            out[row * 128 + col] += acc[t][reg] + bias[col];
        }
    }
}

// ---------------- host launch ----------------
extern "C" void kernel_launch(void* const* d_in, const int* in_sizes, int n_in,
                              void* d_out, int out_size, void* d_ws, size_t ws_size,
                              hipStream_t stream) {
    const float* feat = (const float*)d_in[0];
    WnormArgs wa;
    wa.asrc_v = (const float*)d_in[1];  wa.asrc_g = (const float*)d_in[2];  wa.asrc_b = (const float*)d_in[3];
    wa.adst_v = (const float*)d_in[4];  wa.adst_g = (const float*)d_in[5];  wa.adst_b = (const float*)d_in[6];
    wa.asub_v = (const float*)d_in[7];  wa.asub_g = (const float*)d_in[8];  wa.asub_b = (const float*)d_in[9];
    wa.amul_v = (const float*)d_in[10]; wa.amul_g = (const float*)d_in[11]; wa.amul_b = (const float*)d_in[12];
    wa.aout_v = (const float*)d_in[13]; wa.aout_g = (const float*)d_in[14]; wa.aout_b = (const float*)d_in[15];
    wa.pool_v = (const float*)d_in[16]; wa.pool_g = (const float*)d_in[17]; wa.pool_b = (const float*)d_in[18];
    wa.pool2_v= (const float*)d_in[19]; wa.pool2_g= (const float*)d_in[20]; wa.pool2_b= (const float*)d_in[21];
    wa.self_v = (const float*)d_in[22]; wa.self_g = (const float*)d_in[23]; wa.self_b = (const float*)d_in[24];
    wa.neigh_v= (const float*)d_in[25]; wa.neigh_g= (const float*)d_in[26]; wa.neigh_b= (const float*)d_in[27];
    wa.neigh2_v=(const float*)d_in[28]; wa.neigh2_g=(const float*)d_in[29]; wa.neigh2_b=(const float*)d_in[30];
    wa.mlp_v  = (const float*)d_in[31]; wa.mlp_g  = (const float*)d_in[32]; wa.mlp_b  = (const float*)d_in[33];
    const int* src = (const int*)d_in[34];
    const int* dst = (const int*)d_in[35];
    float* out = (float*)d_out;
    float* ws = (float*)d_ws;
    wa.ws = ws;
    unsigned short* featbf  = (unsigned short*)(ws + OFF_FEATBF);
    unsigned short* hbf     = (unsigned short*)(ws + OFF_HBF);
    unsigned short* neighbf = (unsigned short*)(ws + OFF_NEIGHBF);
    unsigned short* wnodebf = (unsigned short*)(ws + OFF_WNODEBF);
    unsigned short* wfinbf  = (unsigned short*)(ws + OFF_WFINBF);
    unsigned short* wmlpbf  = (unsigned short*)(ws + OFF_WMLPBF);
    unsigned short* wedgebf = (unsigned short*)(ws + OFF_WEDGEBF);

    // 1) normalized weights + fused bias vectors
    wnorm_kernel<<<dim3(1281), dim3(128), 0, stream>>>(wa);
    // 2) bf16 conversions (incl. packed fused edge weight table)
    convert_feat_kernel<<<dim3(NN * 128 / (256 * 8)), dim3(256), 0, stream>>>(feat, featbf);
    convert_weights_kernel<<<dim3(832), dim3(256), 0, stream>>>(ws);
    // 3) CSR-by-dst
    hist_zero_kernel<<<dim3((NN + 255) / 256), dim3(256), 0, stream>>>(ws);
    hist_kernel<<<dim3((EE + 255) / 256), dim3(256), 0, stream>>>(dst, ws);
    scan_kernel<<<dim3(1), dim3(1024), 0, stream>>>(ws);
    scatteridx_kernel<<<dim3((EE + 255) / 256), dim3(256), 0, stream>>>(src, dst, ws);
    // 4) node-level GEMM (MFMA): h/h2 only (S fused into edge GEMM)
    gemm_node_mfma<<<dim3(782, 2), dim3(256), 0, stream>>>(featbf, wa.pool_b, wa.pool2_b, hbf, wnodebf);
    // 5) edge GEMM (fused K=384, LDS-staged B dbuf, A prefetch d2) -> sev
    gemm_edge<<<dim3(EE / 128), dim3(256), 0, stream>>>(featbf, wedgebf, ws);
    // 6) segmented reduce -> neighbf (max zeroed | mean)
    segreduce_kernel<<<dim3(NN / 4), dim3(256), 0, stream>>>(ws);
    // 7) final GEMM (MFMA) -> out f32
    gemm_final_mfma<<<dim3(782), dim3(256), 0, stream>>>(neighbf, featbf, wfinbf, out, ws);
    // 8) two residual MLP layers (MFMA, in-place, block-self-contained rows)
    gemm_mlp_mfma<<<dim3(782), dim3(256), 0, stream>>>(out, wmlpbf, wa.mlp_b);
    gemm_mlp_mfma<<<dim3(782), dim3(256), 0, stream>>>(out, wmlpbf + 16384, wa.mlp_b + 128);
}

// Round 6
// 531.885 us; speedup vs baseline: 1.6213x; 1.2419x over previous
//
#include <hip/hip_runtime.h>
#include <hip/hip_bf16.h>
#include <math.h>

// ---------------- problem constants ----------------
constexpr int NN = 50000;   // nodes
constexpr int EE = 800000;  // edges

// ---------------- workspace layout (float offsets) ----------------
// f32 weights (written by wnorm)
constexpr int OFF_WT_NODE  = 0;        // [128][512] k-major: col groups 0:asrc+asub 1:adst-asub 2:pool 3:pool2
constexpr int OFF_WT_AMUL  = 65536;    // [128][128] k-major
constexpr int OFF_WT_FINAL = 81920;    // [384][128] k-major; k: 0-127 neigh, 128-255 neigh2, 256-383 self
constexpr int OFF_WT_MLP   = 131072;   // 2 x [128][128] k-major
constexpr int OFF_WAOUT    = 163840;   // [128]
constexpr int OFF_BE       = 163968;   // [128]
constexpr int OFF_BFIN     = 164096;   // [128]
constexpr int OFF_BAOUT    = 164224;   // [1] (pad 16)
// bf16 transposed weight tables ([o][k])
constexpr int OFF_WNODEBF  = 164240;               // 512*128 ushort = 32768 fl
constexpr int OFF_WFINBF   = OFF_WNODEBF + 32768;  // 128*384 ushort = 24576 fl
constexpr int OFF_WMLPBF   = OFF_WFINBF + 24576;   // 2*128*128 ushort = 16384 fl
constexpr int OFF_WAMULBF  = OFF_WMLPBF + 16384;   // 128*128 ushort = 8192 fl
// big arrays
constexpr int OFF_FEATBF   = OFF_WAMULBF + 8192;   // [N][128] bf16
constexpr int OFF_SBF      = OFF_FEATBF + NN*64;   // region reused: edge fused weight table
constexpr int OFF_WEDGEBF  = OFF_SBF;              // packed fragments: [(t*3+slice)*4+kb][lane 64][8] bf16
constexpr int OFF_HBF      = OFF_SBF + NN*128;     // [N][256] bf16 (h | h2)
constexpr int OFF_SEV      = OFF_HBF + NN*128;     // [E] f32, dst-sorted e (scratch for scan blocksums pre-edge)
constexpr int OFF_NEIGHBF  = OFF_SEV + EE;         // [N][256] bf16 (neigh | neigh2)
constexpr int OFF_STARTS   = OFF_NEIGHBF + NN*128; // [N+1] int (+pad)
constexpr int OFF_HIST     = OFF_STARTS + NN + 8;  // [N] int
constexpr int OFF_CURSOR   = OFF_HIST + NN;        // [N] int
constexpr int OFF_SSRCD    = OFF_CURSOR + NN;      // [E] int2 (src,dst sorted by dst)

constexpr int SCAN_NB = (NN + 255) / 256;          // 196 scan blocks

typedef __attribute__((ext_vector_type(8))) short bf16x8;
typedef __attribute__((ext_vector_type(4))) float f32x4;

// ---------------- device helpers ----------------
// fast GELU (tanh form via sigmoid), log2e folded into polynomial, rcp instead of div.
__device__ __forceinline__ float gelu_f(float x) {
    float x2 = x * x;
    float w = x * fmaf(-0.1029448f, x2, -2.3022082f);
    return x * __builtin_amdgcn_rcpf(1.0f + __builtin_amdgcn_exp2f(w));
}
__device__ __forceinline__ float leaky_f(float x) {
    return x > 0.0f ? x : 0.2f * x;
}
__device__ __forceinline__ unsigned short f2bf(float x) {
    unsigned u = __float_as_uint(x);
    return (unsigned short)((u + 0x7fffu + ((u >> 16) & 1u)) >> 16);
}
__device__ __forceinline__ float bf2f(unsigned short b) {
    return __uint_as_float(((unsigned)b) << 16);
}
__device__ __forceinline__ unsigned pk_bf16(float lo, float hi) {
    __hip_bfloat16 l = __float2bfloat16(lo);
    __hip_bfloat16 h = __float2bfloat16(hi);
    unsigned short lu = *reinterpret_cast<unsigned short*>(&l);
    unsigned short hu = *reinterpret_cast<unsigned short*>(&h);
    return (unsigned)lu | ((unsigned)hu << 16);
}
__device__ __forceinline__ unsigned mulpack(unsigned a, unsigned b) {
    float a0 = __uint_as_float(a << 16), a1 = __uint_as_float(a & 0xffff0000u);
    float b0 = __uint_as_float(b << 16), b1 = __uint_as_float(b & 0xffff0000u);
    return pk_bf16(a0 * b0, a1 * b1);
}
__device__ __forceinline__ float block_sum128(float v, float* sbuf) {
    #pragma unroll
    for (int o = 32; o > 0; o >>= 1) v += __shfl_down(v, o, 64);
    int lane = threadIdx.x & 63, w = threadIdx.x >> 6;
    if (lane == 0) sbuf[w] = v;
    __syncthreads();
    float r = sbuf[0] + sbuf[1];
    __syncthreads();
    return r;
}

// ---------------- weight normalization ----------------
struct WnormArgs {
    const float *asrc_v, *asrc_g, *asrc_b;
    const float *adst_v, *adst_g, *adst_b;
    const float *asub_v, *asub_g, *asub_b;
    const float *amul_v, *amul_g, *amul_b;
    const float *aout_v, *aout_g, *aout_b;
    const float *pool_v, *pool_g, *pool_b;
    const float *pool2_v, *pool2_g, *pool2_b;
    const float *self_v, *self_g, *self_b;
    const float *neigh_v, *neigh_g, *neigh_b;
    const float *neigh2_v, *neigh2_g, *neigh2_b;
    const float *mlp_v, *mlp_g, *mlp_b;
    float* ws;
};

__global__ __launch_bounds__(128) void wnorm_kernel(WnormArgs a) {
    __shared__ float sbuf[2];
    int bid = blockIdx.x, i = threadIdx.x;
    float* ws = a.ws;
    if (bid < 1280) {
        int o = bid & 127, grp = bid >> 7;
        const float *v1 = nullptr, *g1 = nullptr, *v2 = nullptr, *g2 = nullptr;
        float sgn2 = 1.0f; float* dst = nullptr; int stride = 0;
        switch (grp) {
            case 0: v1=a.asrc_v; g1=a.asrc_g; v2=a.asub_v; g2=a.asub_g; sgn2= 1.f; dst=ws+OFF_WT_NODE+o;        stride=512; break;
            case 1: v1=a.adst_v; g1=a.adst_g; v2=a.asub_v; g2=a.asub_g; sgn2=-1.f; dst=ws+OFF_WT_NODE+128+o;    stride=512; break;
            case 2: v1=a.pool_v;  g1=a.pool_g;  dst=ws+OFF_WT_NODE+256+o;          stride=512; break;
            case 3: v1=a.pool2_v; g1=a.pool2_g; dst=ws+OFF_WT_NODE+384+o;          stride=512; break;
            case 4: v1=a.amul_v;  g1=a.amul_g;  dst=ws+OFF_WT_AMUL+o;              stride=128; break;
            case 5: v1=a.neigh_v; g1=a.neigh_g; dst=ws+OFF_WT_FINAL+o;             stride=128; break;
            case 6: v1=a.neigh2_v;g1=a.neigh2_g;dst=ws+OFF_WT_FINAL+128*128+o;     stride=128; break;
            case 7: v1=a.self_v;  g1=a.self_g;  dst=ws+OFF_WT_FINAL+256*128+o;     stride=128; break;
            case 8: v1=a.mlp_v;        g1=a.mlp_g;     dst=ws+OFF_WT_MLP+o;        stride=128; break;
            case 9: v1=a.mlp_v+16384;  g1=a.mlp_g+128; dst=ws+OFF_WT_MLP+16384+o;  stride=128; break;
        }
        float x1 = v1[o*128 + i];
        float n1 = sqrtf(block_sum128(x1*x1, sbuf));
        float w = g1[o] * x1 / n1;
        if (v2) {
            float x2 = v2[o*128 + i];
            float n2 = sqrtf(block_sum128(x2*x2, sbuf));
            w += sgn2 * g2[o] * x2 / n2;
        }
        dst[i * stride] = w;
    } else {
        float v = a.aout_v[i];
        float n = sqrtf(block_sum128(v*v, sbuf));
        ws[OFF_WAOUT + i] = a.aout_g[0] * v / n;
        ws[OFF_BE + i]    = a.asrc_b[i] + a.adst_b[i] + a.asub_b[i] + a.amul_b[i];
        ws[OFF_BFIN + i]  = a.self_b[i] + a.neigh_b[i] + a.neigh2_b[i];
        if (i == 0) ws[OFF_BAOUT] = a.aout_b[0];
    }
}

// ---------------- bf16 conversions ----------------
__global__ __launch_bounds__(256) void convert_feat_kernel(const float* __restrict__ feat,
                                                           unsigned short* __restrict__ featbf) {
    int i = (blockIdx.x * 256 + threadIdx.x) * 8;
    float4 v0 = ((const float4*)feat)[i >> 2];
    float4 v1 = ((const float4*)feat)[(i >> 2) + 1];
    uint4 p;
    p.x = pk_bf16(v0.x, v0.y);
    p.y = pk_bf16(v0.z, v0.w);
    p.z = pk_bf16(v1.x, v1.y);
    p.w = pk_bf16(v1.z, v1.w);
    *(uint4*)&featbf[i] = p;
}

// all weight tables -> bf16; 832 blocks x 256
__global__ __launch_bounds__(256) void convert_weights_kernel(float* __restrict__ ws) {
    int idx = blockIdx.x * 256 + threadIdx.x;
    unsigned short* wnodebf = (unsigned short*)(ws + OFF_WNODEBF);
    unsigned short* wfinbf  = (unsigned short*)(ws + OFF_WFINBF);
    unsigned short* wmlpbf  = (unsigned short*)(ws + OFF_WMLPBF);
    unsigned short* wamulbf = (unsigned short*)(ws + OFF_WAMULBF);
    unsigned short* wedgebf = (unsigned short*)(ws + OFF_WEDGEBF);
    if (idx < 65536) {                 // node: [k 128][n 512] -> [n][k]
        int k = idx >> 9, n = idx & 511;
        wnodebf[n * 128 + k] = f2bf(ws[OFF_WT_NODE + k * 512 + n]);
    } else if (idx < 114688) {         // final: [k 384][o 128] -> [o][k]
        int i = idx - 65536, k = i >> 7, o = i & 127;
        wfinbf[o * 384 + k] = f2bf(ws[OFF_WT_FINAL + k * 128 + o]);
    } else if (idx < 147456) {         // mlp: 2 x [k 128][o 128] -> [o][k]
        int i = idx - 114688, l = i >> 14, j = i & 16383, k = j >> 7, o = j & 127;
        wmlpbf[l * 16384 + o * 128 + k] = f2bf(ws[OFF_WT_MLP + l * 16384 + k * 128 + o]);
    } else if (idx < 163840) {         // amul: [k 128][o 128] -> [o][k]
        int i = idx - 147456, k = i >> 7, o = i & 127;
        wamulbf[o * 128 + k] = f2bf(ws[OFF_WT_AMUL + k * 128 + o]);
    } else {
        // packed fused edge table: fragment id f = (t*3+slice)*4+kb; layout [f][lane 64][elem 8]
        // fragment (t,slice,kb,lane): B row o = t*16 + (lane&15), k = slice*128 + kb*32 + (lane>>4)*8 + elem
        // slice 0 = Wmul, slice 1 = Wsrc+Wsub, slice 2 = Wdst-Wsub
        int i = idx - 163840;              // [0, 49152)
        int elem = i & 7, f = i >> 3;
        int lane = f & 63, kb = (f >> 6) & 3, ts = f >> 8;   // ts in [0,24)
        int t = ts / 3, slice = ts - t * 3;
        int o = t * 16 + (lane & 15);
        int kk = kb * 32 + (lane >> 4) * 8 + elem;
        float v = (slice == 0) ? ws[OFF_WT_AMUL + kk * 128 + o]
                : (slice == 1) ? ws[OFF_WT_NODE + kk * 512 + o]
                               : ws[OFF_WT_NODE + kk * 512 + 128 + o];
        wedgebf[i] = f2bf(v);
    }
}

// ---------------- CSR-by-dst construction ----------------
__global__ __launch_bounds__(256) void hist_zero_kernel(float* __restrict__ ws) {
    int i = blockIdx.x * 256 + threadIdx.x;
    if (i < NN) ((int*)(ws + OFF_HIST))[i] = 0;
}

__global__ __launch_bounds__(256) void hist_kernel(const int* __restrict__ dst, float* __restrict__ ws) {
    int e = blockIdx.x * 256 + threadIdx.x;
    if (e < EE) atomicAdd(&((int*)(ws + OFF_HIST))[dst[e]], 1);
}

// two-level scan, stage 1: per-block exclusive prefix + block sums (196 blocks x 256)
__global__ __launch_bounds__(256) void scan_blocks_kernel(float* __restrict__ ws) {
    __shared__ int wsum[4];
    const int* hist = (const int*)(ws + OFF_HIST);
    int* starts = (int*)(ws + OFF_STARTS);
    int* bsum = (int*)(ws + OFF_SEV);              // scratch (sev written later by gemm_edge)
    int bid = blockIdx.x, t = threadIdx.x;
    int idx = bid * 256 + t;
    int lane = t & 63, w = t >> 6;
    int v = (idx < NN) ? hist[idx] : 0;
    int s = v;                                     // inclusive scan within wave
    #pragma unroll
    for (int o = 1; o < 64; o <<= 1) {
        int u = __shfl_up(s, o, 64);
        if (lane >= o) s += u;
    }
    if (lane == 63) wsum[w] = s;
    __syncthreads();
    int off = 0;
    for (int i = 0; i < w; ++i) off += wsum[i];
    int incl = s + off;
    if (idx < NN) starts[idx] = incl - v;          // exclusive prefix within block
    if (t == 255) bsum[bid] = incl;                // block total
}

// stage 2: exclusive scan of block sums (1 block x 256; SCAN_NB=196 <= 256)
__global__ __launch_bounds__(256) void scan_tops_kernel(float* __restrict__ ws) {
    __shared__ int wsum[4];
    int* bsum = (int*)(ws + OFF_SEV);
    int t = threadIdx.x, lane = t & 63, w = t >> 6;
    int v = (t < SCAN_NB) ? bsum[t] : 0;
    int s = v;
    #pragma unroll
    for (int o = 1; o < 64; o <<= 1) {
        int u = __shfl_up(s, o, 64);
        if (lane >= o) s += u;
    }
    if (lane == 63) wsum[w] = s;
    __syncthreads();
    int off = 0;
    for (int i = 0; i < w; ++i) off += wsum[i];
    if (t < SCAN_NB) bsum[t] = s + off - v;        // exclusive
}

// stage 3: add block offsets, mirror to cursor, terminate starts
__global__ __launch_bounds__(256) void scan_add_kernel(float* __restrict__ ws) {
    int* starts = (int*)(ws + OFF_STARTS);
    int* cursor = (int*)(ws + OFF_CURSOR);
    const int* bsum = (const int*)(ws + OFF_SEV);
    int bid = blockIdx.x, t = threadIdx.x;
    int idx = bid * 256 + t;
    if (idx < NN) {
        int sv = starts[idx] + bsum[bid];
        starts[idx] = sv;
        cursor[idx] = sv;
    }
    if (idx == 0) starts[NN] = EE;
}

__global__ __launch_bounds__(256) void scatteridx_kernel(const int* __restrict__ src,
                                                         const int* __restrict__ dst,
                                                         float* __restrict__ ws) {
    int e = blockIdx.x * 256 + threadIdx.x;
    if (e >= EE) return;
    int d = dst[e];
    int pos = atomicAdd(&((int*)(ws + OFF_CURSOR))[d], 1);
    ((int2*)(ws + OFF_SSRCD))[pos] = make_int2(src[e], d);
}

// ---------------- segmented reduction -> neighbf bf16 [N][256] ----------------
__global__ __launch_bounds__(256) void segreduce_kernel(float* __restrict__ ws) {
    int n = blockIdx.x * 4 + (threadIdx.x >> 6);
    int lane = threadIdx.x & 63;
    const int* starts = (const int*)(ws + OFF_STARTS);
    const int2* ssrcd = (const int2*)(ws + OFF_SSRCD);
    const float* sev = ws + OFF_SEV;
    const unsigned short* hbf = (const unsigned short*)(ws + OFF_HBF);
    unsigned short* neighbf = (unsigned short*)(ws + OFF_NEIGHBF);
    int s0 = starts[n], s1 = starts[n + 1];
    float2 mx = make_float2(-INFINITY, -INFINITY);
    float2 sm = make_float2(0.f, 0.f);
    int i = s0;
    for (; i + 2 <= s1; i += 2) {
        int sA = ssrcd[i].x, sB = ssrcd[i + 1].x;
        float evA = sev[i], evB = sev[i + 1];
        unsigned hvA  = *(const unsigned*)&hbf[sA * 256 + lane * 2];
        unsigned h2vA = *(const unsigned*)&hbf[sA * 256 + 128 + lane * 2];
        unsigned hvB  = *(const unsigned*)&hbf[sB * 256 + lane * 2];
        unsigned h2vB = *(const unsigned*)&hbf[sB * 256 + 128 + lane * 2];
        mx.x = fmaxf(mx.x, evA * bf2f((unsigned short)(hvA & 0xffffu)));
        mx.y = fmaxf(mx.y, evA * bf2f((unsigned short)(hvA >> 16)));
        sm.x += evA * bf2f((unsigned short)(h2vA & 0xffffu));
        sm.y += evA * bf2f((unsigned short)(h2vA >> 16));
        mx.x = fmaxf(mx.x, evB * bf2f((unsigned short)(hvB & 0xffffu)));
        mx.y = fmaxf(mx.y, evB * bf2f((unsigned short)(hvB >> 16)));
        sm.x += evB * bf2f((unsigned short)(h2vB & 0xffffu));
        sm.y += evB * bf2f((unsigned short)(h2vB >> 16));
    }
    if (i < s1) {
        int s = ssrcd[i].x;
        float ev = sev[i];
        unsigned hv  = *(const unsigned*)&hbf[s * 256 + lane * 2];
        unsigned h2v = *(const unsigned*)&hbf[s * 256 + 128 + lane * 2];
        mx.x = fmaxf(mx.x, ev * bf2f((unsigned short)(hv & 0xffffu)));
        mx.y = fmaxf(mx.y, ev * bf2f((unsigned short)(hv >> 16)));
        sm.x += ev * bf2f((unsigned short)(h2v & 0xffffu));
        sm.y += ev * bf2f((unsigned short)(h2v >> 16));
    }
    int cnt = s1 - s0;
    if (cnt == 0) { mx.x = 0.f; mx.y = 0.f; }
    float ic = 1.0f / (float)max(cnt, 1);
    *(unsigned*)&neighbf[n * 256 + lane * 2] = pk_bf16(mx.x, mx.y);
    *(unsigned*)&neighbf[n * 256 + 128 + lane * 2] = pk_bf16(sm.x * ic, sm.y * ic);
}

// ---------------- node GEMM (MFMA): h / h2 only ----------------
__global__ __launch_bounds__(256) void gemm_node_mfma(const unsigned short* __restrict__ featbf,
                                                      const float* __restrict__ pool_b,
                                                      const float* __restrict__ pool2_b,
                                                      unsigned short* __restrict__ hbf,
                                                      const unsigned short* __restrict__ wnodebf) {
    __shared__ unsigned short As[64 * 136];
    int tid = threadIdx.x;
    int row0 = blockIdx.x * 64, gy = blockIdx.y;
    #pragma unroll
    for (int it = 0; it < 4; ++it) {
        int idx = tid + it * 256;
        int r = idx >> 4, u = idx & 15;
        int rr = min(row0 + r, NN - 1);
        *(uint4*)&As[r * 136 + u * 8] = *(const uint4*)&featbf[rr * 128 + u * 8];
    }
    __syncthreads();
    int lane = tid & 63, w = tid >> 6;
    int quad = lane >> 4, l15 = lane & 15;
    const unsigned short* B = wnodebf + (gy + 2) * 128 * 128;
    const float* bias = gy == 0 ? pool_b : pool2_b;
    f32x4 acc[8] = {};
    #pragma unroll 1
    for (int ks = 0; ks < 4; ++ks) {
        bf16x8 a = *(const bf16x8*)&As[(w * 16 + l15) * 136 + ks * 32 + quad * 8];
        #pragma unroll
        for (int t = 0; t < 8; ++t) {
            bf16x8 b = *(const bf16x8*)&B[(t * 16 + l15) * 128 + ks * 32 + quad * 8];
            acc[t] = __builtin_amdgcn_mfma_f32_16x16x32_bf16(a, b, acc[t], 0, 0, 0);
        }
    }
    #pragma unroll
    for (int reg = 0; reg < 4; ++reg) {
        int row = row0 + w * 16 + quad * 4 + reg;
        if (row >= NN) continue;
        #pragma unroll
        for (int t = 0; t < 8; ++t) {
            int col = t * 16 + l15;
            hbf[row * 256 + gy * 128 + col] = f2bf(gelu_f(acc[t][reg] + bias[col]));
        }
    }
}

// ---------------- edge GEMM: fused K=384 [fs*fd | fs | fd] @ B, B LDS-staged (double-buffered,
// T14 issue-early/write-late), A-gather prefetch depth 2, 32 edges/wave, 128/block ----------
__global__ __launch_bounds__(256, 3) void gemm_edge(const unsigned short* __restrict__ featbf,
                                                    const unsigned short* __restrict__ wedgebf,
                                                    float* __restrict__ ws) {
    __shared__ unsigned short Bs[2][24 * 512];   // 2 x 24 KB (24 fragments x 64 lanes x 8 bf16)
    int tid = threadIdx.x;
    int lane = tid & 63, w = tid >> 6;
    int quad = lane >> 4, l15 = lane & 15;
    int e0 = blockIdx.x * 128;
    const int2* ssrcd = (const int2*)(ws + OFF_SSRCD);
    int base = e0 + w * 32 + l15;                // wave handles edges [e0+w*32, +32)
    int2 i0 = ssrcd[base];
    int2 i1 = ssrcd[base + 16];
    const unsigned short* p0s = &featbf[i0.x * 128];
    const unsigned short* p0d = &featbf[i0.y * 128];
    const unsigned short* p1s = &featbf[i1.x * 128];
    const unsigned short* p1d = &featbf[i1.y * 128];
    int ko = quad * 8;

    // ---- prologue: A chunks kb0,kb1; B stage kb0 ----
    uint4 ca[2][4];                              // A double-buffer [kb&1][stream]
    ca[0][0] = *(const uint4*)&p0s[ko];
    ca[0][1] = *(const uint4*)&p0d[ko];
    ca[0][2] = *(const uint4*)&p1s[ko];
    ca[0][3] = *(const uint4*)&p1d[ko];
    ca[1][0] = *(const uint4*)&p0s[ko + 32];
    ca[1][1] = *(const uint4*)&p0d[ko + 32];
    ca[1][2] = *(const uint4*)&p1s[ko + 32];
    ca[1][3] = *(const uint4*)&p1d[ko + 32];
    uint4 sb[6];                                 // B staging regs: wave w owns frags ts = w*6..w*6+5
    #pragma unroll
    for (int i = 0; i < 6; ++i) {
        int ts = w * 6 + i;
        sb[i] = *(const uint4*)&wedgebf[(ts * 4 + 0) * 512 + lane * 8];
    }
    #pragma unroll
    for (int i = 0; i < 6; ++i) {
        int ts = w * 6 + i;
        *(uint4*)&Bs[0][ts * 512 + lane * 8] = sb[i];
    }
    __syncthreads();

    f32x4 acc0[8] = {}, acc1[8] = {};
    #pragma unroll
    for (int kb = 0; kb < 4; ++kb) {
        // consume current A chunk into bf16 fragments (before overwrite by prefetch)
        uint4 c0s = ca[kb & 1][0], c0d = ca[kb & 1][1];
        uint4 c1s = ca[kb & 1][2], c1d = ca[kb & 1][3];
        uint4 m0, m1;                            // elementwise fs*fd (bf16)
        m0.x = mulpack(c0s.x, c0d.x); m0.y = mulpack(c0s.y, c0d.y);
        m0.z = mulpack(c0s.z, c0d.z); m0.w = mulpack(c0s.w, c0d.w);
        m1.x = mulpack(c1s.x, c1d.x); m1.y = mulpack(c1s.y, c1d.y);
        m1.z = mulpack(c1s.z, c1d.z); m1.w = mulpack(c1s.w, c1d.w);
        bf16x8 am0 = *(const bf16x8*)&m0,  am1 = *(const bf16x8*)&m1;
        bf16x8 as0 = *(const bf16x8*)&c0s, ad0 = *(const bf16x8*)&c0d;
        bf16x8 as1 = *(const bf16x8*)&c1s, ad1 = *(const bf16x8*)&c1d;
        // issue A prefetch for kb+2 into the freed slot
        if (kb < 2) {
            int k2 = ko + (kb + 2) * 32;
            ca[kb & 1][0] = *(const uint4*)&p0s[k2];
            ca[kb & 1][1] = *(const uint4*)&p0d[k2];
            ca[kb & 1][2] = *(const uint4*)&p1s[k2];
            ca[kb & 1][3] = *(const uint4*)&p1d[k2];
        }
        // issue B global loads for kb+1 (write to LDS after MFMA phase — T14 split)
        if (kb < 3) {
            #pragma unroll
            for (int i = 0; i < 6; ++i) {
                int ts = w * 6 + i;
                sb[i] = *(const uint4*)&wedgebf[(ts * 4 + kb + 1) * 512 + lane * 8];
            }
        }
        // MFMA phase: B from LDS (ds_read_b128, conflict-free)
        const unsigned short* bb = &Bs[kb & 1][lane * 8];
        #pragma unroll
        for (int t = 0; t < 8; ++t) {
            bf16x8 bm = *(const bf16x8*)&bb[(t * 3 + 0) * 512];
            bf16x8 b1 = *(const bf16x8*)&bb[(t * 3 + 1) * 512];
            bf16x8 b2 = *(const bf16x8*)&bb[(t * 3 + 2) * 512];
            acc0[t] = __builtin_amdgcn_mfma_f32_16x16x32_bf16(am0, bm, acc0[t], 0, 0, 0);
            acc1[t] = __builtin_amdgcn_mfma_f32_16x16x32_bf16(am1, bm, acc1[t], 0, 0, 0);
            acc0[t] = __builtin_amdgcn_mfma_f32_16x16x32_bf16(as0, b1, acc0[t], 0, 0, 0);
            acc1[t] = __builtin_amdgcn_mfma_f32_16x16x32_bf16(as1, b1, acc1[t], 0, 0, 0);
            acc0[t] = __builtin_amdgcn_mfma_f32_16x16x32_bf16(ad0, b2, acc0[t], 0, 0, 0);
            acc1[t] = __builtin_amdgcn_mfma_f32_16x16x32_bf16(ad1, b2, acc1[t], 0, 0, 0);
        }
        // write-late: staged B -> LDS buf for kb+1, then barrier
        if (kb < 3) {
            #pragma unroll
            for (int i = 0; i < 6; ++i) {
                int ts = w * 6 + i;
                *(uint4*)&Bs[(kb + 1) & 1][ts * 512 + lane * 8] = sb[i];
            }
            __syncthreads();
        }
    }

    // epilogue: e = leaky(sum_col gelu(acc + be) * waout + b_aout)
    const float* waout = ws + OFF_WAOUT;
    const float* be = ws + OFF_BE;
    float b_aout = ws[OFF_BAOUT];
    float* e_out = ws + OFF_SEV;
    float wv[8], bv[8];
    #pragma unroll
    for (int t = 0; t < 8; ++t) { wv[t] = waout[t * 16 + l15]; bv[t] = be[t * 16 + l15]; }
    #pragma unroll
    for (int g = 0; g < 2; ++g) {
        #pragma unroll
        for (int reg = 0; reg < 4; ++reg) {
            int r = w * 32 + g * 16 + quad * 4 + reg;
            float partial = 0.0f;
            #pragma unroll
            for (int t = 0; t < 8; ++t) {
                float v = (g ? acc1[t][reg] : acc0[t][reg]) + bv[t];
                partial += gelu_f(v) * wv[t];
            }
            partial += __shfl_xor(partial, 1, 16);
            partial += __shfl_xor(partial, 2, 16);
            partial += __shfl_xor(partial, 4, 16);
            partial += __shfl_xor(partial, 8, 16);
            if (l15 == 0) e_out[e0 + r] = leaky_f(partial + b_aout);
        }
    }
}

// ---------------- final GEMM (MFMA, K=384, single-stage LDS) -> out f32 ----------------
__global__ __launch_bounds__(256) void gemm_final_mfma(const unsigned short* __restrict__ neighbf,
                                                       const unsigned short* __restrict__ featbf,
                                                       const unsigned short* __restrict__ wfinbf,
                                                       float* __restrict__ out,
                                                       const float* __restrict__ ws) {
    __shared__ unsigned short As[64 * 392];   // 64 rows x 384 cols bf16 (+8 pad)
    __shared__ float bfin_s[128];
    int tid = threadIdx.x;
    int row0 = blockIdx.x * 64;
    if (tid < 128) bfin_s[tid] = ws[OFF_BFIN + tid];
    #pragma unroll
    for (int rg = 0; rg < 3; ++rg) {
        #pragma unroll
        for (int it = 0; it < 4; ++it) {
            int idx = tid + it * 256;
            int r = idx >> 4, u = idx & 15;
            int rr = min(row0 + r, NN - 1);
            const unsigned short* sp = (rg == 0) ? &neighbf[rr * 256 + u * 8]
                                     : (rg == 1) ? &neighbf[rr * 256 + 128 + u * 8]
                                                 : &featbf[rr * 128 + u * 8];
            *(uint4*)&As[r * 392 + rg * 128 + u * 8] = *(const uint4*)sp;
        }
    }
    __syncthreads();
    int lane = tid & 63, w = tid >> 6;
    int quad = lane >> 4, l15 = lane & 15;
    f32x4 acc[8] = {};
    #pragma unroll 1
    for (int ks = 0; ks < 12; ++ks) {
        bf16x8 a = *(const bf16x8*)&As[(w * 16 + l15) * 392 + ks * 32 + quad * 8];
        #pragma unroll
        for (int t = 0; t < 8; ++t) {
            bf16x8 b = *(const bf16x8*)&wfinbf[(t * 16 + l15) * 384 + ks * 32 + quad * 8];
            acc[t] = __builtin_amdgcn_mfma_f32_16x16x32_bf16(a, b, acc[t], 0, 0, 0);
        }
    }
    #pragma unroll
    for (int reg = 0; reg < 4; ++reg) {
        int row = row0 + w * 16 + quad * 4 + reg;
        if (row >= NN) continue;
        #pragma unroll
        for (int t = 0; t < 8; ++t) {
            int col = t * 16 + l15;
            out[row * 128 + col] = acc[t][reg] + bfin_s[col];
        }
    }
}

// ---------------- MLP layer (MFMA, in-place on out; block reads only its own rows) ----------------
__global__ __launch_bounds__(256) void gemm_mlp_mfma(float* __restrict__ out,
                                                     const unsigned short* __restrict__ wmlp,
                                                     const float* __restrict__ bias) {
    __shared__ unsigned short As[64 * 136];
    int tid = threadIdx.x;
    int row0 = blockIdx.x * 64;
    #pragma unroll
    for (int it = 0; it < 8; ++it) {
        int idx = tid + it * 256;            // 64 rows x 32 float4-units
        int r = idx >> 5, u = idx & 31;
        int rr = min(row0 + r, NN - 1);      // clamp stays within this block's rows
        float4 v = ((const float4*)out)[rr * 32 + u];
        unsigned p0 = pk_bf16(gelu_f(v.x), gelu_f(v.y));
        unsigned p1 = pk_bf16(gelu_f(v.z), gelu_f(v.w));
        *(unsigned*)&As[r * 136 + u * 4]     = p0;
        *(unsigned*)&As[r * 136 + u * 4 + 2] = p1;
    }
    __syncthreads();
    int lane = tid & 63, w = tid >> 6;
    int quad = lane >> 4, l15 = lane & 15;
    f32x4 acc[8] = {};
    #pragma unroll 1
    for (int ks = 0; ks < 4; ++ks) {
        bf16x8 a = *(const bf16x8*)&As[(w * 16 + l15) * 136 + ks * 32 + quad * 8];
        #pragma unroll
        for (int t = 0; t < 8; ++t) {
            bf16x8 b = *(const bf16x8*)&wmlp[(t * 16 + l15) * 128 + ks * 32 + quad * 8];
            acc[t] = __builtin_amdgcn_mfma_f32_16x16x32_bf16(a, b, acc[t], 0, 0, 0);
        }
    }
    #pragma unroll
    for (int reg = 0; reg < 4; ++reg) {
        int row = row0 + w * 16 + quad * 4 + reg;
        if (row >= NN) continue;
        #pragma unroll
        for (int t = 0; t < 8; ++t) {
            int col = t * 16 + l15;
            out[row * 128 + col] += acc[t][reg] + bias[col];
        }
    }
}

// ---------------- host launch ----------------
extern "C" void kernel_launch(void* const* d_in, const int* in_sizes, int n_in,
                              void* d_out, int out_size, void* d_ws, size_t ws_size,
                              hipStream_t stream) {
    const float* feat = (const float*)d_in[0];
    WnormArgs wa;
    wa.asrc_v = (const float*)d_in[1];  wa.asrc_g = (const float*)d_in[2];  wa.asrc_b = (const float*)d_in[3];
    wa.adst_v = (const float*)d_in[4];  wa.adst_g = (const float*)d_in[5];  wa.adst_b = (const float*)d_in[6];
    wa.asub_v = (const float*)d_in[7];  wa.asub_g = (const float*)d_in[8];  wa.asub_b = (const float*)d_in[9];
    wa.amul_v = (const float*)d_in[10]; wa.amul_g = (const float*)d_in[11]; wa.amul_b = (const float*)d_in[12];
    wa.aout_v = (const float*)d_in[13]; wa.aout_g = (const float*)d_in[14]; wa.aout_b = (const float*)d_in[15];
    wa.pool_v = (const float*)d_in[16]; wa.pool_g = (const float*)d_in[17]; wa.pool_b = (const float*)d_in[18];
    wa.pool2_v= (const float*)d_in[19]; wa.pool2_g= (const float*)d_in[20]; wa.pool2_b= (const float*)d_in[21];
    wa.self_v = (const float*)d_in[22]; wa.self_g = (const float*)d_in[23]; wa.self_b = (const float*)d_in[24];
    wa.neigh_v= (const float*)d_in[25]; wa.neigh_g= (const float*)d_in[26]; wa.neigh_b= (const float*)d_in[27];
    wa.neigh2_v=(const float*)d_in[28]; wa.neigh2_g=(const float*)d_in[29]; wa.neigh2_b=(const float*)d_in[30];
    wa.mlp_v  = (const float*)d_in[31]; wa.mlp_g  = (const float*)d_in[32]; wa.mlp_b  = (const float*)d_in[33];
    const int* src = (const int*)d_in[34];
    const int* dst = (const int*)d_in[35];
    float* out = (float*)d_out;
    float* ws = (float*)d_ws;
    wa.ws = ws;
    unsigned short* featbf  = (unsigned short*)(ws + OFF_FEATBF);
    unsigned short* hbf     = (unsigned short*)(ws + OFF_HBF);
    unsigned short* neighbf = (unsigned short*)(ws + OFF_NEIGHBF);
    unsigned short* wnodebf = (unsigned short*)(ws + OFF_WNODEBF);
    unsigned short* wfinbf  = (unsigned short*)(ws + OFF_WFINBF);
    unsigned short* wmlpbf  = (unsigned short*)(ws + OFF_WMLPBF);
    unsigned short* wedgebf = (unsigned short*)(ws + OFF_WEDGEBF);

    // 1) normalized weights + fused bias vectors
    wnorm_kernel<<<dim3(1281), dim3(128), 0, stream>>>(wa);
    // 2) bf16 conversions (incl. packed fused edge weight table)
    convert_feat_kernel<<<dim3(NN * 128 / (256 * 8)), dim3(256), 0, stream>>>(feat, featbf);
    convert_weights_kernel<<<dim3(832), dim3(256), 0, stream>>>(ws);
    // 3) CSR-by-dst (two-level parallel scan)
    hist_zero_kernel<<<dim3((NN + 255) / 256), dim3(256), 0, stream>>>(ws);
    hist_kernel<<<dim3((EE + 255) / 256), dim3(256), 0, stream>>>(dst, ws);
    scan_blocks_kernel<<<dim3(SCAN_NB), dim3(256), 0, stream>>>(ws);
    scan_tops_kernel<<<dim3(1), dim3(256), 0, stream>>>(ws);
    scan_add_kernel<<<dim3(SCAN_NB), dim3(256), 0, stream>>>(ws);
    scatteridx_kernel<<<dim3((EE + 255) / 256), dim3(256), 0, stream>>>(src, dst, ws);
    // 4) node-level GEMM (MFMA): h/h2 only (S fused into edge GEMM)
    gemm_node_mfma<<<dim3(782, 2), dim3(256), 0, stream>>>(featbf, wa.pool_b, wa.pool2_b, hbf, wnodebf);
    // 5) edge GEMM (fused K=384, LDS-staged B dbuf, A prefetch d2) -> sev
    gemm_edge<<<dim3(EE / 128), dim3(256), 0, stream>>>(featbf, wedgebf, ws);
    // 6) segmented reduce -> neighbf (max zeroed | mean)
    segreduce_kernel<<<dim3(NN / 4), dim3(256), 0, stream>>>(ws);
    // 7) final GEMM (MFMA) -> out f32
    gemm_final_mfma<<<dim3(782), dim3(256), 0, stream>>>(neighbf, featbf, wfinbf, out, ws);
    // 8) two residual MLP layers (MFMA, in-place, block-self-contained rows)
    gemm_mlp_mfma<<<dim3(782), dim3(256), 0, stream>>>(out, wmlpbf, wa.mlp_b);
    gemm_mlp_mfma<<<dim3(782), dim3(256), 0, stream>>>(out, wmlpbf + 16384, wa.mlp_b + 128);
}

// Round 7
// 510.341 us; speedup vs baseline: 1.6897x; 1.0422x over previous
//
#include <hip/hip_runtime.h>
#include <hip/hip_bf16.h>
#include <math.h>

// ---------------- problem constants ----------------
constexpr int NN = 50000;   // nodes
constexpr int EE = 800000;  // edges

// ---------------- workspace layout (float offsets) ----------------
// f32 weights (written by wnorm)
constexpr int OFF_WT_NODE  = 0;        // [128][512] k-major: col groups 0:asrc+asub 1:adst-asub 2:pool 3:pool2
constexpr int OFF_WT_AMUL  = 65536;    // [128][128] k-major
constexpr int OFF_WT_FINAL = 81920;    // [384][128] k-major; k: 0-127 neigh, 128-255 neigh2, 256-383 self
constexpr int OFF_WT_MLP   = 131072;   // 2 x [128][128] k-major
constexpr int OFF_WAOUT    = 163840;   // [128]
constexpr int OFF_BE       = 163968;   // [128]
constexpr int OFF_BFIN     = 164096;   // [128]
constexpr int OFF_BAOUT    = 164224;   // [1] (pad 16)
// bf16 transposed weight tables ([o][k])
constexpr int OFF_WNODEBF  = 164240;               // 512*128 ushort = 32768 fl
constexpr int OFF_WFINBF   = OFF_WNODEBF + 32768;  // 128*384 ushort = 24576 fl
constexpr int OFF_WMLPBF   = OFF_WFINBF + 24576;   // 2*128*128 ushort = 16384 fl
constexpr int OFF_WAMULBF  = OFF_WMLPBF + 16384;   // 128*128 ushort = 8192 fl
// big arrays
constexpr int OFF_FEATBF   = OFF_WAMULBF + 8192;   // [N][128] bf16
constexpr int OFF_SBF      = OFF_FEATBF + NN*64;   // region reused: edge fused weight table
constexpr int OFF_WEDGEBF  = OFF_SBF;              // packed fragments: [(t*3+slice)*4+kb][lane 64][8] bf16
constexpr int OFF_HBF      = OFF_SBF + NN*128;     // [N][256] bf16 (h | h2)
constexpr int OFF_SEV      = OFF_HBF + NN*128;     // [E] f32, dst-sorted e (scratch for scan blocksums pre-edge)
constexpr int OFF_NEIGHBF  = OFF_SEV + EE;         // [N][256] bf16 (neigh | neigh2)
constexpr int OFF_STARTS   = OFF_NEIGHBF + NN*128; // [N+1] int (+pad)
constexpr int OFF_HIST     = OFF_STARTS + NN + 8;  // [N] int
constexpr int OFF_CURSOR   = OFF_HIST + NN;        // [N] int
constexpr int OFF_SSRCD    = OFF_CURSOR + NN;      // [E] int2 (src,dst sorted by dst)

constexpr int SCAN_NB = (NN + 255) / 256;          // 196 scan blocks

typedef __attribute__((ext_vector_type(8))) short bf16x8;
typedef __attribute__((ext_vector_type(4))) float f32x4;

// ---------------- device helpers ----------------
// fast GELU (tanh form via sigmoid), log2e folded into polynomial, rcp instead of div.
__device__ __forceinline__ float gelu_f(float x) {
    float x2 = x * x;
    float w = x * fmaf(-0.1029448f, x2, -2.3022082f);
    return x * __builtin_amdgcn_rcpf(1.0f + __builtin_amdgcn_exp2f(w));
}
__device__ __forceinline__ float leaky_f(float x) {
    return x > 0.0f ? x : 0.2f * x;
}
__device__ __forceinline__ unsigned short f2bf(float x) {
    unsigned u = __float_as_uint(x);
    return (unsigned short)((u + 0x7fffu + ((u >> 16) & 1u)) >> 16);
}
__device__ __forceinline__ float bf2f(unsigned short b) {
    return __uint_as_float(((unsigned)b) << 16);
}
__device__ __forceinline__ unsigned pk_bf16(float lo, float hi) {
    __hip_bfloat16 l = __float2bfloat16(lo);
    __hip_bfloat16 h = __float2bfloat16(hi);
    unsigned short lu = *reinterpret_cast<unsigned short*>(&l);
    unsigned short hu = *reinterpret_cast<unsigned short*>(&h);
    return (unsigned)lu | ((unsigned)hu << 16);
}
__device__ __forceinline__ unsigned mulpack(unsigned a, unsigned b) {
    float a0 = __uint_as_float(a << 16), a1 = __uint_as_float(a & 0xffff0000u);
    float b0 = __uint_as_float(b << 16), b1 = __uint_as_float(b & 0xffff0000u);
    return pk_bf16(a0 * b0, a1 * b1);
}
__device__ __forceinline__ float block_sum128(float v, float* sbuf) {
    #pragma unroll
    for (int o = 32; o > 0; o >>= 1) v += __shfl_down(v, o, 64);
    int lane = threadIdx.x & 63, w = threadIdx.x >> 6;
    if (lane == 0) sbuf[w] = v;
    __syncthreads();
    float r = sbuf[0] + sbuf[1];
    __syncthreads();
    return r;
}

// ---------------- weight normalization ----------------
struct WnormArgs {
    const float *asrc_v, *asrc_g, *asrc_b;
    const float *adst_v, *adst_g, *adst_b;
    const float *asub_v, *asub_g, *asub_b;
    const float *amul_v, *amul_g, *amul_b;
    const float *aout_v, *aout_g, *aout_b;
    const float *pool_v, *pool_g, *pool_b;
    const float *pool2_v, *pool2_g, *pool2_b;
    const float *self_v, *self_g, *self_b;
    const float *neigh_v, *neigh_g, *neigh_b;
    const float *neigh2_v, *neigh2_g, *neigh2_b;
    const float *mlp_v, *mlp_g, *mlp_b;
    float* ws;
};

__global__ __launch_bounds__(128) void wnorm_kernel(WnormArgs a) {
    __shared__ float sbuf[2];
    int bid = blockIdx.x, i = threadIdx.x;
    float* ws = a.ws;
    if (bid < 1280) {
        int o = bid & 127, grp = bid >> 7;
        const float *v1 = nullptr, *g1 = nullptr, *v2 = nullptr, *g2 = nullptr;
        float sgn2 = 1.0f; float* dst = nullptr; int stride = 0;
        switch (grp) {
            case 0: v1=a.asrc_v; g1=a.asrc_g; v2=a.asub_v; g2=a.asub_g; sgn2= 1.f; dst=ws+OFF_WT_NODE+o;        stride=512; break;
            case 1: v1=a.adst_v; g1=a.adst_g; v2=a.asub_v; g2=a.asub_g; sgn2=-1.f; dst=ws+OFF_WT_NODE+128+o;    stride=512; break;
            case 2: v1=a.pool_v;  g1=a.pool_g;  dst=ws+OFF_WT_NODE+256+o;          stride=512; break;
            case 3: v1=a.pool2_v; g1=a.pool2_g; dst=ws+OFF_WT_NODE+384+o;          stride=512; break;
            case 4: v1=a.amul_v;  g1=a.amul_g;  dst=ws+OFF_WT_AMUL+o;              stride=128; break;
            case 5: v1=a.neigh_v; g1=a.neigh_g; dst=ws+OFF_WT_FINAL+o;             stride=128; break;
            case 6: v1=a.neigh2_v;g1=a.neigh2_g;dst=ws+OFF_WT_FINAL+128*128+o;     stride=128; break;
            case 7: v1=a.self_v;  g1=a.self_g;  dst=ws+OFF_WT_FINAL+256*128+o;     stride=128; break;
            case 8: v1=a.mlp_v;        g1=a.mlp_g;     dst=ws+OFF_WT_MLP+o;        stride=128; break;
            case 9: v1=a.mlp_v+16384;  g1=a.mlp_g+128; dst=ws+OFF_WT_MLP+16384+o;  stride=128; break;
        }
        float x1 = v1[o*128 + i];
        float n1 = sqrtf(block_sum128(x1*x1, sbuf));
        float w = g1[o] * x1 / n1;
        if (v2) {
            float x2 = v2[o*128 + i];
            float n2 = sqrtf(block_sum128(x2*x2, sbuf));
            w += sgn2 * g2[o] * x2 / n2;
        }
        dst[i * stride] = w;
    } else {
        float v = a.aout_v[i];
        float n = sqrtf(block_sum128(v*v, sbuf));
        ws[OFF_WAOUT + i] = a.aout_g[0] * v / n;
        ws[OFF_BE + i]    = a.asrc_b[i] + a.adst_b[i] + a.asub_b[i] + a.amul_b[i];
        ws[OFF_BFIN + i]  = a.self_b[i] + a.neigh_b[i] + a.neigh2_b[i];
        if (i == 0) ws[OFF_BAOUT] = a.aout_b[0];
    }
}

// ---------------- weight tables -> bf16; 832 blocks x 256 ----------------
__global__ __launch_bounds__(256) void convert_weights_kernel(float* __restrict__ ws) {
    int idx = blockIdx.x * 256 + threadIdx.x;
    unsigned short* wnodebf = (unsigned short*)(ws + OFF_WNODEBF);
    unsigned short* wfinbf  = (unsigned short*)(ws + OFF_WFINBF);
    unsigned short* wmlpbf  = (unsigned short*)(ws + OFF_WMLPBF);
    unsigned short* wamulbf = (unsigned short*)(ws + OFF_WAMULBF);
    unsigned short* wedgebf = (unsigned short*)(ws + OFF_WEDGEBF);
    if (idx < 65536) {                 // node: [k 128][n 512] -> [n][k]
        int k = idx >> 9, n = idx & 511;
        wnodebf[n * 128 + k] = f2bf(ws[OFF_WT_NODE + k * 512 + n]);
    } else if (idx < 114688) {         // final: [k 384][o 128] -> [o][k]
        int i = idx - 65536, k = i >> 7, o = i & 127;
        wfinbf[o * 384 + k] = f2bf(ws[OFF_WT_FINAL + k * 128 + o]);
    } else if (idx < 147456) {         // mlp: 2 x [k 128][o 128] -> [o][k]
        int i = idx - 114688, l = i >> 14, j = i & 16383, k = j >> 7, o = j & 127;
        wmlpbf[l * 16384 + o * 128 + k] = f2bf(ws[OFF_WT_MLP + l * 16384 + k * 128 + o]);
    } else if (idx < 163840) {         // amul: [k 128][o 128] -> [o][k]
        int i = idx - 147456, k = i >> 7, o = i & 127;
        wamulbf[o * 128 + k] = f2bf(ws[OFF_WT_AMUL + k * 128 + o]);
    } else {
        // packed fused edge table: fragment id f = (t*3+slice)*4+kb; layout [f][lane 64][elem 8]
        int i = idx - 163840;              // [0, 49152)
        int elem = i & 7, f = i >> 3;
        int lane = f & 63, kb = (f >> 6) & 3, ts = f >> 8;   // ts in [0,24)
        int t = ts / 3, slice = ts - t * 3;
        int o = t * 16 + (lane & 15);
        int kk = kb * 32 + (lane >> 4) * 8 + elem;
        float v = (slice == 0) ? ws[OFF_WT_AMUL + kk * 128 + o]
                : (slice == 1) ? ws[OFF_WT_NODE + kk * 512 + o]
                               : ws[OFF_WT_NODE + kk * 512 + 128 + o];
        wedgebf[i] = f2bf(v);
    }
}

// ---------------- CSR-by-dst construction ----------------
__global__ __launch_bounds__(256) void hist_zero_kernel(float* __restrict__ ws) {
    int i = blockIdx.x * 256 + threadIdx.x;
    if (i < NN) ((int*)(ws + OFF_HIST))[i] = 0;
}

__global__ __launch_bounds__(256) void hist_kernel(const int* __restrict__ dst, float* __restrict__ ws) {
    int e = blockIdx.x * 256 + threadIdx.x;
    if (e < EE) atomicAdd(&((int*)(ws + OFF_HIST))[dst[e]], 1);
}

// two-level scan, stage 1: per-block exclusive prefix + block sums (196 blocks x 256)
__global__ __launch_bounds__(256) void scan_blocks_kernel(float* __restrict__ ws) {
    __shared__ int wsum[4];
    const int* hist = (const int*)(ws + OFF_HIST);
    int* starts = (int*)(ws + OFF_STARTS);
    int* bsum = (int*)(ws + OFF_SEV);              // scratch (sev written later by gemm_edge)
    int bid = blockIdx.x, t = threadIdx.x;
    int idx = bid * 256 + t;
    int lane = t & 63, w = t >> 6;
    int v = (idx < NN) ? hist[idx] : 0;
    int s = v;                                     // inclusive scan within wave
    #pragma unroll
    for (int o = 1; o < 64; o <<= 1) {
        int u = __shfl_up(s, o, 64);
        if (lane >= o) s += u;
    }
    if (lane == 63) wsum[w] = s;
    __syncthreads();
    int off = 0;
    for (int i = 0; i < w; ++i) off += wsum[i];
    int incl = s + off;
    if (idx < NN) starts[idx] = incl - v;          // exclusive prefix within block
    if (t == 255) bsum[bid] = incl;                // block total
}

// stage 2: exclusive scan of block sums (1 block x 256; SCAN_NB=196 <= 256)
__global__ __launch_bounds__(256) void scan_tops_kernel(float* __restrict__ ws) {
    __shared__ int wsum[4];
    int* bsum = (int*)(ws + OFF_SEV);
    int t = threadIdx.x, lane = t & 63, w = t >> 6;
    int v = (t < SCAN_NB) ? bsum[t] : 0;
    int s = v;
    #pragma unroll
    for (int o = 1; o < 64; o <<= 1) {
        int u = __shfl_up(s, o, 64);
        if (lane >= o) s += u;
    }
    if (lane == 63) wsum[w] = s;
    __syncthreads();
    int off = 0;
    for (int i = 0; i < w; ++i) off += wsum[i];
    if (t < SCAN_NB) bsum[t] = s + off - v;        // exclusive
}

// stage 3: add block offsets, mirror to cursor, terminate starts
__global__ __launch_bounds__(256) void scan_add_kernel(float* __restrict__ ws) {
    int* starts = (int*)(ws + OFF_STARTS);
    int* cursor = (int*)(ws + OFF_CURSOR);
    const int* bsum = (const int*)(ws + OFF_SEV);
    int bid = blockIdx.x, t = threadIdx.x;
    int idx = bid * 256 + t;
    if (idx < NN) {
        int sv = starts[idx] + bsum[bid];
        starts[idx] = sv;
        cursor[idx] = sv;
    }
    if (idx == 0) starts[NN] = EE;
}

__global__ __launch_bounds__(256) void scatteridx_kernel(const int* __restrict__ src,
                                                         const int* __restrict__ dst,
                                                         float* __restrict__ ws) {
    int e = blockIdx.x * 256 + threadIdx.x;
    if (e >= EE) return;
    int d = dst[e];
    int pos = atomicAdd(&((int*)(ws + OFF_CURSOR))[d], 1);
    ((int2*)(ws + OFF_SSRCD))[pos] = make_int2(src[e], d);
}

// ---------------- segmented reduction -> neighbf bf16 [N][256], 4-wide pipelined ----------------
__global__ __launch_bounds__(256) void segreduce_kernel(float* __restrict__ ws) {
    int n = blockIdx.x * 4 + (threadIdx.x >> 6);
    int lane = threadIdx.x & 63;
    const int* starts = (const int*)(ws + OFF_STARTS);
    const int2* ssrcd = (const int2*)(ws + OFF_SSRCD);
    const float* sev = ws + OFF_SEV;
    const unsigned short* hbf = (const unsigned short*)(ws + OFF_HBF);
    unsigned short* neighbf = (unsigned short*)(ws + OFF_NEIGHBF);
    int s0 = starts[n], s1 = starts[n + 1];
    float2 mx = make_float2(-INFINITY, -INFINITY);
    float2 sm = make_float2(0.f, 0.f);
    int i = s0;
    for (; i + 4 <= s1; i += 4) {
        int sA = ssrcd[i].x, sB = ssrcd[i + 1].x, sC = ssrcd[i + 2].x, sD = ssrcd[i + 3].x;
        float eA = sev[i], eB = sev[i + 1], eC = sev[i + 2], eD = sev[i + 3];
        unsigned hA = *(const unsigned*)&hbf[sA * 256 + lane * 2];
        unsigned gA = *(const unsigned*)&hbf[sA * 256 + 128 + lane * 2];
        unsigned hB = *(const unsigned*)&hbf[sB * 256 + lane * 2];
        unsigned gB = *(const unsigned*)&hbf[sB * 256 + 128 + lane * 2];
        unsigned hC = *(const unsigned*)&hbf[sC * 256 + lane * 2];
        unsigned gC = *(const unsigned*)&hbf[sC * 256 + 128 + lane * 2];
        unsigned hD = *(const unsigned*)&hbf[sD * 256 + lane * 2];
        unsigned gD = *(const unsigned*)&hbf[sD * 256 + 128 + lane * 2];
        mx.x = fmaxf(mx.x, eA * bf2f((unsigned short)(hA & 0xffffu)));
        mx.y = fmaxf(mx.y, eA * bf2f((unsigned short)(hA >> 16)));
        sm.x += eA * bf2f((unsigned short)(gA & 0xffffu));
        sm.y += eA * bf2f((unsigned short)(gA >> 16));
        mx.x = fmaxf(mx.x, eB * bf2f((unsigned short)(hB & 0xffffu)));
        mx.y = fmaxf(mx.y, eB * bf2f((unsigned short)(hB >> 16)));
        sm.x += eB * bf2f((unsigned short)(gB & 0xffffu));
        sm.y += eB * bf2f((unsigned short)(gB >> 16));
        mx.x = fmaxf(mx.x, eC * bf2f((unsigned short)(hC & 0xffffu)));
        mx.y = fmaxf(mx.y, eC * bf2f((unsigned short)(hC >> 16)));
        sm.x += eC * bf2f((unsigned short)(gC & 0xffffu));
        sm.y += eC * bf2f((unsigned short)(gC >> 16));
        mx.x = fmaxf(mx.x, eD * bf2f((unsigned short)(hD & 0xffffu)));
        mx.y = fmaxf(mx.y, eD * bf2f((unsigned short)(hD >> 16)));
        sm.x += eD * bf2f((unsigned short)(gD & 0xffffu));
        sm.y += eD * bf2f((unsigned short)(gD >> 16));
    }
    for (; i < s1; ++i) {
        int s = ssrcd[i].x;
        float ev = sev[i];
        unsigned hv  = *(const unsigned*)&hbf[s * 256 + lane * 2];
        unsigned h2v = *(const unsigned*)&hbf[s * 256 + 128 + lane * 2];
        mx.x = fmaxf(mx.x, ev * bf2f((unsigned short)(hv & 0xffffu)));
        mx.y = fmaxf(mx.y, ev * bf2f((unsigned short)(hv >> 16)));
        sm.x += ev * bf2f((unsigned short)(h2v & 0xffffu));
        sm.y += ev * bf2f((unsigned short)(h2v >> 16));
    }
    int cnt = s1 - s0;
    if (cnt == 0) { mx.x = 0.f; mx.y = 0.f; }
    float ic = 1.0f / (float)max(cnt, 1);
    *(unsigned*)&neighbf[n * 256 + lane * 2] = pk_bf16(mx.x, mx.y);
    *(unsigned*)&neighbf[n * 256 + 128 + lane * 2] = pk_bf16(sm.x * ic, sm.y * ic);
}

// ---------------- node GEMM (MFMA): converts feat f32 -> featbf AND computes h/h2 ----------------
__global__ __launch_bounds__(256) void gemm_node_mfma(const float* __restrict__ feat,
                                                      const float* __restrict__ pool_b,
                                                      const float* __restrict__ pool2_b,
                                                      unsigned short* __restrict__ featbf,
                                                      unsigned short* __restrict__ hbf,
                                                      const unsigned short* __restrict__ wnodebf) {
    __shared__ unsigned short As[64 * 136];
    int tid = threadIdx.x;
    int row0 = blockIdx.x * 64;
    #pragma unroll
    for (int it = 0; it < 8; ++it) {
        int idx = tid + it * 256;            // 64 rows x 32 float4-units
        int r = idx >> 5, u = idx & 31;
        int rr = min(row0 + r, NN - 1);
        float4 v = ((const float4*)feat)[rr * 32 + u];
        unsigned p0 = pk_bf16(v.x, v.y);
        unsigned p1 = pk_bf16(v.z, v.w);
        *(unsigned*)&As[r * 136 + u * 4]     = p0;
        *(unsigned*)&As[r * 136 + u * 4 + 2] = p1;
        *(uint2*)&featbf[rr * 128 + u * 4] = make_uint2(p0, p1);   // write bf16 feat table
    }
    __syncthreads();
    int lane = tid & 63, w = tid >> 6;
    int quad = lane >> 4, l15 = lane & 15;
    #pragma unroll 1
    for (int gy = 0; gy < 2; ++gy) {
        const unsigned short* B = wnodebf + (gy + 2) * 128 * 128;
        const float* bias = gy == 0 ? pool_b : pool2_b;
        f32x4 acc[8] = {};
        #pragma unroll 1
        for (int ks = 0; ks < 4; ++ks) {
            bf16x8 a = *(const bf16x8*)&As[(w * 16 + l15) * 136 + ks * 32 + quad * 8];
            #pragma unroll
            for (int t = 0; t < 8; ++t) {
                bf16x8 b = *(const bf16x8*)&B[(t * 16 + l15) * 128 + ks * 32 + quad * 8];
                acc[t] = __builtin_amdgcn_mfma_f32_16x16x32_bf16(a, b, acc[t], 0, 0, 0);
            }
        }
        #pragma unroll
        for (int reg = 0; reg < 4; ++reg) {
            int row = row0 + w * 16 + quad * 4 + reg;
            if (row >= NN) continue;
            #pragma unroll
            for (int t = 0; t < 8; ++t) {
                int col = t * 16 + l15;
                hbf[row * 256 + gy * 128 + col] = f2bf(gelu_f(acc[t][reg] + bias[col]));
            }
        }
    }
}

// ---------------- edge GEMM: fused K=384 [fs*fd | fs | fd] @ B, B LDS-staged (double-buffered,
// T14 issue-early/write-late), A-gather prefetch depth 2, 32 edges/wave, 128/block ----------
__global__ __launch_bounds__(256, 3) void gemm_edge(const unsigned short* __restrict__ featbf,
                                                    const unsigned short* __restrict__ wedgebf,
                                                    float* __restrict__ ws) {
    __shared__ unsigned short Bs[2][24 * 512];   // 2 x 24 KB (24 fragments x 64 lanes x 8 bf16)
    int tid = threadIdx.x;
    int lane = tid & 63, w = tid >> 6;
    int quad = lane >> 4, l15 = lane & 15;
    int e0 = blockIdx.x * 128;
    const int2* ssrcd = (const int2*)(ws + OFF_SSRCD);
    int base = e0 + w * 32 + l15;                // wave handles edges [e0+w*32, +32)
    int2 i0 = ssrcd[base];
    int2 i1 = ssrcd[base + 16];
    const unsigned short* p0s = &featbf[i0.x * 128];
    const unsigned short* p0d = &featbf[i0.y * 128];
    const unsigned short* p1s = &featbf[i1.x * 128];
    const unsigned short* p1d = &featbf[i1.y * 128];
    int ko = quad * 8;

    // ---- prologue: A chunks kb0,kb1; B stage kb0 ----
    uint4 ca[2][4];                              // A double-buffer [kb&1][stream]
    ca[0][0] = *(const uint4*)&p0s[ko];
    ca[0][1] = *(const uint4*)&p0d[ko];
    ca[0][2] = *(const uint4*)&p1s[ko];
    ca[0][3] = *(const uint4*)&p1d[ko];
    ca[1][0] = *(const uint4*)&p0s[ko + 32];
    ca[1][1] = *(const uint4*)&p0d[ko + 32];
    ca[1][2] = *(const uint4*)&p1s[ko + 32];
    ca[1][3] = *(const uint4*)&p1d[ko + 32];
    uint4 sb[6];                                 // B staging regs: wave w owns frags ts = w*6..w*6+5
    #pragma unroll
    for (int i = 0; i < 6; ++i) {
        int ts = w * 6 + i;
        sb[i] = *(const uint4*)&wedgebf[(ts * 4 + 0) * 512 + lane * 8];
    }
    #pragma unroll
    for (int i = 0; i < 6; ++i) {
        int ts = w * 6 + i;
        *(uint4*)&Bs[0][ts * 512 + lane * 8] = sb[i];
    }
    __syncthreads();

    f32x4 acc0[8] = {}, acc1[8] = {};
    #pragma unroll
    for (int kb = 0; kb < 4; ++kb) {
        // consume current A chunk into bf16 fragments (before overwrite by prefetch)
        uint4 c0s = ca[kb & 1][0], c0d = ca[kb & 1][1];
        uint4 c1s = ca[kb & 1][2], c1d = ca[kb & 1][3];
        uint4 m0, m1;                            // elementwise fs*fd (bf16)
        m0.x = mulpack(c0s.x, c0d.x); m0.y = mulpack(c0s.y, c0d.y);
        m0.z = mulpack(c0s.z, c0d.z); m0.w = mulpack(c0s.w, c0d.w);
        m1.x = mulpack(c1s.x, c1d.x); m1.y = mulpack(c1s.y, c1d.y);
        m1.z = mulpack(c1s.z, c1d.z); m1.w = mulpack(c1s.w, c1d.w);
        bf16x8 am0 = *(const bf16x8*)&m0,  am1 = *(const bf16x8*)&m1;
        bf16x8 as0 = *(const bf16x8*)&c0s, ad0 = *(const bf16x8*)&c0d;
        bf16x8 as1 = *(const bf16x8*)&c1s, ad1 = *(const bf16x8*)&c1d;
        // issue A prefetch for kb+2 into the freed slot
        if (kb < 2) {
            int k2 = ko + (kb + 2) * 32;
            ca[kb & 1][0] = *(const uint4*)&p0s[k2];
            ca[kb & 1][1] = *(const uint4*)&p0d[k2];
            ca[kb & 1][2] = *(const uint4*)&p1s[k2];
            ca[kb & 1][3] = *(const uint4*)&p1d[k2];
        }
        // issue B global loads for kb+1 (write to LDS after MFMA phase — T14 split)
        if (kb < 3) {
            #pragma unroll
            for (int i = 0; i < 6; ++i) {
                int ts = w * 6 + i;
                sb[i] = *(const uint4*)&wedgebf[(ts * 4 + kb + 1) * 512 + lane * 8];
            }
        }
        // MFMA phase: B from LDS (ds_read_b128, conflict-free)
        const unsigned short* bb = &Bs[kb & 1][lane * 8];
        #pragma unroll
        for (int t = 0; t < 8; ++t) {
            bf16x8 bm = *(const bf16x8*)&bb[(t * 3 + 0) * 512];
            bf16x8 b1 = *(const bf16x8*)&bb[(t * 3 + 1) * 512];
            bf16x8 b2 = *(const bf16x8*)&bb[(t * 3 + 2) * 512];
            acc0[t] = __builtin_amdgcn_mfma_f32_16x16x32_bf16(am0, bm, acc0[t], 0, 0, 0);
            acc1[t] = __builtin_amdgcn_mfma_f32_16x16x32_bf16(am1, bm, acc1[t], 0, 0, 0);
            acc0[t] = __builtin_amdgcn_mfma_f32_16x16x32_bf16(as0, b1, acc0[t], 0, 0, 0);
            acc1[t] = __builtin_amdgcn_mfma_f32_16x16x32_bf16(as1, b1, acc1[t], 0, 0, 0);
            acc0[t] = __builtin_amdgcn_mfma_f32_16x16x32_bf16(ad0, b2, acc0[t], 0, 0, 0);
            acc1[t] = __builtin_amdgcn_mfma_f32_16x16x32_bf16(ad1, b2, acc1[t], 0, 0, 0);
        }
        // write-late: staged B -> LDS buf for kb+1, then barrier
        if (kb < 3) {
            #pragma unroll
            for (int i = 0; i < 6; ++i) {
                int ts = w * 6 + i;
                *(uint4*)&Bs[(kb + 1) & 1][ts * 512 + lane * 8] = sb[i];
            }
            __syncthreads();
        }
    }

    // epilogue: e = leaky(sum_col gelu(acc + be) * waout + b_aout)
    const float* waout = ws + OFF_WAOUT;
    const float* be = ws + OFF_BE;
    float b_aout = ws[OFF_BAOUT];
    float* e_out = ws + OFF_SEV;
    float wv[8], bv[8];
    #pragma unroll
    for (int t = 0; t < 8; ++t) { wv[t] = waout[t * 16 + l15]; bv[t] = be[t * 16 + l15]; }
    #pragma unroll
    for (int g = 0; g < 2; ++g) {
        #pragma unroll
        for (int reg = 0; reg < 4; ++reg) {
            int r = w * 32 + g * 16 + quad * 4 + reg;
            float partial = 0.0f;
            #pragma unroll
            for (int t = 0; t < 8; ++t) {
                float v = (g ? acc1[t][reg] : acc0[t][reg]) + bv[t];
                partial += gelu_f(v) * wv[t];
            }
            partial += __shfl_xor(partial, 1, 16);
            partial += __shfl_xor(partial, 2, 16);
            partial += __shfl_xor(partial, 4, 16);
            partial += __shfl_xor(partial, 8, 16);
            if (l15 == 0) e_out[e0 + r] = leaky_f(partial + b_aout);
        }
    }
}

// ---------------- fused final GEMM (K=384) + 2 residual MLP layers -> out f32 (single pass) ----
__global__ __launch_bounds__(256) void gemm_final_mlp(const unsigned short* __restrict__ neighbf,
                                                      const unsigned short* __restrict__ featbf,
                                                      const unsigned short* __restrict__ wfinbf,
                                                      const unsigned short* __restrict__ wmlpbf,
                                                      const float* __restrict__ mlp_b,
                                                      float* __restrict__ out,
                                                      const float* __restrict__ ws) {
    __shared__ unsigned short As[64 * 392];   // stage1: 64x384 (+8 pad); reused as 64x136 for MLP
    __shared__ float bfin_s[128];
    int tid = threadIdx.x;
    int row0 = blockIdx.x * 64;
    if (tid < 128) bfin_s[tid] = ws[OFF_BFIN + tid];
    #pragma unroll
    for (int rg = 0; rg < 3; ++rg) {
        #pragma unroll
        for (int it = 0; it < 4; ++it) {
            int idx = tid + it * 256;
            int r = idx >> 4, u = idx & 15;
            int rr = min(row0 + r, NN - 1);
            const unsigned short* sp = (rg == 0) ? &neighbf[rr * 256 + u * 8]
                                     : (rg == 1) ? &neighbf[rr * 256 + 128 + u * 8]
                                                 : &featbf[rr * 128 + u * 8];
            *(uint4*)&As[r * 392 + rg * 128 + u * 8] = *(const uint4*)sp;
        }
    }
    __syncthreads();
    int lane = tid & 63, w = tid >> 6;
    int quad = lane >> 4, l15 = lane & 15;
    f32x4 rst[8] = {};
    #pragma unroll 1
    for (int ks = 0; ks < 12; ++ks) {
        bf16x8 a = *(const bf16x8*)&As[(w * 16 + l15) * 392 + ks * 32 + quad * 8];
        #pragma unroll
        for (int t = 0; t < 8; ++t) {
            bf16x8 b = *(const bf16x8*)&wfinbf[(t * 16 + l15) * 384 + ks * 32 + quad * 8];
            rst[t] = __builtin_amdgcn_mfma_f32_16x16x32_bf16(a, b, rst[t], 0, 0, 0);
        }
    }
    #pragma unroll
    for (int t = 0; t < 8; ++t) {
        float bf = bfin_s[t * 16 + l15];
        #pragma unroll
        for (int reg = 0; reg < 4; ++reg) rst[t][reg] += bf;
    }
    // two residual MLP layers, all in-block (no global round trip)
    #pragma unroll 1
    for (int layer = 0; layer < 2; ++layer) {
        __syncthreads();                       // prior As reads complete before overwrite
        #pragma unroll
        for (int t = 0; t < 8; ++t) {
            #pragma unroll
            for (int reg = 0; reg < 4; ++reg) {
                int row = w * 16 + quad * 4 + reg;
                As[row * 136 + t * 16 + l15] = f2bf(gelu_f(rst[t][reg]));
            }
        }
        __syncthreads();
        const unsigned short* wB = wmlpbf + layer * 16384;
        f32x4 acc[8] = {};
        #pragma unroll 1
        for (int ks = 0; ks < 4; ++ks) {
            bf16x8 a = *(const bf16x8*)&As[(w * 16 + l15) * 136 + ks * 32 + quad * 8];
            #pragma unroll
            for (int t = 0; t < 8; ++t) {
                bf16x8 b = *(const bf16x8*)&wB[(t * 16 + l15) * 128 + ks * 32 + quad * 8];
                acc[t] = __builtin_amdgcn_mfma_f32_16x16x32_bf16(a, b, acc[t], 0, 0, 0);
            }
        }
        #pragma unroll
        for (int t = 0; t < 8; ++t) {
            float bias = mlp_b[layer * 128 + t * 16 + l15];
            #pragma unroll
            for (int reg = 0; reg < 4; ++reg) rst[t][reg] += acc[t][reg] + bias;
        }
    }
    #pragma unroll
    for (int reg = 0; reg < 4; ++reg) {
        int row = row0 + w * 16 + quad * 4 + reg;
        if (row >= NN) continue;
        #pragma unroll
        for (int t = 0; t < 8; ++t) {
            out[row * 128 + t * 16 + l15] = rst[t][reg];
        }
    }
}

// ---------------- host launch ----------------
extern "C" void kernel_launch(void* const* d_in, const int* in_sizes, int n_in,
                              void* d_out, int out_size, void* d_ws, size_t ws_size,
                              hipStream_t stream) {
    const float* feat = (const float*)d_in[0];
    WnormArgs wa;
    wa.asrc_v = (const float*)d_in[1];  wa.asrc_g = (const float*)d_in[2];  wa.asrc_b = (const float*)d_in[3];
    wa.adst_v = (const float*)d_in[4];  wa.adst_g = (const float*)d_in[5];  wa.adst_b = (const float*)d_in[6];
    wa.asub_v = (const float*)d_in[7];  wa.asub_g = (const float*)d_in[8];  wa.asub_b = (const float*)d_in[9];
    wa.amul_v = (const float*)d_in[10]; wa.amul_g = (const float*)d_in[11]; wa.amul_b = (const float*)d_in[12];
    wa.aout_v = (const float*)d_in[13]; wa.aout_g = (const float*)d_in[14]; wa.aout_b = (const float*)d_in[15];
    wa.pool_v = (const float*)d_in[16]; wa.pool_g = (const float*)d_in[17]; wa.pool_b = (const float*)d_in[18];
    wa.pool2_v= (const float*)d_in[19]; wa.pool2_g= (const float*)d_in[20]; wa.pool2_b= (const float*)d_in[21];
    wa.self_v = (const float*)d_in[22]; wa.self_g = (const float*)d_in[23]; wa.self_b = (const float*)d_in[24];
    wa.neigh_v= (const float*)d_in[25]; wa.neigh_g= (const float*)d_in[26]; wa.neigh_b= (const float*)d_in[27];
    wa.neigh2_v=(const float*)d_in[28]; wa.neigh2_g=(const float*)d_in[29]; wa.neigh2_b=(const float*)d_in[30];
    wa.mlp_v  = (const float*)d_in[31]; wa.mlp_g  = (const float*)d_in[32]; wa.mlp_b  = (const float*)d_in[33];
    const int* src = (const int*)d_in[34];
    const int* dst = (const int*)d_in[35];
    float* out = (float*)d_out;
    float* ws = (float*)d_ws;
    wa.ws = ws;
    unsigned short* featbf  = (unsigned short*)(ws + OFF_FEATBF);
    unsigned short* hbf     = (unsigned short*)(ws + OFF_HBF);
    unsigned short* neighbf = (unsigned short*)(ws + OFF_NEIGHBF);
    unsigned short* wnodebf = (unsigned short*)(ws + OFF_WNODEBF);
    unsigned short* wfinbf  = (unsigned short*)(ws + OFF_WFINBF);
    unsigned short* wmlpbf  = (unsigned short*)(ws + OFF_WMLPBF);
    unsigned short* wedgebf = (unsigned short*)(ws + OFF_WEDGEBF);

    // 1) normalized weights + fused bias vectors
    wnorm_kernel<<<dim3(1281), dim3(128), 0, stream>>>(wa);
    // 2) weight tables -> bf16 (incl. packed fused edge weight table)
    convert_weights_kernel<<<dim3(832), dim3(256), 0, stream>>>(ws);
    // 3) CSR-by-dst (two-level parallel scan)
    hist_zero_kernel<<<dim3((NN + 255) / 256), dim3(256), 0, stream>>>(ws);
    hist_kernel<<<dim3((EE + 255) / 256), dim3(256), 0, stream>>>(dst, ws);
    scan_blocks_kernel<<<dim3(SCAN_NB), dim3(256), 0, stream>>>(ws);
    scan_tops_kernel<<<dim3(1), dim3(256), 0, stream>>>(ws);
    scan_add_kernel<<<dim3(SCAN_NB), dim3(256), 0, stream>>>(ws);
    scatteridx_kernel<<<dim3((EE + 255) / 256), dim3(256), 0, stream>>>(src, dst, ws);
    // 4) node GEMM (MFMA): converts feat->bf16 AND computes h/h2 (one launch)
    gemm_node_mfma<<<dim3(782), dim3(256), 0, stream>>>(feat, wa.pool_b, wa.pool2_b, featbf, hbf, wnodebf);
    // 5) edge GEMM (fused K=384, LDS-staged B dbuf, A prefetch d2) -> sev
    gemm_edge<<<dim3(EE / 128), dim3(256), 0, stream>>>(featbf, wedgebf, ws);
    // 6) segmented reduce -> neighbf (max zeroed | mean)
    segreduce_kernel<<<dim3(NN / 4), dim3(256), 0, stream>>>(ws);
    // 7) fused final GEMM + 2 MLP layers -> out (single pass, no global round trips)
    gemm_final_mlp<<<dim3(782), dim3(256), 0, stream>>>(neighbf, featbf, wfinbf, wmlpbf, wa.mlp_b, out, ws);
}